// Round 10
// baseline (1011.263 us; speedup 1.0000x reference)
//
#include <hip/hip_runtime.h>
#include <cstdio>

#define DD 128
#define NREL 4

using short8 = __attribute__((ext_vector_type(8))) short;
using f32x4  = __attribute__((ext_vector_type(4))) float;

struct PtrB4 { const unsigned short* p[4]; };
struct OutB4 { unsigned short* p[4]; };

// processing-order relation r uses edge_index/rel_emb row (r+3)&3  (perm = [3,0,1,2])
__device__ __forceinline__ int edge_perm(int r) { return (r + 3) & 3; }

__device__ __forceinline__ float bf_lo(unsigned u) { return __uint_as_float(u << 16); }
__device__ __forceinline__ float bf_hi(unsigned u) { return __uint_as_float(u & 0xffff0000u); }
__device__ __forceinline__ float bfe(short s) {
  return __uint_as_float(((unsigned)(unsigned short)s) << 16);
}
__device__ __forceinline__ unsigned short f2bf(float f) {
  unsigned x = __float_as_uint(f);
  unsigned r = (x + 0x7fffu + ((x >> 16) & 1u)) >> 16;
  return (unsigned short)r;
}
__device__ __forceinline__ unsigned pack2(float a, float b) {
  return (unsigned)f2bf(a) | ((unsigned)f2bf(b) << 16);
}

// swizzled LDS index for 64x136-short tiles: rows 16 apart land on distinct banks
#define SWIDX(row, col) ((row) * 136 + ((col) ^ ((((row) >> 4) & 3) << 4)))

// ---------------- init / weight prep ----------------

__global__ void rels_init(const float* __restrict__ rel_emb, float* __restrict__ rels) {
  int t = threadIdx.x;              // 512 = r*128 + c
  int r = t >> 7, c = t & 127;
  rels[t] = rel_emb[edge_perm(r) * DD + c];
}

__global__ void rels_update(const float* __restrict__ rin, const float* __restrict__ Wrt,
                            const float* __restrict__ brt, float* __restrict__ rout) {
  int t = threadIdx.x;  // 512 = r*128 + j
  int r = t >> 7, j = t & 127;
  float s = brt[j];
  const float* wr = Wrt + j * DD;
  const float* xr = rin + r * DD;
  for (int c = 0; c < DD; ++c) s += xr[c] * wr[c];
  rout[t] = s;
}

// Wsb[r][j][c] = bf16(rels[r][c] * Wg[c][j])  -- MFMA-B layout [n=j][k=c]
__global__ void scale_w_bf(const float* __restrict__ rels_i, const float* __restrict__ Wg,
                           unsigned short* __restrict__ Wsb) {
  int i = blockIdx.x * 256 + threadIdx.x;   // 4*16384
  int r = i >> 14, rem = i & 16383, j = rem >> 7, c = rem & 127;
  Wsb[i] = f2bf(rels_i[r * DD + c] * Wg[c * DD + j]);
}

// Wab = bf16( attn_w_in (3*16384) || attn_wout (16384) || fusion_w (16384) ), all [j][c]
__global__ void conv_w(const float* __restrict__ w_in, const float* __restrict__ w_out,
                       const float* __restrict__ w_fus, unsigned short* __restrict__ Wab) {
  int i = blockIdx.x * 256 + threadIdx.x;   // 5*16384
  float v = (i < 49152) ? w_in[i] : (i < 65536 ? w_out[i - 49152] : w_fus[i - 65536]);
  Wab[i] = f2bf(v);
}

// fp32 -> bf16 single slice
__global__ void conv_f2b(const float* __restrict__ in, unsigned* __restrict__ out2, size_t n4) {
  size_t i = (size_t)blockIdx.x * 256 + threadIdx.x;
  if (i < n4) {
    float4 v = ((const float4*)in)[i];
    out2[i * 2]     = pack2(v.x, v.y);
    out2[i * 2 + 1] = pack2(v.z, v.w);
  }
}

// ---------------- CSR build ----------------

__global__ void count_deg(const int* __restrict__ ei, int* __restrict__ deg, int N, int E) {
  int r = blockIdx.y;
  int base = blockIdx.x * 1024 + threadIdx.x;
  const int* dsts = ei + (size_t)edge_perm(r) * 2 * E + E;
#pragma unroll
  for (int k = 0; k < 4; ++k) {
    int e = base + k * 256;
    if (e < E) atomicAdd(deg + (size_t)r * N + dsts[e], 1);
  }
}

__global__ void finalize_dinv(const int* __restrict__ deg, float* __restrict__ dinv, int total) {
  int i = blockIdx.x * 256 + threadIdx.x;
  if (i < total) dinv[i] = rsqrtf((float)deg[i] + 1.0f);
}

__global__ void scan_block(const int* __restrict__ deg, int* __restrict__ excl,
                           int* __restrict__ bsums, int n) {
  __shared__ int sh[256];
  int i = blockIdx.x * 256 + threadIdx.x;
  int v = (i < n) ? deg[i] : 0;
  sh[threadIdx.x] = v;
  __syncthreads();
  for (int st = 1; st < 256; st <<= 1) {
    int t = (threadIdx.x >= st) ? sh[threadIdx.x - st] : 0;
    __syncthreads();
    sh[threadIdx.x] += t;
    __syncthreads();
  }
  if (i < n) excl[i] = sh[threadIdx.x] - v;
  if (threadIdx.x == 255) bsums[blockIdx.x] = sh[255];
}

__global__ void scan_sums(int* __restrict__ bsums, int nb) {
  __shared__ int sh[1024];
  int v = (threadIdx.x < nb) ? bsums[threadIdx.x] : 0;
  sh[threadIdx.x] = v;
  __syncthreads();
  for (int st = 1; st < 1024; st <<= 1) {
    int t = (threadIdx.x >= st) ? sh[threadIdx.x - st] : 0;
    __syncthreads();
    sh[threadIdx.x] += t;
    __syncthreads();
  }
  if (threadIdx.x < nb) bsums[threadIdx.x] = sh[threadIdx.x] - v;  // exclusive
}

__global__ void scan_add(int* __restrict__ excl, int* __restrict__ cursor,
                         const int* __restrict__ bsums, int n) {
  int i = blockIdx.x * 256 + threadIdx.x;
  if (i < n) {
    int o = excl[i] + bsums[blockIdx.x];
    excl[i] = o;
    cursor[i] = o;
  }
}

// 4 edges/thread: 4 independent atomic-returns in flight
__global__ void fill_edges(const int* __restrict__ ei, int* __restrict__ cursor,
                           int* __restrict__ srcbuf, int N, int E) {
  int r = blockIdx.y;
  int base = blockIdx.x * 1024 + threadIdx.x;
  const int* bp = ei + (size_t)edge_perm(r) * 2 * E;
  int s[4], d[4], pos[4];
#pragma unroll
  for (int k = 0; k < 4; ++k) {
    int e = base + k * 256;
    s[k] = (e < E) ? bp[e] : 0;
    d[k] = (e < E) ? bp[E + e] : 0;
  }
#pragma unroll
  for (int k = 0; k < 4; ++k) {
    int e = base + k * 256;
    if (e < E) pos[k] = atomicAdd(&cursor[r * N + d[k]], 1);
  }
#pragma unroll
  for (int k = 0; k < 4; ++k) {
    int e = base + k * 256;
    if (e < E) srcbuf[pos[k]] = r * N + s[k];
  }
}

// ---------------- weight-stationary MFMA GEMM (round-7 proven) ----------------
// Block 256 = 4 waves: wave = (rowhalf<<1)|colhalf; each wave: 32 rows x 64 cols.
// MODE 0: out bf16 = y * dinv[z*M+row]           (GCN messages)
template <int MODE>
__global__ __launch_bounds__(256) void gemm_ws(PtrB4 xs, PtrB4 wz, OutB4 ys,
                                               const float* __restrict__ bias,
                                               const float* __restrict__ dinv, int M) {
  int z = blockIdx.y;
  const unsigned short* __restrict__ X = xs.p[z];
  const unsigned short* __restrict__ W = wz.p[z];
  int tid = threadIdx.x;
  int wave = tid >> 6, lane = tid & 63;
  int r16 = lane & 15, kgrp = lane >> 4;
  int rowhalf = wave >> 1, colbase = (wave & 1) * 64;
  int blockrow = blockIdx.x * 64;

  short8 b[4][4];
#pragma unroll
  for (int s = 0; s < 4; ++s)
#pragma unroll
    for (int cn = 0; cn < 4; ++cn)
      b[s][cn] = *(const short8*)(W + ((colbase + cn * 16 + r16) << 7) + s * 32 + kgrp * 8);

  int row0 = blockrow + rowhalf * 32 + r16;
  int r0c = row0 < M ? row0 : M - 1;
  int r1c = row0 + 16 < M ? row0 + 16 : M - 1;
  short8 a[2][4];
#pragma unroll
  for (int s = 0; s < 4; ++s) {
    a[0][s] = *(const short8*)(X + (size_t)r0c * DD + s * 32 + kgrp * 8);
    a[1][s] = *(const short8*)(X + (size_t)r1c * DD + s * 32 + kgrp * 8);
  }

  f32x4 acc[2][4];
#pragma unroll
  for (int rt = 0; rt < 2; ++rt)
#pragma unroll
    for (int cn = 0; cn < 4; ++cn)
#pragma unroll
      for (int j = 0; j < 4; ++j) acc[rt][cn][j] = 0.f;

#pragma unroll
  for (int s = 0; s < 4; ++s)
#pragma unroll
    for (int rt = 0; rt < 2; ++rt)
#pragma unroll
      for (int cn = 0; cn < 4; ++cn)
        acc[rt][cn] = __builtin_amdgcn_mfma_f32_16x16x32_bf16(a[rt][s], b[s][cn], acc[rt][cn], 0, 0, 0);

  __shared__ __align__(16) unsigned short tile[64][DD + 8];
  float dv[2][4];
  if constexpr (MODE == 0) {
#pragma unroll
    for (int rt = 0; rt < 2; ++rt)
#pragma unroll
      for (int i = 0; i < 4; ++i) {
        int row = blockrow + rowhalf * 32 + rt * 16 + kgrp * 4 + i;
        dv[rt][i] = dinv[(size_t)z * M + (row < M ? row : 0)];
      }
  }
#pragma unroll
  for (int rt = 0; rt < 2; ++rt)
#pragma unroll
    for (int cn = 0; cn < 4; ++cn) {
      int col = colbase + cn * 16 + r16;
#pragma unroll
      for (int i = 0; i < 4; ++i) {
        int wrow = rowhalf * 32 + rt * 16 + kgrp * 4 + i;
        float y = acc[rt][cn][i];
        if constexpr (MODE == 0) y *= dv[rt][i];
        tile[wrow][col] = f2bf(y);
      }
    }
  __syncthreads();
  int orow = tid >> 2, seg = tid & 3;
  int grow = blockrow + orow;
  if (grow < M) {
    unsigned short* Yp = ys.p[z] + (size_t)grow * DD + seg * 32;
    const unsigned short* tp = &tile[orow][seg * 32];
#pragma unroll
    for (int k = 0; k < 4; ++k)
      *(uint4*)(Yp + k * 8) = *(const uint4*)(tp + k * 8);
  }
}

// Layers 1/2 fused GEMM (round-7 proven): e = res + leaky(bn(Ab)); optional writeback;
// messages = (e@Wz)*dinv
template <int WB>
__global__ __launch_bounds__(256) void gemm_upd(PtrB4 res, PtrB4 abs_, PtrB4 wz,
                                                OutB4 xout, OutB4 ys,
                                                const float* __restrict__ ssx,
                                                const float* __restrict__ dinv, int M) {
  int z = blockIdx.y;
  const unsigned short* __restrict__ R = res.p[z];
  const unsigned short* __restrict__ A = abs_.p[z];
  const unsigned short* __restrict__ W = wz.p[z];
  int tid = threadIdx.x;

  __shared__ float ssc[DD], ssh[DD];
  if (tid < DD) {
    ssc[tid] = ssx[((size_t)z * DD + tid) * 2];
    ssh[tid] = ssx[((size_t)z * DD + tid) * 2 + 1];
  }
  __syncthreads();

  int wave = tid >> 6, lane = tid & 63;
  int r16 = lane & 15, kgrp = lane >> 4;
  int rowhalf = wave >> 1, colbase = (wave & 1) * 64;
  int blockrow = blockIdx.x * 64;

  short8 b[4][4];
#pragma unroll
  for (int s = 0; s < 4; ++s)
#pragma unroll
    for (int cn = 0; cn < 4; ++cn)
      b[s][cn] = *(const short8*)(W + ((colbase + cn * 16 + r16) << 7) + s * 32 + kgrp * 8);

  int row0 = blockrow + rowhalf * 32 + r16;
  int rc[2];
  rc[0] = row0 < M ? row0 : M - 1;
  rc[1] = row0 + 16 < M ? row0 + 16 : M - 1;
  short8 a[2][4];
#pragma unroll
  for (int rt = 0; rt < 2; ++rt)
#pragma unroll
    for (int s = 0; s < 4; ++s) {
      int cbase = s * 32 + kgrp * 8;
      short8 rv = *(const short8*)(R + (size_t)rc[rt] * DD + cbase);
      short8 av = *(const short8*)(A + (size_t)rc[rt] * DD + cbase);
      short8 av2;
#pragma unroll
      for (int j = 0; j < 8; ++j) {
        float x = bfe(av[j]) * ssc[cbase + j] + ssh[cbase + j];
        x = x > 0.f ? x : 0.01f * x;
        av2[j] = (short)f2bf(bfe(rv[j]) + x);
      }
      a[rt][s] = av2;
    }
  if (WB) {
#pragma unroll
    for (int rt = 0; rt < 2; ++rt) {
      int row = row0 + rt * 16;
      if (row < M) {
#pragma unroll
        for (int s = 0; s < 4; ++s)
          *(short8*)(xout.p[z] + (size_t)row * DD + s * 32 + kgrp * 8) = a[rt][s];
      }
    }
  }

  f32x4 acc[2][4];
#pragma unroll
  for (int rt = 0; rt < 2; ++rt)
#pragma unroll
    for (int cn = 0; cn < 4; ++cn)
#pragma unroll
      for (int j = 0; j < 4; ++j) acc[rt][cn][j] = 0.f;
#pragma unroll
  for (int s = 0; s < 4; ++s)
#pragma unroll
    for (int rt = 0; rt < 2; ++rt)
#pragma unroll
      for (int cn = 0; cn < 4; ++cn)
        acc[rt][cn] = __builtin_amdgcn_mfma_f32_16x16x32_bf16(a[rt][s], b[s][cn], acc[rt][cn], 0, 0, 0);

  __shared__ __align__(16) unsigned short tile[64][DD + 8];
  float dv[2][4];
#pragma unroll
  for (int rt = 0; rt < 2; ++rt)
#pragma unroll
    for (int i = 0; i < 4; ++i) {
      int row = blockrow + rowhalf * 32 + rt * 16 + kgrp * 4 + i;
      dv[rt][i] = dinv[(size_t)z * M + (row < M ? row : 0)];
    }
#pragma unroll
  for (int rt = 0; rt < 2; ++rt)
#pragma unroll
    for (int cn = 0; cn < 4; ++cn) {
      int col = colbase + cn * 16 + r16;
#pragma unroll
      for (int i = 0; i < 4; ++i) {
        int wrow = rowhalf * 32 + rt * 16 + kgrp * 4 + i;
        tile[wrow][col] = f2bf(acc[rt][cn][i] * dv[rt][i]);
      }
    }
  __syncthreads();
  int orow = tid >> 2, seg = tid & 3;
  int grow = blockrow + orow;
  if (grow < M) {
    unsigned short* Yp = ys.p[z] + (size_t)grow * DD + seg * 32;
    const unsigned short* tp = &tile[orow][seg * 32];
#pragma unroll
    for (int k = 0; k < 4; ++k)
      *(uint4*)(Yp + k * 8) = *(const uint4*)(tp + k * 8);
  }
}

// ---------------- mega-fused attention phase (v2: 2 LDS arrays + swizzle) ----------------
// One block = 16 nodes (N divisible workload). Rows r in [0,64): layer l = r>>4,
// node = nodebase + (r&15).  Phases:
//   Q->q_s, K->k_s | scores -> p regs | V->q_s | PV: O->k_s | proj -> q_s |
//   blend (f -> global + q_s) | fusion GEMM + score reduce.
// LDS 34.8 KB -> 4 blocks/CU; SWIDX kills the row-stride bank conflicts.
__global__ __launch_bounds__(256, 4) void attn_mega(PtrB4 stks,
    const unsigned short* __restrict__ Wab,
    const float* __restrict__ b_in, const float* __restrict__ b_out,
    const float* __restrict__ alphas, const float* __restrict__ fus_b,
    const float* __restrict__ fq, unsigned short* __restrict__ fbuf,
    float* __restrict__ S, int N) {
  __shared__ __align__(16) unsigned short q_s[64 * 136];  // Q -> V -> proj -> f
  __shared__ __align__(16) unsigned short k_s[64 * 136];  // K -> O
  __shared__ float lred[4];
  size_t NK = (size_t)N * DD;

  int tid = threadIdx.x;
  int wave = tid >> 6, lane = tid & 63;
  int r16 = lane & 15, kgrp = lane >> 4;
  int rowhalf = wave >> 1, colbase = (wave & 1) * 64;
  int nodebase = blockIdx.x * 16;

  int rlo = rowhalf * 32 + r16;     // 0..63
  int rhi = rlo + 16;
  int nlo = nodebase + (rlo & 15); if (nlo >= N) nlo = N - 1;
  int nhi = nodebase + (rhi & 15); if (nhi >= N) nhi = N - 1;
  const unsigned short* a0p = stks.p[rlo >> 4] + (size_t)nlo * DD + kgrp * 8;
  const unsigned short* a1p = stks.p[rhi >> 4] + (size_t)nhi * DD + kgrp * 8;
  short8 A0[4], A1[4];
#pragma unroll
  for (int s = 0; s < 4; ++s) {
    A0[s] = *(const short8*)(a0p + s * 32);
    A1[s] = *(const short8*)(a1p + s * 32);
  }

  // ---- Q -> q_s, K -> k_s ----
  for (int o = 0; o < 2; ++o) {
    const unsigned short* W = Wab + o * 16384;
    short8 b[4][4];
#pragma unroll
    for (int s = 0; s < 4; ++s)
#pragma unroll
      for (int cn = 0; cn < 4; ++cn)
        b[s][cn] = *(const short8*)(W + ((colbase + cn * 16 + r16) << 7) + s * 32 + kgrp * 8);
    f32x4 acc[2][4];
#pragma unroll
    for (int rt = 0; rt < 2; ++rt)
#pragma unroll
      for (int cn = 0; cn < 4; ++cn)
#pragma unroll
        for (int j = 0; j < 4; ++j) acc[rt][cn][j] = 0.f;
#pragma unroll
    for (int s = 0; s < 4; ++s)
#pragma unroll
      for (int cn = 0; cn < 4; ++cn) {
        acc[0][cn] = __builtin_amdgcn_mfma_f32_16x16x32_bf16(A0[s], b[s][cn], acc[0][cn], 0, 0, 0);
        acc[1][cn] = __builtin_amdgcn_mfma_f32_16x16x32_bf16(A1[s], b[s][cn], acc[1][cn], 0, 0, 0);
      }
    unsigned short* dst = (o == 0) ? q_s : k_s;
#pragma unroll
    for (int rt = 0; rt < 2; ++rt)
#pragma unroll
      for (int cn = 0; cn < 4; ++cn) {
        int col = colbase + cn * 16 + r16;
        float bb = b_in[o * DD + col];
#pragma unroll
        for (int i = 0; i < 4; ++i) {
          int wrow = rowhalf * 32 + rt * 16 + kgrp * 4 + i;
          dst[SWIDX(wrow, col)] = f2bf(acc[rt][cn][i] + bb);
        }
      }
  }
  __syncthreads();

  // ---- scores -> p[4] regs (wave owns nodes wave*4..+3) ----
  float p[4];
  {
    int h = lane >> 4, li = (lane >> 2) & 3, m = lane & 3;
    for (int t = 0; t < 4; ++t) {
      int nd = wave * 4 + t;
      float sc = 0.f;
#pragma unroll
      for (int s4 = 0; s4 < 4; ++s4) {
        short8 qv = *(const short8*)&q_s[SWIDX(li * 16 + nd, h * 32 + s4 * 8)];
        short8 kv = *(const short8*)&k_s[SWIDX(m * 16 + nd, h * 32 + s4 * 8)];
#pragma unroll
        for (int j = 0; j < 8; ++j) sc += bfe(qv[j]) * bfe(kv[j]);
      }
      sc *= 0.17677669529663687f;              // 1/sqrt(32)
      float mx = sc;
      mx = fmaxf(mx, __shfl_xor(mx, 1));
      mx = fmaxf(mx, __shfl_xor(mx, 2));
      float e = expf(sc - mx);
      float sum = e;
      sum += __shfl_xor(sum, 1);
      sum += __shfl_xor(sum, 2);
      p[t] = e / sum;                          // lane holds p[h][li][m] for node nd
    }
  }
  __syncthreads();   // all score reads done before V overwrites q_s

  // ---- V -> q_s ----
  {
    const unsigned short* W = Wab + 2 * 16384;
    short8 b[4][4];
#pragma unroll
    for (int s = 0; s < 4; ++s)
#pragma unroll
      for (int cn = 0; cn < 4; ++cn)
        b[s][cn] = *(const short8*)(W + ((colbase + cn * 16 + r16) << 7) + s * 32 + kgrp * 8);
    f32x4 acc[2][4];
#pragma unroll
    for (int rt = 0; rt < 2; ++rt)
#pragma unroll
      for (int cn = 0; cn < 4; ++cn)
#pragma unroll
        for (int j = 0; j < 4; ++j) acc[rt][cn][j] = 0.f;
#pragma unroll
    for (int s = 0; s < 4; ++s)
#pragma unroll
      for (int cn = 0; cn < 4; ++cn) {
        acc[0][cn] = __builtin_amdgcn_mfma_f32_16x16x32_bf16(A0[s], b[s][cn], acc[0][cn], 0, 0, 0);
        acc[1][cn] = __builtin_amdgcn_mfma_f32_16x16x32_bf16(A1[s], b[s][cn], acc[1][cn], 0, 0, 0);
      }
#pragma unroll
    for (int rt = 0; rt < 2; ++rt)
#pragma unroll
      for (int cn = 0; cn < 4; ++cn) {
        int col = colbase + cn * 16 + r16;
        float bb = b_in[2 * DD + col];
#pragma unroll
        for (int i = 0; i < 4; ++i) {
          int wrow = rowhalf * 32 + rt * 16 + kgrp * 4 + i;
          q_s[SWIDX(wrow, col)] = f2bf(acc[rt][cn][i] + bb);
        }
      }
  }
  __syncthreads();

  // ---- PV: O -> k_s (p distributed via shuffles; wave-local nodes) ----
  {
    int c0 = lane * 2, hh = lane >> 4;   // hh = c0>>5
    for (int t = 0; t < 4; ++t) {
      int nd = wave * 4 + t;
      unsigned v[4];
#pragma unroll
      for (int m = 0; m < 4; ++m)
        v[m] = *(const unsigned*)&q_s[SWIDX(m * 16 + nd, c0)];
#pragma unroll
      for (int lo = 0; lo < 4; ++lo) {
        float ol = 0.f, oh = 0.f;
#pragma unroll
        for (int m = 0; m < 4; ++m) {
          float pm = __shfl(p[t], hh * 16 + lo * 4 + m);
          ol += pm * bf_lo(v[m]);
          oh += pm * bf_hi(v[m]);
        }
        *(unsigned*)&k_s[SWIDX(lo * 16 + nd, c0)] = pack2(ol, oh);
      }
    }
  }
  __syncthreads();

  // ---- out-proj: A = O (k_s) -> q_s holds y + b_out ----
  {
    const unsigned short* W = Wab + 3 * 16384;
    short8 b[4][4];
#pragma unroll
    for (int s = 0; s < 4; ++s)
#pragma unroll
      for (int cn = 0; cn < 4; ++cn)
        b[s][cn] = *(const short8*)(W + ((colbase + cn * 16 + r16) << 7) + s * 32 + kgrp * 8);
    short8 AO0[4], AO1[4];
#pragma unroll
    for (int s = 0; s < 4; ++s) {
      AO0[s] = *(const short8*)&k_s[SWIDX(rlo, s * 32 + kgrp * 8)];
      AO1[s] = *(const short8*)&k_s[SWIDX(rhi, s * 32 + kgrp * 8)];
    }
    f32x4 acc[2][4];
#pragma unroll
    for (int rt = 0; rt < 2; ++rt)
#pragma unroll
      for (int cn = 0; cn < 4; ++cn)
#pragma unroll
        for (int j = 0; j < 4; ++j) acc[rt][cn][j] = 0.f;
#pragma unroll
    for (int s = 0; s < 4; ++s)
#pragma unroll
      for (int cn = 0; cn < 4; ++cn) {
        acc[0][cn] = __builtin_amdgcn_mfma_f32_16x16x32_bf16(AO0[s], b[s][cn], acc[0][cn], 0, 0, 0);
        acc[1][cn] = __builtin_amdgcn_mfma_f32_16x16x32_bf16(AO1[s], b[s][cn], acc[1][cn], 0, 0, 0);
      }
#pragma unroll
    for (int rt = 0; rt < 2; ++rt)
#pragma unroll
      for (int cn = 0; cn < 4; ++cn) {
        int col = colbase + cn * 16 + r16;
        float bb = b_out[col];
#pragma unroll
        for (int i = 0; i < 4; ++i) {
          int wrow = rowhalf * 32 + rt * 16 + kgrp * 4 + i;
          q_s[SWIDX(wrow, col)] = f2bf(acc[rt][cn][i] + bb);
        }
      }
  }
  __syncthreads();

  // ---- blend with stk, store f to global, write back to q_s ----
  {
    int orow = tid >> 2, seg = tid & 3;
    int lb = orow >> 4, nb = nodebase + (orow & 15);
    if (nb < N) {
      float aa = alphas[lb], na = 1.f - aa;
      const unsigned short* sp = stks.p[lb] + (size_t)nb * DD + seg * 32;
      unsigned short* Yp = fbuf + (size_t)lb * NK + (size_t)nb * DD + seg * 32;
#pragma unroll
      for (int k = 0; k < 4; ++k) {
        unsigned short* tp = &q_s[SWIDX(orow, seg * 32 + k * 8)];
        uint4 pv = *(const uint4*)tp;
        uint4 sv = *(const uint4*)(sp + k * 8);
        const unsigned* pw = &pv.x;
        const unsigned* sw = &sv.x;
        uint4 o; unsigned* ow = &o.x;
#pragma unroll
        for (int j = 0; j < 4; ++j)
          ow[j] = pack2(aa * bf_lo(pw[j]) + na * bf_lo(sw[j]),
                        aa * bf_hi(pw[j]) + na * bf_hi(sw[j]));
        *(uint4*)(Yp + k * 8) = o;
        *(uint4*)tp = o;
      }
    }
  }
  __syncthreads();

  // ---- fusion GEMM on f (q_s) + leaky*fq score reduce ----
  {
    const unsigned short* W = Wab + 4 * 16384;
    short8 b[4][4];
#pragma unroll
    for (int s = 0; s < 4; ++s)
#pragma unroll
      for (int cn = 0; cn < 4; ++cn)
        b[s][cn] = *(const short8*)(W + ((colbase + cn * 16 + r16) << 7) + s * 32 + kgrp * 8);
    short8 AF0[4], AF1[4];
#pragma unroll
    for (int s = 0; s < 4; ++s) {
      AF0[s] = *(const short8*)&q_s[SWIDX(rlo, s * 32 + kgrp * 8)];
      AF1[s] = *(const short8*)&q_s[SWIDX(rhi, s * 32 + kgrp * 8)];
    }
    f32x4 acc[2][4];
#pragma unroll
    for (int rt = 0; rt < 2; ++rt)
#pragma unroll
      for (int cn = 0; cn < 4; ++cn)
#pragma unroll
        for (int j = 0; j < 4; ++j) acc[rt][cn][j] = 0.f;
#pragma unroll
    for (int s = 0; s < 4; ++s)
#pragma unroll
      for (int cn = 0; cn < 4; ++cn) {
        acc[0][cn] = __builtin_amdgcn_mfma_f32_16x16x32_bf16(AF0[s], b[s][cn], acc[0][cn], 0, 0, 0);
        acc[1][cn] = __builtin_amdgcn_mfma_f32_16x16x32_bf16(AF1[s], b[s][cn], acc[1][cn], 0, 0, 0);
      }
    float ss0 = 0.f, ss1 = 0.f;
#pragma unroll
    for (int cn = 0; cn < 4; ++cn) {
      int col = colbase + cn * 16 + r16;
      float bb = fus_b[col];
      float qc = fq[col];
#pragma unroll
      for (int i = 0; i < 4; ++i) {
        if (nodebase + kgrp * 4 + i < N) {
          float y0 = acc[0][cn][i] + bb;
          float y1 = acc[1][cn][i] + bb;
          ss0 += (y0 > 0.f ? y0 : 0.01f * y0) * qc;
          ss1 += (y1 > 0.f ? y1 : 0.01f * y1) * qc;
        }
      }
    }
    if (tid < 4) lred[tid] = 0.f;
    __syncthreads();
    atomicAdd(&lred[rowhalf * 2], ss0);
    atomicAdd(&lred[rowhalf * 2 + 1], ss1);
    __syncthreads();
    if (tid < 4) atomicAdd(S + tid, lred[tid]);
  }
}

// ---------------- GCN aggregation: CSR gather, 2 nodes/wave, unroll x8 ----------------
__global__ __launch_bounds__(256) void gather_agg(const int* __restrict__ srcbuf,
                                                  const int* __restrict__ offs,
                                                  const int* __restrict__ deg,
                                                  const float* __restrict__ dinv,
                                                  const uint2* __restrict__ Bs2,
                                                  const float* __restrict__ bias,
                                                  uint2* __restrict__ Ab2, int N4) {
  int rn = blockIdx.x * 8 + (threadIdx.x >> 5);
  if (rn >= N4) return;
  int lane = threadIdx.x & 31;
  int st = offs[rn], cnt = deg[rn];
  uint2 u = Bs2[(size_t)rn * 32 + lane];        // self message
  float a0 = bf_lo(u.x), a1 = bf_hi(u.x), a2 = bf_lo(u.y), a3 = bf_hi(u.y);
  int e = 0;
  for (; e + 8 <= cnt; e += 8) {
    int rr[8];
#pragma unroll
    for (int j = 0; j < 8; ++j) rr[j] = srcbuf[st + e + j];
    uint2 vv[8];
#pragma unroll
    for (int j = 0; j < 8; ++j) vv[j] = Bs2[(size_t)rr[j] * 32 + lane];
#pragma unroll
    for (int j = 0; j < 8; ++j) {
      a0 += bf_lo(vv[j].x); a1 += bf_hi(vv[j].x);
      a2 += bf_lo(vv[j].y); a3 += bf_hi(vv[j].y);
    }
  }
  if (e + 4 <= cnt) {
    int rr[4];
#pragma unroll
    for (int j = 0; j < 4; ++j) rr[j] = srcbuf[st + e + j];
    uint2 vv[4];
#pragma unroll
    for (int j = 0; j < 4; ++j) vv[j] = Bs2[(size_t)rr[j] * 32 + lane];
#pragma unroll
    for (int j = 0; j < 4; ++j) {
      a0 += bf_lo(vv[j].x); a1 += bf_hi(vv[j].x);
      a2 += bf_lo(vv[j].y); a3 += bf_hi(vv[j].y);
    }
    e += 4;
  }
  for (; e < cnt; ++e) {
    uint2 v = Bs2[(size_t)srcbuf[st + e] * 32 + lane];
    a0 += bf_lo(v.x); a1 += bf_hi(v.x); a2 += bf_lo(v.y); a3 += bf_hi(v.y);
  }
  float dvv = dinv[rn];
  int c = lane * 4;
  uint2 o;
  o.x = pack2(a0 * dvv + bias[c],     a1 * dvv + bias[c + 1]);
  o.y = pack2(a2 * dvv + bias[c + 2], a3 * dvv + bias[c + 3]);
  Ab2[(size_t)rn * 32 + lane] = o;
}

// ---------------- batchnorm ----------------

__global__ void bn_stats(const unsigned* __restrict__ Ab2, float* __restrict__ sums, int N) {
  int r = blockIdx.y;
  int lane = threadIdx.x & 63, grp = threadIdx.x >> 6;
  float s0 = 0.f, q0 = 0.f, s1 = 0.f, q1 = 0.f;
  const unsigned* base = Ab2 + (size_t)r * N * 64;
  for (int n = blockIdx.x * 4 + grp; n < N; n += gridDim.x * 4) {
    unsigned u = base[(size_t)n * 64 + lane];
    float a = bf_lo(u), b = bf_hi(u);
    s0 += a; q0 += a * a; s1 += b; q1 += b * b;
  }
  __shared__ float sh[4][64][4];
  sh[grp][lane][0] = s0; sh[grp][lane][1] = q0; sh[grp][lane][2] = s1; sh[grp][lane][3] = q1;
  __syncthreads();
  if (grp == 0) {
#pragma unroll
    for (int g = 1; g < 4; ++g) {
      s0 += sh[g][lane][0]; q0 += sh[g][lane][1]; s1 += sh[g][lane][2]; q1 += sh[g][lane][3];
    }
    int c0 = lane * 2;
    atomicAdd(sums + (r * DD + c0) * 2, s0);
    atomicAdd(sums + (r * DD + c0) * 2 + 1, q0);
    atomicAdd(sums + (r * DD + c0 + 1) * 2, s1);
    atomicAdd(sums + (r * DD + c0 + 1) * 2 + 1, q1);
  }
}

__global__ void bn_final(const float* __restrict__ sums, const float* __restrict__ gamma,
                         const float* __restrict__ beta, float* __restrict__ ss, int N) {
  int t = threadIdx.x;       // 512 = r*128+c
  int c = t & 127;
  float mu = sums[t * 2] / N;
  float var = sums[t * 2 + 1] / N - mu * mu;
  float sc = gamma[c] * rsqrtf(var + 1e-5f);
  ss[t * 2] = sc;
  ss[t * 2 + 1] = beta[c] - mu * sc;
}

// w = softmax([S(f0),S(f1),S(f3),S(f2)]);  coef[l] multiplies f[l]: coef = [w0,w1,w3,w2]
__global__ void wcoef(const float* __restrict__ S, float* __restrict__ coef, int N) {
  if (threadIdx.x == 0) {
    float v0 = S[0] / N, v1 = S[1] / N, v2 = S[3] / N, v3 = S[2] / N;
    float mx = fmaxf(fmaxf(v0, v1), fmaxf(v2, v3));
    float e0 = expf(v0 - mx), e1 = expf(v1 - mx), e2 = expf(v2 - mx), e3 = expf(v3 - mx);
    float inv = 1.f / (e0 + e1 + e2 + e3);
    coef[0] = e0 * inv; coef[1] = e1 * inv; coef[2] = e3 * inv; coef[3] = e2 * inv;
  }
}

__device__ __forceinline__ float bfat(uint2 u, int j) {
  unsigned w = (j < 2) ? u.x : u.y;
  return (j & 1) ? bf_hi(w) : bf_lo(w);
}

// region = sum coef[l]*f[l]; outputs: region, region*rels3[{3,0,1,2}]
__global__ void final_out(const unsigned short* __restrict__ fb, const float* __restrict__ coef,
                          const float* __restrict__ rels3, float* __restrict__ out, int N) {
  size_t NK = (size_t)N * DD;
  size_t i4 = (size_t)blockIdx.x * 256 + threadIdx.x;  // 4-elem groups
  if (i4 >= NK / 4) return;
  size_t g = i4 * 4;
  int c = (int)(g & 127);
  float c0 = coef[0], c1 = coef[1], c2 = coef[2], c3 = coef[3];
  uint2 u0 = *(const uint2*)(fb + g);
  uint2 u1 = *(const uint2*)(fb + NK + g);
  uint2 u2 = *(const uint2*)(fb + 2 * NK + g);
  uint2 u3 = *(const uint2*)(fb + 3 * NK + g);
  float4 reg4, o1, o2, o3, o4;
  float* rp = &reg4.x; float* p1 = &o1.x; float* p2 = &o2.x; float* p3 = &o3.x; float* p4 = &o4.x;
#pragma unroll
  for (int j = 0; j < 4; ++j) {
    float region = c0 * bfat(u0, j) + c1 * bfat(u1, j) + c2 * bfat(u2, j) + c3 * bfat(u3, j);
    rp[j] = region;
    p1[j] = region * rels3[3 * DD + c + j];
    p2[j] = region * rels3[0 * DD + c + j];
    p3[j] = region * rels3[1 * DD + c + j];
    p4[j] = region * rels3[2 * DD + c + j];
  }
  *(float4*)(out + g) = reg4;
  *(float4*)(out + NK + g) = o1;
  *(float4*)(out + 2 * NK + g) = o2;
  *(float4*)(out + 3 * NK + g) = o3;
  *(float4*)(out + 4 * NK + g) = o4;
}

// ---------------- host ----------------

extern "C" void kernel_launch(void* const* d_in, const int* in_sizes, int n_in,
                              void* d_out, int out_size, void* d_ws, size_t ws_size,
                              hipStream_t stream) {
  const float* features  = (const float*)d_in[0];
  const float* rel_emb   = (const float*)d_in[1];
  const int*   edge_idx  = (const int*)d_in[2];
  const float* W_gcn     = (const float*)d_in[3];
  const float* b_gcn     = (const float*)d_in[4];
  const float* bn_gamma  = (const float*)d_in[5];
  const float* bn_beta   = (const float*)d_in[6];
  const float* W_rt      = (const float*)d_in[7];
  const float* b_rt      = (const float*)d_in[8];
  const float* attn_w_in = (const float*)d_in[9];
  const float* attn_b_in = (const float*)d_in[10];
  const float* attn_wout = (const float*)d_in[11];
  const float* attn_bout = (const float*)d_in[12];
  const float* alphas    = (const float*)d_in[13];
  const float* fusion_q  = (const float*)d_in[14];
  const float* fusion_w  = (const float*)d_in[15];
  const float* fusion_b  = (const float*)d_in[16];

  int N = in_sizes[0] / DD;                  // 50000
  int E = in_sizes[2] / (2 * NREL);          // 400000
  size_t NK = (size_t)N * DD;
  int N4 = 4 * N;

  unsigned short* Xb = (unsigned short*)d_ws;            // 4*NK (emb1)
  unsigned short* Bs = Xb + 4 * NK;                      // 4*NK (messages / f)
  unsigned short* Ab = Bs + 4 * NK;                      // 4*NK (agg / stack)
  unsigned short* Ub = Ab + 4 * NK;                      // 4*NK (spare)
  unsigned short* Fb = Ub + 4 * NK;                      // NK (bf16 features, shared)
  float* dinv  = (float*)(Fb + NK);                      // 4*N
  unsigned short* Wgcnb = (unsigned short*)(dinv + N4);  // 4*16384
  unsigned short* Wab   = Wgcnb + 4 * DD * DD;           // 5*16384
  float* rels  = (float*)(Wab + 5 * DD * DD);            // 4 stages * 512
  float* bnsum = rels + 4 * 512;                         // 1024
  float* bnss  = bnsum + 1024;                           // 1024
  float* S     = bnss + 1024;                            // 4
  float* coef  = S + 4;                                  // 4
  int* deg_i   = (int*)(coef + 4);                       // 4*N
  int* offs    = deg_i + N4;                             // 4*N
  int* cur     = offs + N4;                              // 4*N
  int* bsums   = cur + N4;                               // 1024
  int* srcb    = bsums + 1024;                           // 4*E

  size_t needed = (size_t)((char*)(srcb + 4 * E) - (char*)d_ws);
  if (ws_size < needed) {
    fprintf(stderr, "kernel_launch: ws too small (%zu < %zu)\n", ws_size, needed);
    return;
  }

  int gemmGrid = (N + 63) / 64;
  int scanBlocks = (N4 + 255) / 256;
  int egrid4 = (E + 1023) / 1024;

  // ---- CSR build (edges fixed across layers) ----
  hipMemsetAsync(deg_i, 0, (size_t)N4 * sizeof(int), stream);
  count_deg<<<dim3(egrid4, 4), 256, 0, stream>>>(edge_idx, deg_i, N, E);
  finalize_dinv<<<scanBlocks, 256, 0, stream>>>(deg_i, dinv, N4);
  scan_block<<<scanBlocks, 256, 0, stream>>>(deg_i, offs, bsums, N4);
  scan_sums<<<1, 1024, 0, stream>>>(bsums, scanBlocks);
  scan_add<<<scanBlocks, 256, 0, stream>>>(offs, cur, bsums, N4);
  fill_edges<<<dim3(egrid4, 4), 256, 0, stream>>>(edge_idx, cur, srcb, N, E);

  rels_init<<<1, 512, 0, stream>>>(rel_emb, rels);
  conv_w<<<5 * 16384 / 256, 256, 0, stream>>>(attn_w_in, attn_wout, fusion_w, Wab);
  conv_f2b<<<(int)((NK / 4 + 255) / 256), 256, 0, stream>>>(features, (unsigned*)Fb, NK / 4);

  PtrB4 wz, abIn, resIn;
  OutB4 msgOut, xbOut, dummyO;
  for (int r = 0; r < 4; ++r) {
    wz.p[r] = Wgcnb + (size_t)r * DD * DD;
    abIn.p[r] = Ab + (size_t)r * NK;
    msgOut.p[r] = Bs + (size_t)r * NK;
    xbOut.p[r] = Xb + (size_t)r * NK;
    dummyO.p[r] = nullptr;
  }

  // ---- Layer 0 ----
  scale_w_bf<<<256, 256, 0, stream>>>(rels, W_gcn, Wgcnb);
  {
    PtrB4 xs; for (int r = 0; r < 4; ++r) xs.p[r] = Fb;
    gemm_ws<0><<<dim3(gemmGrid, 4), 256, 0, stream>>>(xs, wz, msgOut, nullptr, dinv, N);
  }
  gather_agg<<<(N4 + 7) / 8, 256, 0, stream>>>(srcb, offs, deg_i, dinv, (const uint2*)Bs,
                                               b_gcn, (uint2*)Ab, N4);
  hipMemsetAsync(bnsum, 0, 1024 * sizeof(float), stream);
  bn_stats<<<dim3(400, 4), 256, 0, stream>>>((const unsigned*)Ab, bnsum, N);
  bn_final<<<1, 512, 0, stream>>>(bnsum, bn_gamma, bn_beta, bnss, N);
  rels_update<<<1, 512, 0, stream>>>(rels, W_rt, b_rt, rels + 512);

  // ---- Layer 1 (fused BN-update, writeback emb1) ----
  scale_w_bf<<<256, 256, 0, stream>>>(rels + 512, W_gcn + (size_t)DD * DD, Wgcnb);
  for (int r = 0; r < 4; ++r) resIn.p[r] = Fb;           // emb0 = features (shared)
  gemm_upd<1><<<dim3(gemmGrid, 4), 256, 0, stream>>>(resIn, abIn, wz, xbOut, msgOut,
                                                     bnss, dinv, N);
  gather_agg<<<(N4 + 7) / 8, 256, 0, stream>>>(srcb, offs, deg_i, dinv, (const uint2*)Bs,
                                               b_gcn + DD, (uint2*)Ab, N4);
  hipMemsetAsync(bnsum, 0, 1024 * sizeof(float), stream);
  bn_stats<<<dim3(400, 4), 256, 0, stream>>>((const unsigned*)Ab, bnsum, N);
  bn_final<<<1, 512, 0, stream>>>(bnsum, bn_gamma + DD, bn_beta + DD, bnss, N);
  rels_update<<<1, 512, 0, stream>>>(rels + 512, W_rt + (size_t)DD * DD, b_rt + DD, rels + 1024);

  // ---- Layer 2 (fused BN-update, no writeback) ----
  scale_w_bf<<<256, 256, 0, stream>>>(rels + 1024, W_gcn + (size_t)2 * DD * DD, Wgcnb);
  for (int r = 0; r < 4; ++r) resIn.p[r] = Xb + (size_t)r * NK;   // emb1
  gemm_upd<0><<<dim3(gemmGrid, 4), 256, 0, stream>>>(resIn, abIn, wz, dummyO, msgOut,
                                                     bnss, dinv, N);
  gather_agg<<<(N4 + 7) / 8, 256, 0, stream>>>(srcb, offs, deg_i, dinv, (const uint2*)Bs,
                                               b_gcn + 2 * DD, (uint2*)Ab, N4);
  rels_update<<<1, 512, 0, stream>>>(rels + 1024, W_rt + (size_t)2 * DD * DD, b_rt + 2 * DD,
                                     rels + 1536);
  // Ab = final GCN outputs (stack source). Xb, Bs, Ub free.

  const int pstk[4] = {3, 0, 2, 1};
  PtrB4 stk;
  for (int l = 0; l < 4; ++l) stk.p[l] = Ab + (size_t)pstk[l] * NK;

  hipMemsetAsync(S, 0, 4 * sizeof(float), stream);
  attn_mega<<<(N + 15) / 16, 256, 0, stream>>>(stk, Wab, attn_b_in, attn_bout, alphas,
                                               fusion_b, fusion_q, Bs, S, N);
  wcoef<<<1, 64, 0, stream>>>(S, coef, N);
  final_out<<<(int)((NK / 4 + 255) / 256), 256, 0, stream>>>(Bs, coef, rels + 1536,
                                                             (float*)d_out, N);
}

// Round 11
// 974.541 us; speedup vs baseline: 1.0377x; 1.0377x over previous
//
#include <hip/hip_runtime.h>
#include <cstdio>

#define DD 128
#define NREL 4

using short8 = __attribute__((ext_vector_type(8))) short;
using f32x4  = __attribute__((ext_vector_type(4))) float;

struct PtrB4 { const unsigned short* p[4]; };
struct OutB4 { unsigned short* p[4]; };

// processing-order relation r uses edge_index/rel_emb row (r+3)&3  (perm = [3,0,1,2])
__device__ __forceinline__ int edge_perm(int r) { return (r + 3) & 3; }

__device__ __forceinline__ float bf_lo(unsigned u) { return __uint_as_float(u << 16); }
__device__ __forceinline__ float bf_hi(unsigned u) { return __uint_as_float(u & 0xffff0000u); }
__device__ __forceinline__ float bfe(short s) {
  return __uint_as_float(((unsigned)(unsigned short)s) << 16);
}
__device__ __forceinline__ unsigned short f2bf(float f) {
  unsigned x = __float_as_uint(f);
  unsigned r = (x + 0x7fffu + ((x >> 16) & 1u)) >> 16;
  return (unsigned short)r;
}
__device__ __forceinline__ unsigned pack2(float a, float b) {
  return (unsigned)f2bf(a) | ((unsigned)f2bf(b) << 16);
}

// swizzled LDS index for 64x136-short tiles: rows 16 apart land on distinct banks
#define SWIDX(row, col) ((row) * 136 + ((col) ^ ((((row) >> 4) & 3) << 4)))

// ---------------- init / weight prep ----------------

__global__ void rels_init(const float* __restrict__ rel_emb, float* __restrict__ rels) {
  int t = threadIdx.x;              // 512 = r*128 + c
  int r = t >> 7, c = t & 127;
  rels[t] = rel_emb[edge_perm(r) * DD + c];
}

__global__ void rels_update(const float* __restrict__ rin, const float* __restrict__ Wrt,
                            const float* __restrict__ brt, float* __restrict__ rout) {
  int t = threadIdx.x;  // 512 = r*128 + j
  int r = t >> 7, j = t & 127;
  float s = brt[j];
  const float* wr = Wrt + j * DD;
  const float* xr = rin + r * DD;
  for (int c = 0; c < DD; ++c) s += xr[c] * wr[c];
  rout[t] = s;
}

// Wsb[r][j][c] = bf16(rels[r][c] * Wg[c][j])  -- MFMA-B layout [n=j][k=c]
__global__ void scale_w_bf(const float* __restrict__ rels_i, const float* __restrict__ Wg,
                           unsigned short* __restrict__ Wsb) {
  int i = blockIdx.x * 256 + threadIdx.x;   // 4*16384
  int r = i >> 14, rem = i & 16383, j = rem >> 7, c = rem & 127;
  Wsb[i] = f2bf(rels_i[r * DD + c] * Wg[c * DD + j]);
}

// Wab = bf16( attn_w_in (3*16384) || attn_wout (16384) || fusion_w (16384) ), all [j][c]
__global__ void conv_w(const float* __restrict__ w_in, const float* __restrict__ w_out,
                       const float* __restrict__ w_fus, unsigned short* __restrict__ Wab) {
  int i = blockIdx.x * 256 + threadIdx.x;   // 5*16384
  float v = (i < 49152) ? w_in[i] : (i < 65536 ? w_out[i - 49152] : w_fus[i - 65536]);
  Wab[i] = f2bf(v);
}

// fp32 -> bf16 single slice
__global__ void conv_f2b(const float* __restrict__ in, unsigned* __restrict__ out2, size_t n4) {
  size_t i = (size_t)blockIdx.x * 256 + threadIdx.x;
  if (i < n4) {
    float4 v = ((const float4*)in)[i];
    out2[i * 2]     = pack2(v.x, v.y);
    out2[i * 2 + 1] = pack2(v.z, v.w);
  }
}

// ---------------- CSR build ----------------

__global__ void count_deg(const int* __restrict__ ei, int* __restrict__ deg, int N, int E) {
  int r = blockIdx.y;
  int base = blockIdx.x * 1024 + threadIdx.x;
  const int* dsts = ei + (size_t)edge_perm(r) * 2 * E + E;
#pragma unroll
  for (int k = 0; k < 4; ++k) {
    int e = base + k * 256;
    if (e < E) atomicAdd(deg + (size_t)r * N + dsts[e], 1);
  }
}

__global__ void finalize_dinv(const int* __restrict__ deg, float* __restrict__ dinv, int total) {
  int i = blockIdx.x * 256 + threadIdx.x;
  if (i < total) dinv[i] = rsqrtf((float)deg[i] + 1.0f);
}

__global__ void scan_block(const int* __restrict__ deg, int* __restrict__ excl,
                           int* __restrict__ bsums, int n) {
  __shared__ int sh[256];
  int i = blockIdx.x * 256 + threadIdx.x;
  int v = (i < n) ? deg[i] : 0;
  sh[threadIdx.x] = v;
  __syncthreads();
  for (int st = 1; st < 256; st <<= 1) {
    int t = (threadIdx.x >= st) ? sh[threadIdx.x - st] : 0;
    __syncthreads();
    sh[threadIdx.x] += t;
    __syncthreads();
  }
  if (i < n) excl[i] = sh[threadIdx.x] - v;
  if (threadIdx.x == 255) bsums[blockIdx.x] = sh[255];
}

__global__ void scan_sums(int* __restrict__ bsums, int nb) {
  __shared__ int sh[1024];
  int v = (threadIdx.x < nb) ? bsums[threadIdx.x] : 0;
  sh[threadIdx.x] = v;
  __syncthreads();
  for (int st = 1; st < 1024; st <<= 1) {
    int t = (threadIdx.x >= st) ? sh[threadIdx.x - st] : 0;
    __syncthreads();
    sh[threadIdx.x] += t;
    __syncthreads();
  }
  if (threadIdx.x < nb) bsums[threadIdx.x] = sh[threadIdx.x] - v;  // exclusive
}

__global__ void scan_add(int* __restrict__ excl, int* __restrict__ cursor,
                         const int* __restrict__ bsums, int n) {
  int i = blockIdx.x * 256 + threadIdx.x;
  if (i < n) {
    int o = excl[i] + bsums[blockIdx.x];
    excl[i] = o;
    cursor[i] = o;
  }
}

// 4 edges/thread: 4 independent atomic-returns in flight
__global__ void fill_edges(const int* __restrict__ ei, int* __restrict__ cursor,
                           int* __restrict__ srcbuf, int N, int E) {
  int r = blockIdx.y;
  int base = blockIdx.x * 1024 + threadIdx.x;
  const int* bp = ei + (size_t)edge_perm(r) * 2 * E;
  int s[4], d[4], pos[4];
#pragma unroll
  for (int k = 0; k < 4; ++k) {
    int e = base + k * 256;
    s[k] = (e < E) ? bp[e] : 0;
    d[k] = (e < E) ? bp[E + e] : 0;
  }
#pragma unroll
  for (int k = 0; k < 4; ++k) {
    int e = base + k * 256;
    if (e < E) pos[k] = atomicAdd(&cursor[r * N + d[k]], 1);
  }
#pragma unroll
  for (int k = 0; k < 4; ++k) {
    int e = base + k * 256;
    if (e < E) srcbuf[pos[k]] = r * N + s[k];
  }
}

// ---------------- weight-stationary MFMA GEMM (round-7 proven) ----------------
// Block 256 = 4 waves: wave = (rowhalf<<1)|colhalf; each wave: 32 rows x 64 cols.
// MODE 0: out bf16 = y * dinv[z*M+row]           (GCN messages)
template <int MODE>
__global__ __launch_bounds__(256) void gemm_ws(PtrB4 xs, PtrB4 wz, OutB4 ys,
                                               const float* __restrict__ bias,
                                               const float* __restrict__ dinv, int M) {
  int z = blockIdx.y;
  const unsigned short* __restrict__ X = xs.p[z];
  const unsigned short* __restrict__ W = wz.p[z];
  int tid = threadIdx.x;
  int wave = tid >> 6, lane = tid & 63;
  int r16 = lane & 15, kgrp = lane >> 4;
  int rowhalf = wave >> 1, colbase = (wave & 1) * 64;
  int blockrow = blockIdx.x * 64;

  short8 b[4][4];
#pragma unroll
  for (int s = 0; s < 4; ++s)
#pragma unroll
    for (int cn = 0; cn < 4; ++cn)
      b[s][cn] = *(const short8*)(W + ((colbase + cn * 16 + r16) << 7) + s * 32 + kgrp * 8);

  int row0 = blockrow + rowhalf * 32 + r16;
  int r0c = row0 < M ? row0 : M - 1;
  int r1c = row0 + 16 < M ? row0 + 16 : M - 1;
  short8 a[2][4];
#pragma unroll
  for (int s = 0; s < 4; ++s) {
    a[0][s] = *(const short8*)(X + (size_t)r0c * DD + s * 32 + kgrp * 8);
    a[1][s] = *(const short8*)(X + (size_t)r1c * DD + s * 32 + kgrp * 8);
  }

  f32x4 acc[2][4];
#pragma unroll
  for (int rt = 0; rt < 2; ++rt)
#pragma unroll
    for (int cn = 0; cn < 4; ++cn)
#pragma unroll
      for (int j = 0; j < 4; ++j) acc[rt][cn][j] = 0.f;

#pragma unroll
  for (int s = 0; s < 4; ++s)
#pragma unroll
    for (int rt = 0; rt < 2; ++rt)
#pragma unroll
      for (int cn = 0; cn < 4; ++cn)
        acc[rt][cn] = __builtin_amdgcn_mfma_f32_16x16x32_bf16(a[rt][s], b[s][cn], acc[rt][cn], 0, 0, 0);

  __shared__ __align__(16) unsigned short tile[64][DD + 8];
  float dv[2][4];
  if constexpr (MODE == 0) {
#pragma unroll
    for (int rt = 0; rt < 2; ++rt)
#pragma unroll
      for (int i = 0; i < 4; ++i) {
        int row = blockrow + rowhalf * 32 + rt * 16 + kgrp * 4 + i;
        dv[rt][i] = dinv[(size_t)z * M + (row < M ? row : 0)];
      }
  }
#pragma unroll
  for (int rt = 0; rt < 2; ++rt)
#pragma unroll
    for (int cn = 0; cn < 4; ++cn) {
      int col = colbase + cn * 16 + r16;
#pragma unroll
      for (int i = 0; i < 4; ++i) {
        int wrow = rowhalf * 32 + rt * 16 + kgrp * 4 + i;
        float y = acc[rt][cn][i];
        if constexpr (MODE == 0) y *= dv[rt][i];
        tile[wrow][col] = f2bf(y);
      }
    }
  __syncthreads();
  int orow = tid >> 2, seg = tid & 3;
  int grow = blockrow + orow;
  if (grow < M) {
    unsigned short* Yp = ys.p[z] + (size_t)grow * DD + seg * 32;
    const unsigned short* tp = &tile[orow][seg * 32];
#pragma unroll
    for (int k = 0; k < 4; ++k)
      *(uint4*)(Yp + k * 8) = *(const uint4*)(tp + k * 8);
  }
}

// Layers 1/2 fused GEMM (round-7 proven): e = res + leaky(bn(Ab)); optional writeback;
// messages = (e@Wz)*dinv
template <int WB>
__global__ __launch_bounds__(256) void gemm_upd(PtrB4 res, PtrB4 abs_, PtrB4 wz,
                                                OutB4 xout, OutB4 ys,
                                                const float* __restrict__ ssx,
                                                const float* __restrict__ dinv, int M) {
  int z = blockIdx.y;
  const unsigned short* __restrict__ R = res.p[z];
  const unsigned short* __restrict__ A = abs_.p[z];
  const unsigned short* __restrict__ W = wz.p[z];
  int tid = threadIdx.x;

  __shared__ float ssc[DD], ssh[DD];
  if (tid < DD) {
    ssc[tid] = ssx[((size_t)z * DD + tid) * 2];
    ssh[tid] = ssx[((size_t)z * DD + tid) * 2 + 1];
  }
  __syncthreads();

  int wave = tid >> 6, lane = tid & 63;
  int r16 = lane & 15, kgrp = lane >> 4;
  int rowhalf = wave >> 1, colbase = (wave & 1) * 64;
  int blockrow = blockIdx.x * 64;

  short8 b[4][4];
#pragma unroll
  for (int s = 0; s < 4; ++s)
#pragma unroll
    for (int cn = 0; cn < 4; ++cn)
      b[s][cn] = *(const short8*)(W + ((colbase + cn * 16 + r16) << 7) + s * 32 + kgrp * 8);

  int row0 = blockrow + rowhalf * 32 + r16;
  int rc[2];
  rc[0] = row0 < M ? row0 : M - 1;
  rc[1] = row0 + 16 < M ? row0 + 16 : M - 1;
  short8 a[2][4];
#pragma unroll
  for (int rt = 0; rt < 2; ++rt)
#pragma unroll
    for (int s = 0; s < 4; ++s) {
      int cbase = s * 32 + kgrp * 8;
      short8 rv = *(const short8*)(R + (size_t)rc[rt] * DD + cbase);
      short8 av = *(const short8*)(A + (size_t)rc[rt] * DD + cbase);
      short8 av2;
#pragma unroll
      for (int j = 0; j < 8; ++j) {
        float x = bfe(av[j]) * ssc[cbase + j] + ssh[cbase + j];
        x = x > 0.f ? x : 0.01f * x;
        av2[j] = (short)f2bf(bfe(rv[j]) + x);
      }
      a[rt][s] = av2;
    }
  if (WB) {
#pragma unroll
    for (int rt = 0; rt < 2; ++rt) {
      int row = row0 + rt * 16;
      if (row < M) {
#pragma unroll
        for (int s = 0; s < 4; ++s)
          *(short8*)(xout.p[z] + (size_t)row * DD + s * 32 + kgrp * 8) = a[rt][s];
      }
    }
  }

  f32x4 acc[2][4];
#pragma unroll
  for (int rt = 0; rt < 2; ++rt)
#pragma unroll
    for (int cn = 0; cn < 4; ++cn)
#pragma unroll
      for (int j = 0; j < 4; ++j) acc[rt][cn][j] = 0.f;
#pragma unroll
  for (int s = 0; s < 4; ++s)
#pragma unroll
    for (int rt = 0; rt < 2; ++rt)
#pragma unroll
      for (int cn = 0; cn < 4; ++cn)
        acc[rt][cn] = __builtin_amdgcn_mfma_f32_16x16x32_bf16(a[rt][s], b[s][cn], acc[rt][cn], 0, 0, 0);

  __shared__ __align__(16) unsigned short tile[64][DD + 8];
  float dv[2][4];
#pragma unroll
  for (int rt = 0; rt < 2; ++rt)
#pragma unroll
    for (int i = 0; i < 4; ++i) {
      int row = blockrow + rowhalf * 32 + rt * 16 + kgrp * 4 + i;
      dv[rt][i] = dinv[(size_t)z * M + (row < M ? row : 0)];
    }
#pragma unroll
  for (int rt = 0; rt < 2; ++rt)
#pragma unroll
    for (int cn = 0; cn < 4; ++cn) {
      int col = colbase + cn * 16 + r16;
#pragma unroll
      for (int i = 0; i < 4; ++i) {
        int wrow = rowhalf * 32 + rt * 16 + kgrp * 4 + i;
        tile[wrow][col] = f2bf(acc[rt][cn][i] * dv[rt][i]);
      }
    }
  __syncthreads();
  int orow = tid >> 2, seg = tid & 3;
  int grow = blockrow + orow;
  if (grow < M) {
    unsigned short* Yp = ys.p[z] + (size_t)grow * DD + seg * 32;
    const unsigned short* tp = &tile[orow][seg * 32];
#pragma unroll
    for (int k = 0; k < 4; ++k)
      *(uint4*)(Yp + k * 8) = *(const uint4*)(tp + k * 8);
  }
}

// ---------------- mega-fused attention phase (v3: 2 LDS arrays, no spills) ----------------
// One block = 16 nodes. Rows r in [0,64): layer l = r>>4, node = nodebase + (r&15).
// Phases: Q->q_s,K->k_s | scores -> p regs | V->q_s (A reloaded from stk, L3-hot) |
//         PV: O->k_s | proj -> q_s | blend (f->global+q_s) | fusion GEMM + reduce.
// LDS 34.8 KB -> 4 blocks/CU; no forced VGPR clamp (spills were r10's regression).
__global__ __launch_bounds__(256) void attn_mega(PtrB4 stks,
    const unsigned short* __restrict__ Wab,
    const float* __restrict__ b_in, const float* __restrict__ b_out,
    const float* __restrict__ alphas, const float* __restrict__ fus_b,
    const float* __restrict__ fq, unsigned short* __restrict__ fbuf,
    float* __restrict__ S, int N) {
  __shared__ __align__(16) unsigned short q_s[64 * 136];  // Q -> V -> proj -> f
  __shared__ __align__(16) unsigned short k_s[64 * 136];  // K -> O
  __shared__ float lred[4];
  size_t NK = (size_t)N * DD;

  int tid = threadIdx.x;
  int wave = tid >> 6, lane = tid & 63;
  int r16 = lane & 15, kgrp = lane >> 4;
  int rowhalf = wave >> 1, colbase = (wave & 1) * 64;
  int nodebase = blockIdx.x * 16;

  int rlo = rowhalf * 32 + r16;     // 0..63
  int rhi = rlo + 16;
  int nlo = nodebase + (rlo & 15); if (nlo >= N) nlo = N - 1;
  int nhi = nodebase + (rhi & 15); if (nhi >= N) nhi = N - 1;
  const unsigned short* a0p = stks.p[rlo >> 4] + (size_t)nlo * DD + kgrp * 8;
  const unsigned short* a1p = stks.p[rhi >> 4] + (size_t)nhi * DD + kgrp * 8;

  // ---- Q -> q_s, K -> k_s (A loaded fresh, dies at end of this phase) ----
  {
    short8 A0[4], A1[4];
#pragma unroll
    for (int s = 0; s < 4; ++s) {
      A0[s] = *(const short8*)(a0p + s * 32);
      A1[s] = *(const short8*)(a1p + s * 32);
    }
    for (int o = 0; o < 2; ++o) {
      const unsigned short* W = Wab + o * 16384;
      short8 b[4][4];
#pragma unroll
      for (int s = 0; s < 4; ++s)
#pragma unroll
        for (int cn = 0; cn < 4; ++cn)
          b[s][cn] = *(const short8*)(W + ((colbase + cn * 16 + r16) << 7) + s * 32 + kgrp * 8);
      f32x4 acc[2][4];
#pragma unroll
      for (int rt = 0; rt < 2; ++rt)
#pragma unroll
        for (int cn = 0; cn < 4; ++cn)
#pragma unroll
          for (int j = 0; j < 4; ++j) acc[rt][cn][j] = 0.f;
#pragma unroll
      for (int s = 0; s < 4; ++s)
#pragma unroll
        for (int cn = 0; cn < 4; ++cn) {
          acc[0][cn] = __builtin_amdgcn_mfma_f32_16x16x32_bf16(A0[s], b[s][cn], acc[0][cn], 0, 0, 0);
          acc[1][cn] = __builtin_amdgcn_mfma_f32_16x16x32_bf16(A1[s], b[s][cn], acc[1][cn], 0, 0, 0);
        }
      unsigned short* dst = (o == 0) ? q_s : k_s;
#pragma unroll
      for (int rt = 0; rt < 2; ++rt)
#pragma unroll
        for (int cn = 0; cn < 4; ++cn) {
          int col = colbase + cn * 16 + r16;
          float bb = b_in[o * DD + col];
#pragma unroll
          for (int i = 0; i < 4; ++i) {
            int wrow = rowhalf * 32 + rt * 16 + kgrp * 4 + i;
            dst[SWIDX(wrow, col)] = f2bf(acc[rt][cn][i] + bb);
          }
        }
    }
  }
  __syncthreads();

  // ---- scores -> p[4] regs (wave owns nodes wave*4..+3) ----
  float p[4];
  {
    int h = lane >> 4, li = (lane >> 2) & 3, m = lane & 3;
    for (int t = 0; t < 4; ++t) {
      int nd = wave * 4 + t;
      float sc = 0.f;
#pragma unroll
      for (int s4 = 0; s4 < 4; ++s4) {
        short8 qv = *(const short8*)&q_s[SWIDX(li * 16 + nd, h * 32 + s4 * 8)];
        short8 kv = *(const short8*)&k_s[SWIDX(m * 16 + nd, h * 32 + s4 * 8)];
#pragma unroll
        for (int j = 0; j < 8; ++j) sc += bfe(qv[j]) * bfe(kv[j]);
      }
      sc *= 0.17677669529663687f;              // 1/sqrt(32)
      float mx = sc;
      mx = fmaxf(mx, __shfl_xor(mx, 1));
      mx = fmaxf(mx, __shfl_xor(mx, 2));
      float e = expf(sc - mx);
      float sum = e;
      sum += __shfl_xor(sum, 1);
      sum += __shfl_xor(sum, 2);
      p[t] = e / sum;                          // lane holds p[h][li][m] for node nd
    }
  }
  __syncthreads();   // all score reads done before V overwrites q_s

  // ---- V -> q_s (A reloaded from stk: L3-hot, avoids cross-phase live range) ----
  {
    short8 A0[4], A1[4];
#pragma unroll
    for (int s = 0; s < 4; ++s) {
      A0[s] = *(const short8*)(a0p + s * 32);
      A1[s] = *(const short8*)(a1p + s * 32);
    }
    const unsigned short* W = Wab + 2 * 16384;
    short8 b[4][4];
#pragma unroll
    for (int s = 0; s < 4; ++s)
#pragma unroll
      for (int cn = 0; cn < 4; ++cn)
        b[s][cn] = *(const short8*)(W + ((colbase + cn * 16 + r16) << 7) + s * 32 + kgrp * 8);
    f32x4 acc[2][4];
#pragma unroll
    for (int rt = 0; rt < 2; ++rt)
#pragma unroll
      for (int cn = 0; cn < 4; ++cn)
#pragma unroll
        for (int j = 0; j < 4; ++j) acc[rt][cn][j] = 0.f;
#pragma unroll
    for (int s = 0; s < 4; ++s)
#pragma unroll
      for (int cn = 0; cn < 4; ++cn) {
        acc[0][cn] = __builtin_amdgcn_mfma_f32_16x16x32_bf16(A0[s], b[s][cn], acc[0][cn], 0, 0, 0);
        acc[1][cn] = __builtin_amdgcn_mfma_f32_16x16x32_bf16(A1[s], b[s][cn], acc[1][cn], 0, 0, 0);
      }
#pragma unroll
    for (int rt = 0; rt < 2; ++rt)
#pragma unroll
      for (int cn = 0; cn < 4; ++cn) {
        int col = colbase + cn * 16 + r16;
        float bb = b_in[2 * DD + col];
#pragma unroll
        for (int i = 0; i < 4; ++i) {
          int wrow = rowhalf * 32 + rt * 16 + kgrp * 4 + i;
          q_s[SWIDX(wrow, col)] = f2bf(acc[rt][cn][i] + bb);
        }
      }
  }
  __syncthreads();

  // ---- PV: O -> k_s (p distributed via shuffles; wave-local nodes) ----
  {
    int c0 = lane * 2, hh = lane >> 4;   // hh = c0>>5
    for (int t = 0; t < 4; ++t) {
      int nd = wave * 4 + t;
      unsigned v[4];
#pragma unroll
      for (int m = 0; m < 4; ++m)
        v[m] = *(const unsigned*)&q_s[SWIDX(m * 16 + nd, c0)];
#pragma unroll
      for (int lo = 0; lo < 4; ++lo) {
        float ol = 0.f, oh = 0.f;
#pragma unroll
        for (int m = 0; m < 4; ++m) {
          float pm = __shfl(p[t], hh * 16 + lo * 4 + m);
          ol += pm * bf_lo(v[m]);
          oh += pm * bf_hi(v[m]);
        }
        *(unsigned*)&k_s[SWIDX(lo * 16 + nd, c0)] = pack2(ol, oh);
      }
    }
  }
  __syncthreads();

  // ---- out-proj: A = O (k_s) -> q_s holds y + b_out ----
  {
    const unsigned short* W = Wab + 3 * 16384;
    short8 b[4][4];
#pragma unroll
    for (int s = 0; s < 4; ++s)
#pragma unroll
      for (int cn = 0; cn < 4; ++cn)
        b[s][cn] = *(const short8*)(W + ((colbase + cn * 16 + r16) << 7) + s * 32 + kgrp * 8);
    short8 AO0[4], AO1[4];
#pragma unroll
    for (int s = 0; s < 4; ++s) {
      AO0[s] = *(const short8*)&k_s[SWIDX(rlo, s * 32 + kgrp * 8)];
      AO1[s] = *(const short8*)&k_s[SWIDX(rhi, s * 32 + kgrp * 8)];
    }
    f32x4 acc[2][4];
#pragma unroll
    for (int rt = 0; rt < 2; ++rt)
#pragma unroll
      for (int cn = 0; cn < 4; ++cn)
#pragma unroll
        for (int j = 0; j < 4; ++j) acc[rt][cn][j] = 0.f;
#pragma unroll
    for (int s = 0; s < 4; ++s)
#pragma unroll
      for (int cn = 0; cn < 4; ++cn) {
        acc[0][cn] = __builtin_amdgcn_mfma_f32_16x16x32_bf16(AO0[s], b[s][cn], acc[0][cn], 0, 0, 0);
        acc[1][cn] = __builtin_amdgcn_mfma_f32_16x16x32_bf16(AO1[s], b[s][cn], acc[1][cn], 0, 0, 0);
      }
#pragma unroll
    for (int rt = 0; rt < 2; ++rt)
#pragma unroll
      for (int cn = 0; cn < 4; ++cn) {
        int col = colbase + cn * 16 + r16;
        float bb = b_out[col];
#pragma unroll
        for (int i = 0; i < 4; ++i) {
          int wrow = rowhalf * 32 + rt * 16 + kgrp * 4 + i;
          q_s[SWIDX(wrow, col)] = f2bf(acc[rt][cn][i] + bb);
        }
      }
  }
  __syncthreads();

  // ---- blend with stk, store f to global, write back to q_s ----
  {
    int orow = tid >> 2, seg = tid & 3;
    int lb = orow >> 4, nb = nodebase + (orow & 15);
    if (nb < N) {
      float aa = alphas[lb], na = 1.f - aa;
      const unsigned short* sp = stks.p[lb] + (size_t)nb * DD + seg * 32;
      unsigned short* Yp = fbuf + (size_t)lb * NK + (size_t)nb * DD + seg * 32;
#pragma unroll
      for (int k = 0; k < 4; ++k) {
        unsigned short* tp = &q_s[SWIDX(orow, seg * 32 + k * 8)];
        uint4 pv = *(const uint4*)tp;
        uint4 sv = *(const uint4*)(sp + k * 8);
        const unsigned* pw = &pv.x;
        const unsigned* sw = &sv.x;
        uint4 o; unsigned* ow = &o.x;
#pragma unroll
        for (int j = 0; j < 4; ++j)
          ow[j] = pack2(aa * bf_lo(pw[j]) + na * bf_lo(sw[j]),
                        aa * bf_hi(pw[j]) + na * bf_hi(sw[j]));
        *(uint4*)(Yp + k * 8) = o;
        *(uint4*)tp = o;
      }
    }
  }
  __syncthreads();

  // ---- fusion GEMM on f (q_s) + leaky*fq score reduce ----
  {
    const unsigned short* W = Wab + 4 * 16384;
    short8 b[4][4];
#pragma unroll
    for (int s = 0; s < 4; ++s)
#pragma unroll
      for (int cn = 0; cn < 4; ++cn)
        b[s][cn] = *(const short8*)(W + ((colbase + cn * 16 + r16) << 7) + s * 32 + kgrp * 8);
    short8 AF0[4], AF1[4];
#pragma unroll
    for (int s = 0; s < 4; ++s) {
      AF0[s] = *(const short8*)&q_s[SWIDX(rlo, s * 32 + kgrp * 8)];
      AF1[s] = *(const short8*)&q_s[SWIDX(rhi, s * 32 + kgrp * 8)];
    }
    f32x4 acc[2][4];
#pragma unroll
    for (int rt = 0; rt < 2; ++rt)
#pragma unroll
      for (int cn = 0; cn < 4; ++cn)
#pragma unroll
        for (int j = 0; j < 4; ++j) acc[rt][cn][j] = 0.f;
#pragma unroll
    for (int s = 0; s < 4; ++s)
#pragma unroll
      for (int cn = 0; cn < 4; ++cn) {
        acc[0][cn] = __builtin_amdgcn_mfma_f32_16x16x32_bf16(AF0[s], b[s][cn], acc[0][cn], 0, 0, 0);
        acc[1][cn] = __builtin_amdgcn_mfma_f32_16x16x32_bf16(AF1[s], b[s][cn], acc[1][cn], 0, 0, 0);
      }
    float ss0 = 0.f, ss1 = 0.f;
#pragma unroll
    for (int cn = 0; cn < 4; ++cn) {
      int col = colbase + cn * 16 + r16;
      float bb = fus_b[col];
      float qc = fq[col];
#pragma unroll
      for (int i = 0; i < 4; ++i) {
        if (nodebase + kgrp * 4 + i < N) {
          float y0 = acc[0][cn][i] + bb;
          float y1 = acc[1][cn][i] + bb;
          ss0 += (y0 > 0.f ? y0 : 0.01f * y0) * qc;
          ss1 += (y1 > 0.f ? y1 : 0.01f * y1) * qc;
        }
      }
    }
    if (tid < 4) lred[tid] = 0.f;
    __syncthreads();
    atomicAdd(&lred[rowhalf * 2], ss0);
    atomicAdd(&lred[rowhalf * 2 + 1], ss1);
    __syncthreads();
    if (tid < 4) atomicAdd(S + tid, lred[tid]);
  }
}

// ---------------- GCN aggregation: CSR gather, 2 nodes/wave, unroll x8 ----------------
__global__ __launch_bounds__(256) void gather_agg(const int* __restrict__ srcbuf,
                                                  const int* __restrict__ offs,
                                                  const int* __restrict__ deg,
                                                  const float* __restrict__ dinv,
                                                  const uint2* __restrict__ Bs2,
                                                  const float* __restrict__ bias,
                                                  uint2* __restrict__ Ab2, int N4) {
  int rn = blockIdx.x * 8 + (threadIdx.x >> 5);
  if (rn >= N4) return;
  int lane = threadIdx.x & 31;
  int st = offs[rn], cnt = deg[rn];
  uint2 u = Bs2[(size_t)rn * 32 + lane];        // self message
  float a0 = bf_lo(u.x), a1 = bf_hi(u.x), a2 = bf_lo(u.y), a3 = bf_hi(u.y);
  int e = 0;
  for (; e + 8 <= cnt; e += 8) {
    int rr[8];
#pragma unroll
    for (int j = 0; j < 8; ++j) rr[j] = srcbuf[st + e + j];
    uint2 vv[8];
#pragma unroll
    for (int j = 0; j < 8; ++j) vv[j] = Bs2[(size_t)rr[j] * 32 + lane];
#pragma unroll
    for (int j = 0; j < 8; ++j) {
      a0 += bf_lo(vv[j].x); a1 += bf_hi(vv[j].x);
      a2 += bf_lo(vv[j].y); a3 += bf_hi(vv[j].y);
    }
  }
  if (e + 4 <= cnt) {
    int rr[4];
#pragma unroll
    for (int j = 0; j < 4; ++j) rr[j] = srcbuf[st + e + j];
    uint2 vv[4];
#pragma unroll
    for (int j = 0; j < 4; ++j) vv[j] = Bs2[(size_t)rr[j] * 32 + lane];
#pragma unroll
    for (int j = 0; j < 4; ++j) {
      a0 += bf_lo(vv[j].x); a1 += bf_hi(vv[j].x);
      a2 += bf_lo(vv[j].y); a3 += bf_hi(vv[j].y);
    }
    e += 4;
  }
  for (; e < cnt; ++e) {
    uint2 v = Bs2[(size_t)srcbuf[st + e] * 32 + lane];
    a0 += bf_lo(v.x); a1 += bf_hi(v.x); a2 += bf_lo(v.y); a3 += bf_hi(v.y);
  }
  float dvv = dinv[rn];
  int c = lane * 4;
  uint2 o;
  o.x = pack2(a0 * dvv + bias[c],     a1 * dvv + bias[c + 1]);
  o.y = pack2(a2 * dvv + bias[c + 2], a3 * dvv + bias[c + 3]);
  Ab2[(size_t)rn * 32 + lane] = o;
}

// ---------------- batchnorm ----------------

__global__ void bn_stats(const unsigned* __restrict__ Ab2, float* __restrict__ sums, int N) {
  int r = blockIdx.y;
  int lane = threadIdx.x & 63, grp = threadIdx.x >> 6;
  float s0 = 0.f, q0 = 0.f, s1 = 0.f, q1 = 0.f;
  const unsigned* base = Ab2 + (size_t)r * N * 64;
  for (int n = blockIdx.x * 4 + grp; n < N; n += gridDim.x * 4) {
    unsigned u = base[(size_t)n * 64 + lane];
    float a = bf_lo(u), b = bf_hi(u);
    s0 += a; q0 += a * a; s1 += b; q1 += b * b;
  }
  __shared__ float sh[4][64][4];
  sh[grp][lane][0] = s0; sh[grp][lane][1] = q0; sh[grp][lane][2] = s1; sh[grp][lane][3] = q1;
  __syncthreads();
  if (grp == 0) {
#pragma unroll
    for (int g = 1; g < 4; ++g) {
      s0 += sh[g][lane][0]; q0 += sh[g][lane][1]; s1 += sh[g][lane][2]; q1 += sh[g][lane][3];
    }
    int c0 = lane * 2;
    atomicAdd(sums + (r * DD + c0) * 2, s0);
    atomicAdd(sums + (r * DD + c0) * 2 + 1, q0);
    atomicAdd(sums + (r * DD + c0 + 1) * 2, s1);
    atomicAdd(sums + (r * DD + c0 + 1) * 2 + 1, q1);
  }
}

__global__ void bn_final(const float* __restrict__ sums, const float* __restrict__ gamma,
                         const float* __restrict__ beta, float* __restrict__ ss, int N) {
  int t = threadIdx.x;       // 512 = r*128+c
  int c = t & 127;
  float mu = sums[t * 2] / N;
  float var = sums[t * 2 + 1] / N - mu * mu;
  float sc = gamma[c] * rsqrtf(var + 1e-5f);
  ss[t * 2] = sc;
  ss[t * 2 + 1] = beta[c] - mu * sc;
}

// w = softmax([S(f0),S(f1),S(f3),S(f2)]);  coef[l] multiplies f[l]: coef = [w0,w1,w3,w2]
__global__ void wcoef(const float* __restrict__ S, float* __restrict__ coef, int N) {
  if (threadIdx.x == 0) {
    float v0 = S[0] / N, v1 = S[1] / N, v2 = S[3] / N, v3 = S[2] / N;
    float mx = fmaxf(fmaxf(v0, v1), fmaxf(v2, v3));
    float e0 = expf(v0 - mx), e1 = expf(v1 - mx), e2 = expf(v2 - mx), e3 = expf(v3 - mx);
    float inv = 1.f / (e0 + e1 + e2 + e3);
    coef[0] = e0 * inv; coef[1] = e1 * inv; coef[2] = e3 * inv; coef[3] = e2 * inv;
  }
}

__device__ __forceinline__ float bfat(uint2 u, int j) {
  unsigned w = (j < 2) ? u.x : u.y;
  return (j & 1) ? bf_hi(w) : bf_lo(w);
}

// region = sum coef[l]*f[l]; outputs: region, region*rels3[{3,0,1,2}]
__global__ void final_out(const unsigned short* __restrict__ fb, const float* __restrict__ coef,
                          const float* __restrict__ rels3, float* __restrict__ out, int N) {
  size_t NK = (size_t)N * DD;
  size_t i4 = (size_t)blockIdx.x * 256 + threadIdx.x;  // 4-elem groups
  if (i4 >= NK / 4) return;
  size_t g = i4 * 4;
  int c = (int)(g & 127);
  float c0 = coef[0], c1 = coef[1], c2 = coef[2], c3 = coef[3];
  uint2 u0 = *(const uint2*)(fb + g);
  uint2 u1 = *(const uint2*)(fb + NK + g);
  uint2 u2 = *(const uint2*)(fb + 2 * NK + g);
  uint2 u3 = *(const uint2*)(fb + 3 * NK + g);
  float4 reg4, o1, o2, o3, o4;
  float* rp = &reg4.x; float* p1 = &o1.x; float* p2 = &o2.x; float* p3 = &o3.x; float* p4 = &o4.x;
#pragma unroll
  for (int j = 0; j < 4; ++j) {
    float region = c0 * bfat(u0, j) + c1 * bfat(u1, j) + c2 * bfat(u2, j) + c3 * bfat(u3, j);
    rp[j] = region;
    p1[j] = region * rels3[3 * DD + c + j];
    p2[j] = region * rels3[0 * DD + c + j];
    p3[j] = region * rels3[1 * DD + c + j];
    p4[j] = region * rels3[2 * DD + c + j];
  }
  *(float4*)(out + g) = reg4;
  *(float4*)(out + NK + g) = o1;
  *(float4*)(out + 2 * NK + g) = o2;
  *(float4*)(out + 3 * NK + g) = o3;
  *(float4*)(out + 4 * NK + g) = o4;
}

// ---------------- host ----------------

extern "C" void kernel_launch(void* const* d_in, const int* in_sizes, int n_in,
                              void* d_out, int out_size, void* d_ws, size_t ws_size,
                              hipStream_t stream) {
  const float* features  = (const float*)d_in[0];
  const float* rel_emb   = (const float*)d_in[1];
  const int*   edge_idx  = (const int*)d_in[2];
  const float* W_gcn     = (const float*)d_in[3];
  const float* b_gcn     = (const float*)d_in[4];
  const float* bn_gamma  = (const float*)d_in[5];
  const float* bn_beta   = (const float*)d_in[6];
  const float* W_rt      = (const float*)d_in[7];
  const float* b_rt      = (const float*)d_in[8];
  const float* attn_w_in = (const float*)d_in[9];
  const float* attn_b_in = (const float*)d_in[10];
  const float* attn_wout = (const float*)d_in[11];
  const float* attn_bout = (const float*)d_in[12];
  const float* alphas    = (const float*)d_in[13];
  const float* fusion_q  = (const float*)d_in[14];
  const float* fusion_w  = (const float*)d_in[15];
  const float* fusion_b  = (const float*)d_in[16];

  int N = in_sizes[0] / DD;                  // 50000
  int E = in_sizes[2] / (2 * NREL);          // 400000
  size_t NK = (size_t)N * DD;
  int N4 = 4 * N;

  unsigned short* Xb = (unsigned short*)d_ws;            // 4*NK (emb1)
  unsigned short* Bs = Xb + 4 * NK;                      // 4*NK (messages / f)
  unsigned short* Ab = Bs + 4 * NK;                      // 4*NK (agg / stack)
  unsigned short* Ub = Ab + 4 * NK;                      // 4*NK (spare)
  unsigned short* Fb = Ub + 4 * NK;                      // NK (bf16 features, shared)
  float* dinv  = (float*)(Fb + NK);                      // 4*N
  unsigned short* Wgcnb = (unsigned short*)(dinv + N4);  // 4*16384
  unsigned short* Wab   = Wgcnb + 4 * DD * DD;           // 5*16384
  float* rels  = (float*)(Wab + 5 * DD * DD);            // 4 stages * 512
  float* bnsum = rels + 4 * 512;                         // 1024
  float* bnss  = bnsum + 1024;                           // 1024
  float* S     = bnss + 1024;                            // 4
  float* coef  = S + 4;                                  // 4
  int* deg_i   = (int*)(coef + 4);                       // 4*N
  int* offs    = deg_i + N4;                             // 4*N
  int* cur     = offs + N4;                              // 4*N
  int* bsums   = cur + N4;                               // 1024
  int* srcb    = bsums + 1024;                           // 4*E

  size_t needed = (size_t)((char*)(srcb + 4 * E) - (char*)d_ws);
  if (ws_size < needed) {
    fprintf(stderr, "kernel_launch: ws too small (%zu < %zu)\n", ws_size, needed);
    return;
  }

  int gemmGrid = (N + 63) / 64;
  int scanBlocks = (N4 + 255) / 256;
  int egrid4 = (E + 1023) / 1024;

  // ---- CSR build (edges fixed across layers) ----
  hipMemsetAsync(deg_i, 0, (size_t)N4 * sizeof(int), stream);
  count_deg<<<dim3(egrid4, 4), 256, 0, stream>>>(edge_idx, deg_i, N, E);
  finalize_dinv<<<scanBlocks, 256, 0, stream>>>(deg_i, dinv, N4);
  scan_block<<<scanBlocks, 256, 0, stream>>>(deg_i, offs, bsums, N4);
  scan_sums<<<1, 1024, 0, stream>>>(bsums, scanBlocks);
  scan_add<<<scanBlocks, 256, 0, stream>>>(offs, cur, bsums, N4);
  fill_edges<<<dim3(egrid4, 4), 256, 0, stream>>>(edge_idx, cur, srcb, N, E);

  rels_init<<<1, 512, 0, stream>>>(rel_emb, rels);
  conv_w<<<5 * 16384 / 256, 256, 0, stream>>>(attn_w_in, attn_wout, fusion_w, Wab);
  conv_f2b<<<(int)((NK / 4 + 255) / 256), 256, 0, stream>>>(features, (unsigned*)Fb, NK / 4);

  PtrB4 wz, abIn, resIn;
  OutB4 msgOut, xbOut, dummyO;
  for (int r = 0; r < 4; ++r) {
    wz.p[r] = Wgcnb + (size_t)r * DD * DD;
    abIn.p[r] = Ab + (size_t)r * NK;
    msgOut.p[r] = Bs + (size_t)r * NK;
    xbOut.p[r] = Xb + (size_t)r * NK;
    dummyO.p[r] = nullptr;
  }

  // ---- Layer 0 ----
  scale_w_bf<<<256, 256, 0, stream>>>(rels, W_gcn, Wgcnb);
  {
    PtrB4 xs; for (int r = 0; r < 4; ++r) xs.p[r] = Fb;
    gemm_ws<0><<<dim3(gemmGrid, 4), 256, 0, stream>>>(xs, wz, msgOut, nullptr, dinv, N);
  }
  gather_agg<<<(N4 + 7) / 8, 256, 0, stream>>>(srcb, offs, deg_i, dinv, (const uint2*)Bs,
                                               b_gcn, (uint2*)Ab, N4);
  hipMemsetAsync(bnsum, 0, 1024 * sizeof(float), stream);
  bn_stats<<<dim3(400, 4), 256, 0, stream>>>((const unsigned*)Ab, bnsum, N);
  bn_final<<<1, 512, 0, stream>>>(bnsum, bn_gamma, bn_beta, bnss, N);
  rels_update<<<1, 512, 0, stream>>>(rels, W_rt, b_rt, rels + 512);

  // ---- Layer 1 (fused BN-update, writeback emb1) ----
  scale_w_bf<<<256, 256, 0, stream>>>(rels + 512, W_gcn + (size_t)DD * DD, Wgcnb);
  for (int r = 0; r < 4; ++r) resIn.p[r] = Fb;           // emb0 = features (shared)
  gemm_upd<1><<<dim3(gemmGrid, 4), 256, 0, stream>>>(resIn, abIn, wz, xbOut, msgOut,
                                                     bnss, dinv, N);
  gather_agg<<<(N4 + 7) / 8, 256, 0, stream>>>(srcb, offs, deg_i, dinv, (const uint2*)Bs,
                                               b_gcn + DD, (uint2*)Ab, N4);
  hipMemsetAsync(bnsum, 0, 1024 * sizeof(float), stream);
  bn_stats<<<dim3(400, 4), 256, 0, stream>>>((const unsigned*)Ab, bnsum, N);
  bn_final<<<1, 512, 0, stream>>>(bnsum, bn_gamma + DD, bn_beta + DD, bnss, N);
  rels_update<<<1, 512, 0, stream>>>(rels + 512, W_rt + (size_t)DD * DD, b_rt + DD, rels + 1024);

  // ---- Layer 2 (fused BN-update, no writeback) ----
  scale_w_bf<<<256, 256, 0, stream>>>(rels + 1024, W_gcn + (size_t)2 * DD * DD, Wgcnb);
  for (int r = 0; r < 4; ++r) resIn.p[r] = Xb + (size_t)r * NK;   // emb1
  gemm_upd<0><<<dim3(gemmGrid, 4), 256, 0, stream>>>(resIn, abIn, wz, dummyO, msgOut,
                                                     bnss, dinv, N);
  gather_agg<<<(N4 + 7) / 8, 256, 0, stream>>>(srcb, offs, deg_i, dinv, (const uint2*)Bs,
                                               b_gcn + 2 * DD, (uint2*)Ab, N4);
  rels_update<<<1, 512, 0, stream>>>(rels + 1024, W_rt + (size_t)2 * DD * DD, b_rt + 2 * DD,
                                     rels + 1536);
  // Ab = final GCN outputs (stack source). Xb, Bs, Ub free.

  const int pstk[4] = {3, 0, 2, 1};
  PtrB4 stk;
  for (int l = 0; l < 4; ++l) stk.p[l] = Ab + (size_t)pstk[l] * NK;

  hipMemsetAsync(S, 0, 4 * sizeof(float), stream);
  attn_mega<<<(N + 15) / 16, 256, 0, stream>>>(stk, Wab, attn_b_in, attn_bout, alphas,
                                               fusion_b, fusion_q, Bs, S, N);
  wcoef<<<1, 64, 0, stream>>>(S, coef, N);
  final_out<<<(int)((NK / 4 + 255) / 256), 256, 0, stream>>>(Bs, coef, rels + 1536,
                                                             (float*)d_out, N);
}

// Round 12
// 954.725 us; speedup vs baseline: 1.0592x; 1.0208x over previous
//
#include <hip/hip_runtime.h>
#include <cstdio>

#define DD 128
#define NREL 4

using short8 = __attribute__((ext_vector_type(8))) short;
using f32x4  = __attribute__((ext_vector_type(4))) float;

struct PtrB4 { const unsigned short* p[4]; };
struct OutB4 { unsigned short* p[4]; };

// processing-order relation r uses edge_index/rel_emb row (r+3)&3  (perm = [3,0,1,2])
__device__ __forceinline__ int edge_perm(int r) { return (r + 3) & 3; }

__device__ __forceinline__ float bf_lo(unsigned u) { return __uint_as_float(u << 16); }
__device__ __forceinline__ float bf_hi(unsigned u) { return __uint_as_float(u & 0xffff0000u); }
__device__ __forceinline__ float bfe(short s) {
  return __uint_as_float(((unsigned)(unsigned short)s) << 16);
}
__device__ __forceinline__ unsigned short f2bf(float f) {
  unsigned x = __float_as_uint(f);
  unsigned r = (x + 0x7fffu + ((x >> 16) & 1u)) >> 16;
  return (unsigned short)r;
}
__device__ __forceinline__ unsigned pack2(float a, float b) {
  return (unsigned)f2bf(a) | ((unsigned)f2bf(b) << 16);
}

// swizzled LDS index for 64x136-short tiles: rows 16 apart land on distinct banks
#define SWIDX(row, col) ((row) * 136 + ((col) ^ ((((row) >> 4) & 3) << 4)))

// ---------------- init / weight prep ----------------

__global__ void rels_init(const float* __restrict__ rel_emb, float* __restrict__ rels) {
  int t = threadIdx.x;              // 512 = r*128 + c
  int r = t >> 7, c = t & 127;
  rels[t] = rel_emb[edge_perm(r) * DD + c];
}

__global__ void rels_update(const float* __restrict__ rin, const float* __restrict__ Wrt,
                            const float* __restrict__ brt, float* __restrict__ rout) {
  int t = threadIdx.x;  // 512 = r*128 + j
  int r = t >> 7, j = t & 127;
  float s = brt[j];
  const float* wr = Wrt + j * DD;
  const float* xr = rin + r * DD;
  for (int c = 0; c < DD; ++c) s += xr[c] * wr[c];
  rout[t] = s;
}

// Wsb[r][j][c] = bf16(rels[r][c] * Wg[c][j])  -- MFMA-B layout [n=j][k=c]
__global__ void scale_w_bf(const float* __restrict__ rels_i, const float* __restrict__ Wg,
                           unsigned short* __restrict__ Wsb) {
  int i = blockIdx.x * 256 + threadIdx.x;   // 4*16384
  int r = i >> 14, rem = i & 16383, j = rem >> 7, c = rem & 127;
  Wsb[i] = f2bf(rels_i[r * DD + c] * Wg[c * DD + j]);
}

// Wab = bf16( attn_w_in (3*16384) || attn_wout (16384) || fusion_w (16384) ), all [j][c]
__global__ void conv_w(const float* __restrict__ w_in, const float* __restrict__ w_out,
                       const float* __restrict__ w_fus, unsigned short* __restrict__ Wab) {
  int i = blockIdx.x * 256 + threadIdx.x;   // 5*16384
  float v = (i < 49152) ? w_in[i] : (i < 65536 ? w_out[i - 49152] : w_fus[i - 65536]);
  Wab[i] = f2bf(v);
}

// fp32 -> bf16 single slice
__global__ void conv_f2b(const float* __restrict__ in, unsigned* __restrict__ out2, size_t n4) {
  size_t i = (size_t)blockIdx.x * 256 + threadIdx.x;
  if (i < n4) {
    float4 v = ((const float4*)in)[i];
    out2[i * 2]     = pack2(v.x, v.y);
    out2[i * 2 + 1] = pack2(v.z, v.w);
  }
}

// ---------------- CSR build ----------------

__global__ void count_deg(const int* __restrict__ ei, int* __restrict__ deg, int N, int E) {
  int r = blockIdx.y;
  int base = blockIdx.x * 1024 + threadIdx.x;
  const int* dsts = ei + (size_t)edge_perm(r) * 2 * E + E;
#pragma unroll
  for (int k = 0; k < 4; ++k) {
    int e = base + k * 256;
    if (e < E) atomicAdd(deg + (size_t)r * N + dsts[e], 1);
  }
}

__global__ void finalize_dinv(const int* __restrict__ deg, float* __restrict__ dinv, int total) {
  int i = blockIdx.x * 256 + threadIdx.x;
  if (i < total) dinv[i] = rsqrtf((float)deg[i] + 1.0f);
}

__global__ void scan_block(const int* __restrict__ deg, int* __restrict__ excl,
                           int* __restrict__ bsums, int n) {
  __shared__ int sh[256];
  int i = blockIdx.x * 256 + threadIdx.x;
  int v = (i < n) ? deg[i] : 0;
  sh[threadIdx.x] = v;
  __syncthreads();
  for (int st = 1; st < 256; st <<= 1) {
    int t = (threadIdx.x >= st) ? sh[threadIdx.x - st] : 0;
    __syncthreads();
    sh[threadIdx.x] += t;
    __syncthreads();
  }
  if (i < n) excl[i] = sh[threadIdx.x] - v;
  if (threadIdx.x == 255) bsums[blockIdx.x] = sh[255];
}

__global__ void scan_sums(int* __restrict__ bsums, int nb) {
  __shared__ int sh[1024];
  int v = (threadIdx.x < nb) ? bsums[threadIdx.x] : 0;
  sh[threadIdx.x] = v;
  __syncthreads();
  for (int st = 1; st < 1024; st <<= 1) {
    int t = (threadIdx.x >= st) ? sh[threadIdx.x - st] : 0;
    __syncthreads();
    sh[threadIdx.x] += t;
    __syncthreads();
  }
  if (threadIdx.x < nb) bsums[threadIdx.x] = sh[threadIdx.x] - v;  // exclusive
}

__global__ void scan_add(int* __restrict__ excl, int* __restrict__ cursor,
                         const int* __restrict__ bsums, int n) {
  int i = blockIdx.x * 256 + threadIdx.x;
  if (i < n) {
    int o = excl[i] + bsums[blockIdx.x];
    excl[i] = o;
    cursor[i] = o;
  }
}

// 4 edges/thread: 4 independent atomic-returns in flight
__global__ void fill_edges(const int* __restrict__ ei, int* __restrict__ cursor,
                           int* __restrict__ srcbuf, int N, int E) {
  int r = blockIdx.y;
  int base = blockIdx.x * 1024 + threadIdx.x;
  const int* bp = ei + (size_t)edge_perm(r) * 2 * E;
  int s[4], d[4], pos[4];
#pragma unroll
  for (int k = 0; k < 4; ++k) {
    int e = base + k * 256;
    s[k] = (e < E) ? bp[e] : 0;
    d[k] = (e < E) ? bp[E + e] : 0;
  }
#pragma unroll
  for (int k = 0; k < 4; ++k) {
    int e = base + k * 256;
    if (e < E) pos[k] = atomicAdd(&cursor[r * N + d[k]], 1);
  }
#pragma unroll
  for (int k = 0; k < 4; ++k) {
    int e = base + k * 256;
    if (e < E) srcbuf[pos[k]] = r * N + s[k];
  }
}

// ---------------- weight-stationary MFMA GEMM (round-7 proven) ----------------
// Block 256 = 4 waves: wave = (rowhalf<<1)|colhalf; each wave: 32 rows x 64 cols.
// MODE 0: out bf16 = y * dinv[z*M+row]           (GCN messages)
template <int MODE>
__global__ __launch_bounds__(256) void gemm_ws(PtrB4 xs, PtrB4 wz, OutB4 ys,
                                               const float* __restrict__ bias,
                                               const float* __restrict__ dinv, int M) {
  int z = blockIdx.y;
  const unsigned short* __restrict__ X = xs.p[z];
  const unsigned short* __restrict__ W = wz.p[z];
  int tid = threadIdx.x;
  int wave = tid >> 6, lane = tid & 63;
  int r16 = lane & 15, kgrp = lane >> 4;
  int rowhalf = wave >> 1, colbase = (wave & 1) * 64;
  int blockrow = blockIdx.x * 64;

  short8 b[4][4];
#pragma unroll
  for (int s = 0; s < 4; ++s)
#pragma unroll
    for (int cn = 0; cn < 4; ++cn)
      b[s][cn] = *(const short8*)(W + ((colbase + cn * 16 + r16) << 7) + s * 32 + kgrp * 8);

  int row0 = blockrow + rowhalf * 32 + r16;
  int r0c = row0 < M ? row0 : M - 1;
  int r1c = row0 + 16 < M ? row0 + 16 : M - 1;
  short8 a[2][4];
#pragma unroll
  for (int s = 0; s < 4; ++s) {
    a[0][s] = *(const short8*)(X + (size_t)r0c * DD + s * 32 + kgrp * 8);
    a[1][s] = *(const short8*)(X + (size_t)r1c * DD + s * 32 + kgrp * 8);
  }

  f32x4 acc[2][4];
#pragma unroll
  for (int rt = 0; rt < 2; ++rt)
#pragma unroll
    for (int cn = 0; cn < 4; ++cn)
#pragma unroll
      for (int j = 0; j < 4; ++j) acc[rt][cn][j] = 0.f;

#pragma unroll
  for (int s = 0; s < 4; ++s)
#pragma unroll
    for (int rt = 0; rt < 2; ++rt)
#pragma unroll
      for (int cn = 0; cn < 4; ++cn)
        acc[rt][cn] = __builtin_amdgcn_mfma_f32_16x16x32_bf16(a[rt][s], b[s][cn], acc[rt][cn], 0, 0, 0);

  __shared__ __align__(16) unsigned short tile[64][DD + 8];
  float dv[2][4];
  if constexpr (MODE == 0) {
#pragma unroll
    for (int rt = 0; rt < 2; ++rt)
#pragma unroll
      for (int i = 0; i < 4; ++i) {
        int row = blockrow + rowhalf * 32 + rt * 16 + kgrp * 4 + i;
        dv[rt][i] = dinv[(size_t)z * M + (row < M ? row : 0)];
      }
  }
#pragma unroll
  for (int rt = 0; rt < 2; ++rt)
#pragma unroll
    for (int cn = 0; cn < 4; ++cn) {
      int col = colbase + cn * 16 + r16;
#pragma unroll
      for (int i = 0; i < 4; ++i) {
        int wrow = rowhalf * 32 + rt * 16 + kgrp * 4 + i;
        float y = acc[rt][cn][i];
        if constexpr (MODE == 0) y *= dv[rt][i];
        tile[wrow][col] = f2bf(y);
      }
    }
  __syncthreads();
  int orow = tid >> 2, seg = tid & 3;
  int grow = blockrow + orow;
  if (grow < M) {
    unsigned short* Yp = ys.p[z] + (size_t)grow * DD + seg * 32;
    const unsigned short* tp = &tile[orow][seg * 32];
#pragma unroll
    for (int k = 0; k < 4; ++k)
      *(uint4*)(Yp + k * 8) = *(const uint4*)(tp + k * 8);
  }
}

// Layers 1/2 fused GEMM (round-7 proven): e = res + leaky(bn(Ab)); optional writeback;
// messages = (e@Wz)*dinv
template <int WB>
__global__ __launch_bounds__(256) void gemm_upd(PtrB4 res, PtrB4 abs_, PtrB4 wz,
                                                OutB4 xout, OutB4 ys,
                                                const float* __restrict__ ssx,
                                                const float* __restrict__ dinv, int M) {
  int z = blockIdx.y;
  const unsigned short* __restrict__ R = res.p[z];
  const unsigned short* __restrict__ A = abs_.p[z];
  const unsigned short* __restrict__ W = wz.p[z];
  int tid = threadIdx.x;

  __shared__ float ssc[DD], ssh[DD];
  if (tid < DD) {
    ssc[tid] = ssx[((size_t)z * DD + tid) * 2];
    ssh[tid] = ssx[((size_t)z * DD + tid) * 2 + 1];
  }
  __syncthreads();

  int wave = tid >> 6, lane = tid & 63;
  int r16 = lane & 15, kgrp = lane >> 4;
  int rowhalf = wave >> 1, colbase = (wave & 1) * 64;
  int blockrow = blockIdx.x * 64;

  short8 b[4][4];
#pragma unroll
  for (int s = 0; s < 4; ++s)
#pragma unroll
    for (int cn = 0; cn < 4; ++cn)
      b[s][cn] = *(const short8*)(W + ((colbase + cn * 16 + r16) << 7) + s * 32 + kgrp * 8);

  int row0 = blockrow + rowhalf * 32 + r16;
  int rc[2];
  rc[0] = row0 < M ? row0 : M - 1;
  rc[1] = row0 + 16 < M ? row0 + 16 : M - 1;
  short8 a[2][4];
#pragma unroll
  for (int rt = 0; rt < 2; ++rt)
#pragma unroll
    for (int s = 0; s < 4; ++s) {
      int cbase = s * 32 + kgrp * 8;
      short8 rv = *(const short8*)(R + (size_t)rc[rt] * DD + cbase);
      short8 av = *(const short8*)(A + (size_t)rc[rt] * DD + cbase);
      short8 av2;
#pragma unroll
      for (int j = 0; j < 8; ++j) {
        float x = bfe(av[j]) * ssc[cbase + j] + ssh[cbase + j];
        x = x > 0.f ? x : 0.01f * x;
        av2[j] = (short)f2bf(bfe(rv[j]) + x);
      }
      a[rt][s] = av2;
    }
  if (WB) {
#pragma unroll
    for (int rt = 0; rt < 2; ++rt) {
      int row = row0 + rt * 16;
      if (row < M) {
#pragma unroll
        for (int s = 0; s < 4; ++s)
          *(short8*)(xout.p[z] + (size_t)row * DD + s * 32 + kgrp * 8) = a[rt][s];
      }
    }
  }

  f32x4 acc[2][4];
#pragma unroll
  for (int rt = 0; rt < 2; ++rt)
#pragma unroll
    for (int cn = 0; cn < 4; ++cn)
#pragma unroll
      for (int j = 0; j < 4; ++j) acc[rt][cn][j] = 0.f;
#pragma unroll
  for (int s = 0; s < 4; ++s)
#pragma unroll
    for (int rt = 0; rt < 2; ++rt)
#pragma unroll
      for (int cn = 0; cn < 4; ++cn)
        acc[rt][cn] = __builtin_amdgcn_mfma_f32_16x16x32_bf16(a[rt][s], b[s][cn], acc[rt][cn], 0, 0, 0);

  __shared__ __align__(16) unsigned short tile[64][DD + 8];
  float dv[2][4];
#pragma unroll
  for (int rt = 0; rt < 2; ++rt)
#pragma unroll
    for (int i = 0; i < 4; ++i) {
      int row = blockrow + rowhalf * 32 + rt * 16 + kgrp * 4 + i;
      dv[rt][i] = dinv[(size_t)z * M + (row < M ? row : 0)];
    }
#pragma unroll
  for (int rt = 0; rt < 2; ++rt)
#pragma unroll
    for (int cn = 0; cn < 4; ++cn) {
      int col = colbase + cn * 16 + r16;
#pragma unroll
      for (int i = 0; i < 4; ++i) {
        int wrow = rowhalf * 32 + rt * 16 + kgrp * 4 + i;
        tile[wrow][col] = f2bf(acc[rt][cn][i] * dv[rt][i]);
      }
    }
  __syncthreads();
  int orow = tid >> 2, seg = tid & 3;
  int grow = blockrow + orow;
  if (grow < M) {
    unsigned short* Yp = ys.p[z] + (size_t)grow * DD + seg * 32;
    const unsigned short* tp = &tile[orow][seg * 32];
#pragma unroll
    for (int k = 0; k < 4; ++k)
      *(uint4*)(Yp + k * 8) = *(const uint4*)(tp + k * 8);
  }
}

// ---------------- mega-fused attention phase (v4: 3 arrays + swizzle + reg-p) ----------------
// One block = 16 nodes. Rows r in [0,64): layer l = r>>4, node = nodebase + (r&15).
// Phases (5 barriers): QKV (A regs shared) -> scores (p regs) -> PV: O->q_s ->
//                      proj -> k_s -> blend (k_s + global) -> fusion GEMM + reduce.
__global__ __launch_bounds__(256) void attn_mega(PtrB4 stks,
    const unsigned short* __restrict__ Wab,
    const float* __restrict__ b_in, const float* __restrict__ b_out,
    const float* __restrict__ alphas, const float* __restrict__ fus_b,
    const float* __restrict__ fq, unsigned short* __restrict__ fbuf,
    float* __restrict__ S, int N) {
  __shared__ __align__(16) unsigned short q_s[64 * 136];  // Q -> O
  __shared__ __align__(16) unsigned short k_s[64 * 136];  // K -> proj/f
  __shared__ __align__(16) unsigned short v_s[64 * 136];  // V
  __shared__ float lred[4];
  size_t NK = (size_t)N * DD;

  int tid = threadIdx.x;
  int wave = tid >> 6, lane = tid & 63;
  int r16 = lane & 15, kgrp = lane >> 4;
  int rowhalf = wave >> 1, colbase = (wave & 1) * 64;
  int nodebase = blockIdx.x * 16;

  int rlo = rowhalf * 32 + r16;     // 0..63
  int rhi = rlo + 16;
  int nlo = nodebase + (rlo & 15); if (nlo >= N) nlo = N - 1;
  int nhi = nodebase + (rhi & 15); if (nhi >= N) nhi = N - 1;
  const unsigned short* a0p = stks.p[rlo >> 4] + (size_t)nlo * DD + kgrp * 8;
  const unsigned short* a1p = stks.p[rhi >> 4] + (size_t)nhi * DD + kgrp * 8;

  // ---- Phase 1: Q,K,V GEMMs (A regs shared across the three) ----
  {
    short8 A0[4], A1[4];
#pragma unroll
    for (int s = 0; s < 4; ++s) {
      A0[s] = *(const short8*)(a0p + s * 32);
      A1[s] = *(const short8*)(a1p + s * 32);
    }
    for (int o = 0; o < 3; ++o) {
      const unsigned short* W = Wab + o * 16384;
      short8 b[4][4];
#pragma unroll
      for (int s = 0; s < 4; ++s)
#pragma unroll
        for (int cn = 0; cn < 4; ++cn)
          b[s][cn] = *(const short8*)(W + ((colbase + cn * 16 + r16) << 7) + s * 32 + kgrp * 8);
      f32x4 acc[2][4];
#pragma unroll
      for (int rt = 0; rt < 2; ++rt)
#pragma unroll
        for (int cn = 0; cn < 4; ++cn)
#pragma unroll
          for (int j = 0; j < 4; ++j) acc[rt][cn][j] = 0.f;
#pragma unroll
      for (int s = 0; s < 4; ++s)
#pragma unroll
        for (int cn = 0; cn < 4; ++cn) {
          acc[0][cn] = __builtin_amdgcn_mfma_f32_16x16x32_bf16(A0[s], b[s][cn], acc[0][cn], 0, 0, 0);
          acc[1][cn] = __builtin_amdgcn_mfma_f32_16x16x32_bf16(A1[s], b[s][cn], acc[1][cn], 0, 0, 0);
        }
      unsigned short* dst = (o == 0) ? q_s : (o == 1) ? k_s : v_s;
#pragma unroll
      for (int rt = 0; rt < 2; ++rt)
#pragma unroll
        for (int cn = 0; cn < 4; ++cn) {
          int col = colbase + cn * 16 + r16;
          float bb = b_in[o * DD + col];
#pragma unroll
          for (int i = 0; i < 4; ++i) {
            int wrow = rowhalf * 32 + rt * 16 + kgrp * 4 + i;
            dst[SWIDX(wrow, col)] = f2bf(acc[rt][cn][i] + bb);
          }
        }
    }
  }
  __syncthreads();

  // ---- Phase 2: scores -> p[4] regs (wave owns nodes wave*4..+3) ----
  float p[4];
  {
    int h = lane >> 4, li = (lane >> 2) & 3, m = lane & 3;
    for (int t = 0; t < 4; ++t) {
      int nd = wave * 4 + t;
      float sc = 0.f;
#pragma unroll
      for (int s4 = 0; s4 < 4; ++s4) {
        short8 qv = *(const short8*)&q_s[SWIDX(li * 16 + nd, h * 32 + s4 * 8)];
        short8 kv = *(const short8*)&k_s[SWIDX(m * 16 + nd, h * 32 + s4 * 8)];
#pragma unroll
        for (int j = 0; j < 8; ++j) sc += bfe(qv[j]) * bfe(kv[j]);
      }
      sc *= 0.17677669529663687f;              // 1/sqrt(32)
      float mx = sc;
      mx = fmaxf(mx, __shfl_xor(mx, 1));
      mx = fmaxf(mx, __shfl_xor(mx, 2));
      float e = expf(sc - mx);
      float sum = e;
      sum += __shfl_xor(sum, 1);
      sum += __shfl_xor(sum, 2);
      p[t] = e / sum;                          // lane holds p[h][li][m] for node nd
    }
  }
  __syncthreads();   // score reads done before O overwrites q_s

  // ---- Phase 3: PV -> O into q_s (p via shuffles; wave-local nodes) ----
  {
    int c0 = lane * 2, hh = lane >> 4;   // hh = c0>>5
    for (int t = 0; t < 4; ++t) {
      int nd = wave * 4 + t;
      unsigned v[4];
#pragma unroll
      for (int m = 0; m < 4; ++m)
        v[m] = *(const unsigned*)&v_s[SWIDX(m * 16 + nd, c0)];
#pragma unroll
      for (int lo = 0; lo < 4; ++lo) {
        float ol = 0.f, oh = 0.f;
#pragma unroll
        for (int m = 0; m < 4; ++m) {
          float pm = __shfl(p[t], hh * 16 + lo * 4 + m);
          ol += pm * bf_lo(v[m]);
          oh += pm * bf_hi(v[m]);
        }
        *(unsigned*)&q_s[SWIDX(lo * 16 + nd, c0)] = pack2(ol, oh);
      }
    }
  }
  __syncthreads();

  // ---- Phase 4: out-proj (A = O from q_s) -> k_s holds y + b_out ----
  {
    const unsigned short* W = Wab + 3 * 16384;
    short8 b[4][4];
#pragma unroll
    for (int s = 0; s < 4; ++s)
#pragma unroll
      for (int cn = 0; cn < 4; ++cn)
        b[s][cn] = *(const short8*)(W + ((colbase + cn * 16 + r16) << 7) + s * 32 + kgrp * 8);
    short8 AO0[4], AO1[4];
#pragma unroll
    for (int s = 0; s < 4; ++s) {
      AO0[s] = *(const short8*)&q_s[SWIDX(rlo, s * 32 + kgrp * 8)];
      AO1[s] = *(const short8*)&q_s[SWIDX(rhi, s * 32 + kgrp * 8)];
    }
    f32x4 acc[2][4];
#pragma unroll
    for (int rt = 0; rt < 2; ++rt)
#pragma unroll
      for (int cn = 0; cn < 4; ++cn)
#pragma unroll
        for (int j = 0; j < 4; ++j) acc[rt][cn][j] = 0.f;
#pragma unroll
    for (int s = 0; s < 4; ++s)
#pragma unroll
      for (int cn = 0; cn < 4; ++cn) {
        acc[0][cn] = __builtin_amdgcn_mfma_f32_16x16x32_bf16(AO0[s], b[s][cn], acc[0][cn], 0, 0, 0);
        acc[1][cn] = __builtin_amdgcn_mfma_f32_16x16x32_bf16(AO1[s], b[s][cn], acc[1][cn], 0, 0, 0);
      }
    __syncthreads();   // K reads of k_s long done; ensure no proj write races score phase (already barriered)
#pragma unroll
    for (int rt = 0; rt < 2; ++rt)
#pragma unroll
      for (int cn = 0; cn < 4; ++cn) {
        int col = colbase + cn * 16 + r16;
        float bb = b_out[col];
#pragma unroll
        for (int i = 0; i < 4; ++i) {
          int wrow = rowhalf * 32 + rt * 16 + kgrp * 4 + i;
          k_s[SWIDX(wrow, col)] = f2bf(acc[rt][cn][i] + bb);
        }
      }
  }
  __syncthreads();

  // ---- Phase 5: blend with stk, store f to global, write back to k_s ----
  {
    int orow = tid >> 2, seg = tid & 3;
    int lb = orow >> 4, nb = nodebase + (orow & 15);
    if (nb < N) {
      float aa = alphas[lb], na = 1.f - aa;
      const unsigned short* sp = stks.p[lb] + (size_t)nb * DD + seg * 32;
      unsigned short* Yp = fbuf + (size_t)lb * NK + (size_t)nb * DD + seg * 32;
#pragma unroll
      for (int k = 0; k < 4; ++k) {
        unsigned short* tp = &k_s[SWIDX(orow, seg * 32 + k * 8)];
        uint4 pv = *(const uint4*)tp;
        uint4 sv = *(const uint4*)(sp + k * 8);
        const unsigned* pw = &pv.x;
        const unsigned* sw = &sv.x;
        uint4 o; unsigned* ow = &o.x;
#pragma unroll
        for (int j = 0; j < 4; ++j)
          ow[j] = pack2(aa * bf_lo(pw[j]) + na * bf_lo(sw[j]),
                        aa * bf_hi(pw[j]) + na * bf_hi(sw[j]));
        *(uint4*)(Yp + k * 8) = o;
        *(uint4*)tp = o;
      }
    }
  }
  __syncthreads();

  // ---- Phase 6: fusion GEMM on f (k_s) + leaky*fq score reduce ----
  {
    const unsigned short* W = Wab + 4 * 16384;
    short8 b[4][4];
#pragma unroll
    for (int s = 0; s < 4; ++s)
#pragma unroll
      for (int cn = 0; cn < 4; ++cn)
        b[s][cn] = *(const short8*)(W + ((colbase + cn * 16 + r16) << 7) + s * 32 + kgrp * 8);
    short8 AF0[4], AF1[4];
#pragma unroll
    for (int s = 0; s < 4; ++s) {
      AF0[s] = *(const short8*)&k_s[SWIDX(rlo, s * 32 + kgrp * 8)];
      AF1[s] = *(const short8*)&k_s[SWIDX(rhi, s * 32 + kgrp * 8)];
    }
    f32x4 acc[2][4];
#pragma unroll
    for (int rt = 0; rt < 2; ++rt)
#pragma unroll
      for (int cn = 0; cn < 4; ++cn)
#pragma unroll
        for (int j = 0; j < 4; ++j) acc[rt][cn][j] = 0.f;
#pragma unroll
    for (int s = 0; s < 4; ++s)
#pragma unroll
      for (int cn = 0; cn < 4; ++cn) {
        acc[0][cn] = __builtin_amdgcn_mfma_f32_16x16x32_bf16(AF0[s], b[s][cn], acc[0][cn], 0, 0, 0);
        acc[1][cn] = __builtin_amdgcn_mfma_f32_16x16x32_bf16(AF1[s], b[s][cn], acc[1][cn], 0, 0, 0);
      }
    float ss0 = 0.f, ss1 = 0.f;
#pragma unroll
    for (int cn = 0; cn < 4; ++cn) {
      int col = colbase + cn * 16 + r16;
      float bb = fus_b[col];
      float qc = fq[col];
#pragma unroll
      for (int i = 0; i < 4; ++i) {
        if (nodebase + kgrp * 4 + i < N) {
          float y0 = acc[0][cn][i] + bb;
          float y1 = acc[1][cn][i] + bb;
          ss0 += (y0 > 0.f ? y0 : 0.01f * y0) * qc;
          ss1 += (y1 > 0.f ? y1 : 0.01f * y1) * qc;
        }
      }
    }
    if (tid < 4) lred[tid] = 0.f;
    __syncthreads();
    atomicAdd(&lred[rowhalf * 2], ss0);
    atomicAdd(&lred[rowhalf * 2 + 1], ss1);
    __syncthreads();
    if (tid < 4) atomicAdd(S + tid, lred[tid]);
  }
}

// ---------------- GCN aggregation: CSR gather, 2 nodes/wave, unroll x8 ----------------
__global__ __launch_bounds__(256) void gather_agg(const int* __restrict__ srcbuf,
                                                  const int* __restrict__ offs,
                                                  const int* __restrict__ deg,
                                                  const float* __restrict__ dinv,
                                                  const uint2* __restrict__ Bs2,
                                                  const float* __restrict__ bias,
                                                  uint2* __restrict__ Ab2, int N4) {
  int rn = blockIdx.x * 8 + (threadIdx.x >> 5);
  if (rn >= N4) return;
  int lane = threadIdx.x & 31;
  int st = offs[rn], cnt = deg[rn];
  uint2 u = Bs2[(size_t)rn * 32 + lane];        // self message
  float a0 = bf_lo(u.x), a1 = bf_hi(u.x), a2 = bf_lo(u.y), a3 = bf_hi(u.y);
  int e = 0;
  for (; e + 8 <= cnt; e += 8) {
    int rr[8];
#pragma unroll
    for (int j = 0; j < 8; ++j) rr[j] = srcbuf[st + e + j];
    uint2 vv[8];
#pragma unroll
    for (int j = 0; j < 8; ++j) vv[j] = Bs2[(size_t)rr[j] * 32 + lane];
#pragma unroll
    for (int j = 0; j < 8; ++j) {
      a0 += bf_lo(vv[j].x); a1 += bf_hi(vv[j].x);
      a2 += bf_lo(vv[j].y); a3 += bf_hi(vv[j].y);
    }
  }
  if (e + 4 <= cnt) {
    int rr[4];
#pragma unroll
    for (int j = 0; j < 4; ++j) rr[j] = srcbuf[st + e + j];
    uint2 vv[4];
#pragma unroll
    for (int j = 0; j < 4; ++j) vv[j] = Bs2[(size_t)rr[j] * 32 + lane];
#pragma unroll
    for (int j = 0; j < 4; ++j) {
      a0 += bf_lo(vv[j].x); a1 += bf_hi(vv[j].x);
      a2 += bf_lo(vv[j].y); a3 += bf_hi(vv[j].y);
    }
    e += 4;
  }
  for (; e < cnt; ++e) {
    uint2 v = Bs2[(size_t)srcbuf[st + e] * 32 + lane];
    a0 += bf_lo(v.x); a1 += bf_hi(v.x); a2 += bf_lo(v.y); a3 += bf_hi(v.y);
  }
  float dvv = dinv[rn];
  int c = lane * 4;
  uint2 o;
  o.x = pack2(a0 * dvv + bias[c],     a1 * dvv + bias[c + 1]);
  o.y = pack2(a2 * dvv + bias[c + 2], a3 * dvv + bias[c + 3]);
  Ab2[(size_t)rn * 32 + lane] = o;
}

// ---------------- batchnorm ----------------

__global__ void bn_stats(const unsigned* __restrict__ Ab2, float* __restrict__ sums, int N) {
  int r = blockIdx.y;
  int lane = threadIdx.x & 63, grp = threadIdx.x >> 6;
  float s0 = 0.f, q0 = 0.f, s1 = 0.f, q1 = 0.f;
  const unsigned* base = Ab2 + (size_t)r * N * 64;
  for (int n = blockIdx.x * 4 + grp; n < N; n += gridDim.x * 4) {
    unsigned u = base[(size_t)n * 64 + lane];
    float a = bf_lo(u), b = bf_hi(u);
    s0 += a; q0 += a * a; s1 += b; q1 += b * b;
  }
  __shared__ float sh[4][64][4];
  sh[grp][lane][0] = s0; sh[grp][lane][1] = q0; sh[grp][lane][2] = s1; sh[grp][lane][3] = q1;
  __syncthreads();
  if (grp == 0) {
#pragma unroll
    for (int g = 1; g < 4; ++g) {
      s0 += sh[g][lane][0]; q0 += sh[g][lane][1]; s1 += sh[g][lane][2]; q1 += sh[g][lane][3];
    }
    int c0 = lane * 2;
    atomicAdd(sums + (r * DD + c0) * 2, s0);
    atomicAdd(sums + (r * DD + c0) * 2 + 1, q0);
    atomicAdd(sums + (r * DD + c0 + 1) * 2, s1);
    atomicAdd(sums + (r * DD + c0 + 1) * 2 + 1, q1);
  }
}

__global__ void bn_final(const float* __restrict__ sums, const float* __restrict__ gamma,
                         const float* __restrict__ beta, float* __restrict__ ss, int N) {
  int t = threadIdx.x;       // 512 = r*128+c
  int c = t & 127;
  float mu = sums[t * 2] / N;
  float var = sums[t * 2 + 1] / N - mu * mu;
  float sc = gamma[c] * rsqrtf(var + 1e-5f);
  ss[t * 2] = sc;
  ss[t * 2 + 1] = beta[c] - mu * sc;
}

// w = softmax([S(f0),S(f1),S(f3),S(f2)]);  coef[l] multiplies f[l]: coef = [w0,w1,w3,w2]
__global__ void wcoef(const float* __restrict__ S, float* __restrict__ coef, int N) {
  if (threadIdx.x == 0) {
    float v0 = S[0] / N, v1 = S[1] / N, v2 = S[3] / N, v3 = S[2] / N;
    float mx = fmaxf(fmaxf(v0, v1), fmaxf(v2, v3));
    float e0 = expf(v0 - mx), e1 = expf(v1 - mx), e2 = expf(v2 - mx), e3 = expf(v3 - mx);
    float inv = 1.f / (e0 + e1 + e2 + e3);
    coef[0] = e0 * inv; coef[1] = e1 * inv; coef[2] = e3 * inv; coef[3] = e2 * inv;
  }
}

__device__ __forceinline__ float bfat(uint2 u, int j) {
  unsigned w = (j < 2) ? u.x : u.y;
  return (j & 1) ? bf_hi(w) : bf_lo(w);
}

// region = sum coef[l]*f[l]; outputs: region, region*rels3[{3,0,1,2}]
__global__ void final_out(const unsigned short* __restrict__ fb, const float* __restrict__ coef,
                          const float* __restrict__ rels3, float* __restrict__ out, int N) {
  size_t NK = (size_t)N * DD;
  size_t i4 = (size_t)blockIdx.x * 256 + threadIdx.x;  // 4-elem groups
  if (i4 >= NK / 4) return;
  size_t g = i4 * 4;
  int c = (int)(g & 127);
  float c0 = coef[0], c1 = coef[1], c2 = coef[2], c3 = coef[3];
  uint2 u0 = *(const uint2*)(fb + g);
  uint2 u1 = *(const uint2*)(fb + NK + g);
  uint2 u2 = *(const uint2*)(fb + 2 * NK + g);
  uint2 u3 = *(const uint2*)(fb + 3 * NK + g);
  float4 reg4, o1, o2, o3, o4;
  float* rp = &reg4.x; float* p1 = &o1.x; float* p2 = &o2.x; float* p3 = &o3.x; float* p4 = &o4.x;
#pragma unroll
  for (int j = 0; j < 4; ++j) {
    float region = c0 * bfat(u0, j) + c1 * bfat(u1, j) + c2 * bfat(u2, j) + c3 * bfat(u3, j);
    rp[j] = region;
    p1[j] = region * rels3[3 * DD + c + j];
    p2[j] = region * rels3[0 * DD + c + j];
    p3[j] = region * rels3[1 * DD + c + j];
    p4[j] = region * rels3[2 * DD + c + j];
  }
  *(float4*)(out + g) = reg4;
  *(float4*)(out + NK + g) = o1;
  *(float4*)(out + 2 * NK + g) = o2;
  *(float4*)(out + 3 * NK + g) = o3;
  *(float4*)(out + 4 * NK + g) = o4;
}

// ---------------- host ----------------

extern "C" void kernel_launch(void* const* d_in, const int* in_sizes, int n_in,
                              void* d_out, int out_size, void* d_ws, size_t ws_size,
                              hipStream_t stream) {
  const float* features  = (const float*)d_in[0];
  const float* rel_emb   = (const float*)d_in[1];
  const int*   edge_idx  = (const int*)d_in[2];
  const float* W_gcn     = (const float*)d_in[3];
  const float* b_gcn     = (const float*)d_in[4];
  const float* bn_gamma  = (const float*)d_in[5];
  const float* bn_beta   = (const float*)d_in[6];
  const float* W_rt      = (const float*)d_in[7];
  const float* b_rt      = (const float*)d_in[8];
  const float* attn_w_in = (const float*)d_in[9];
  const float* attn_b_in = (const float*)d_in[10];
  const float* attn_wout = (const float*)d_in[11];
  const float* attn_bout = (const float*)d_in[12];
  const float* alphas    = (const float*)d_in[13];
  const float* fusion_q  = (const float*)d_in[14];
  const float* fusion_w  = (const float*)d_in[15];
  const float* fusion_b  = (const float*)d_in[16];

  int N = in_sizes[0] / DD;                  // 50000
  int E = in_sizes[2] / (2 * NREL);          // 400000
  size_t NK = (size_t)N * DD;
  int N4 = 4 * N;

  unsigned short* Xb = (unsigned short*)d_ws;            // 4*NK (emb1)
  unsigned short* Bs = Xb + 4 * NK;                      // 4*NK (messages / f)
  unsigned short* Ab = Bs + 4 * NK;                      // 4*NK (agg / stack)
  unsigned short* Ub = Ab + 4 * NK;                      // 4*NK (spare)
  unsigned short* Fb = Ub + 4 * NK;                      // NK (bf16 features, shared)
  float* dinv  = (float*)(Fb + NK);                      // 4*N
  unsigned short* Wgcnb = (unsigned short*)(dinv + N4);  // 4*16384
  unsigned short* Wab   = Wgcnb + 4 * DD * DD;           // 5*16384
  float* rels  = (float*)(Wab + 5 * DD * DD);            // 4 stages * 512
  float* bnsum = rels + 4 * 512;                         // 1024
  float* bnss  = bnsum + 1024;                           // 1024
  float* S     = bnss + 1024;                            // 4
  float* coef  = S + 4;                                  // 4
  int* deg_i   = (int*)(coef + 4);                       // 4*N
  int* offs    = deg_i + N4;                             // 4*N
  int* cur     = offs + N4;                              // 4*N
  int* bsums   = cur + N4;                               // 1024
  int* srcb    = bsums + 1024;                           // 4*E

  size_t needed = (size_t)((char*)(srcb + 4 * E) - (char*)d_ws);
  if (ws_size < needed) {
    fprintf(stderr, "kernel_launch: ws too small (%zu < %zu)\n", ws_size, needed);
    return;
  }

  int gemmGrid = (N + 63) / 64;
  int scanBlocks = (N4 + 255) / 256;
  int egrid4 = (E + 1023) / 1024;

  // ---- CSR build (edges fixed across layers) ----
  hipMemsetAsync(deg_i, 0, (size_t)N4 * sizeof(int), stream);
  count_deg<<<dim3(egrid4, 4), 256, 0, stream>>>(edge_idx, deg_i, N, E);
  finalize_dinv<<<scanBlocks, 256, 0, stream>>>(deg_i, dinv, N4);
  scan_block<<<scanBlocks, 256, 0, stream>>>(deg_i, offs, bsums, N4);
  scan_sums<<<1, 1024, 0, stream>>>(bsums, scanBlocks);
  scan_add<<<scanBlocks, 256, 0, stream>>>(offs, cur, bsums, N4);
  fill_edges<<<dim3(egrid4, 4), 256, 0, stream>>>(edge_idx, cur, srcb, N, E);

  rels_init<<<1, 512, 0, stream>>>(rel_emb, rels);
  conv_w<<<5 * 16384 / 256, 256, 0, stream>>>(attn_w_in, attn_wout, fusion_w, Wab);
  conv_f2b<<<(int)((NK / 4 + 255) / 256), 256, 0, stream>>>(features, (unsigned*)Fb, NK / 4);

  PtrB4 wz, abIn, resIn;
  OutB4 msgOut, xbOut, dummyO;
  for (int r = 0; r < 4; ++r) {
    wz.p[r] = Wgcnb + (size_t)r * DD * DD;
    abIn.p[r] = Ab + (size_t)r * NK;
    msgOut.p[r] = Bs + (size_t)r * NK;
    xbOut.p[r] = Xb + (size_t)r * NK;
    dummyO.p[r] = nullptr;
  }

  // ---- Layer 0 ----
  scale_w_bf<<<256, 256, 0, stream>>>(rels, W_gcn, Wgcnb);
  {
    PtrB4 xs; for (int r = 0; r < 4; ++r) xs.p[r] = Fb;
    gemm_ws<0><<<dim3(gemmGrid, 4), 256, 0, stream>>>(xs, wz, msgOut, nullptr, dinv, N);
  }
  gather_agg<<<(N4 + 7) / 8, 256, 0, stream>>>(srcb, offs, deg_i, dinv, (const uint2*)Bs,
                                               b_gcn, (uint2*)Ab, N4);
  hipMemsetAsync(bnsum, 0, 1024 * sizeof(float), stream);
  bn_stats<<<dim3(400, 4), 256, 0, stream>>>((const unsigned*)Ab, bnsum, N);
  bn_final<<<1, 512, 0, stream>>>(bnsum, bn_gamma, bn_beta, bnss, N);
  rels_update<<<1, 512, 0, stream>>>(rels, W_rt, b_rt, rels + 512);

  // ---- Layer 1 (fused BN-update, writeback emb1) ----
  scale_w_bf<<<256, 256, 0, stream>>>(rels + 512, W_gcn + (size_t)DD * DD, Wgcnb);
  for (int r = 0; r < 4; ++r) resIn.p[r] = Fb;           // emb0 = features (shared)
  gemm_upd<1><<<dim3(gemmGrid, 4), 256, 0, stream>>>(resIn, abIn, wz, xbOut, msgOut,
                                                     bnss, dinv, N);
  gather_agg<<<(N4 + 7) / 8, 256, 0, stream>>>(srcb, offs, deg_i, dinv, (const uint2*)Bs,
                                               b_gcn + DD, (uint2*)Ab, N4);
  hipMemsetAsync(bnsum, 0, 1024 * sizeof(float), stream);
  bn_stats<<<dim3(400, 4), 256, 0, stream>>>((const unsigned*)Ab, bnsum, N);
  bn_final<<<1, 512, 0, stream>>>(bnsum, bn_gamma + DD, bn_beta + DD, bnss, N);
  rels_update<<<1, 512, 0, stream>>>(rels + 512, W_rt + (size_t)DD * DD, b_rt + DD, rels + 1024);

  // ---- Layer 2 (fused BN-update, no writeback) ----
  scale_w_bf<<<256, 256, 0, stream>>>(rels + 1024, W_gcn + (size_t)2 * DD * DD, Wgcnb);
  for (int r = 0; r < 4; ++r) resIn.p[r] = Xb + (size_t)r * NK;   // emb1
  gemm_upd<0><<<dim3(gemmGrid, 4), 256, 0, stream>>>(resIn, abIn, wz, dummyO, msgOut,
                                                     bnss, dinv, N);
  gather_agg<<<(N4 + 7) / 8, 256, 0, stream>>>(srcb, offs, deg_i, dinv, (const uint2*)Bs,
                                               b_gcn + 2 * DD, (uint2*)Ab, N4);
  rels_update<<<1, 512, 0, stream>>>(rels + 1024, W_rt + (size_t)2 * DD * DD, b_rt + 2 * DD,
                                     rels + 1536);
  // Ab = final GCN outputs (stack source). Xb, Bs, Ub free.

  const int pstk[4] = {3, 0, 2, 1};
  PtrB4 stk;
  for (int l = 0; l < 4; ++l) stk.p[l] = Ab + (size_t)pstk[l] * NK;

  hipMemsetAsync(S, 0, 4 * sizeof(float), stream);
  attn_mega<<<(N + 15) / 16, 256, 0, stream>>>(stk, Wab, attn_b_in, attn_bout, alphas,
                                               fusion_b, fusion_q, Bs, S, N);
  wcoef<<<1, 64, 0, stream>>>(S, coef, N);
  final_out<<<(int)((NK / 4 + 255) / 256), 256, 0, stream>>>(Bs, coef, rels + 1536,
                                                             (float*)d_out, N);
}

// Round 14
// 947.879 us; speedup vs baseline: 1.0669x; 1.0072x over previous
//
#include <hip/hip_runtime.h>
#include <hip/hip_bf16.h>
#include <cstdio>

#define DD 128
#define NREL 4

using short8 = __attribute__((ext_vector_type(8))) short;
using f32x4  = __attribute__((ext_vector_type(4))) float;

struct PtrB4 { const unsigned short* p[4]; };
struct OutB4 { unsigned short* p[4]; };

// processing-order relation r uses edge_index/rel_emb row (r+3)&3  (perm = [3,0,1,2])
__device__ __forceinline__ int edge_perm(int r) { return (r + 3) & 3; }

__device__ __forceinline__ float bf_lo(unsigned u) { return __uint_as_float(u << 16); }
__device__ __forceinline__ float bf_hi(unsigned u) { return __uint_as_float(u & 0xffff0000u); }
__device__ __forceinline__ float bfe(short s) {
  return __uint_as_float(((unsigned)(unsigned short)s) << 16);
}
// native RNE converts (compiler emits v_cvt_pk_bf16_f32 for adjacent pairs)
__device__ __forceinline__ unsigned short f2bf(float f) {
  return __bfloat16_as_ushort(__float2bfloat16(f));
}
__device__ __forceinline__ unsigned pack2(float a, float b) {
  return (unsigned)f2bf(a) | ((unsigned)f2bf(b) << 16);
}

// swizzled LDS index for 64x136-short tiles: rows 16 apart land on distinct banks
#define SWIDX(row, col) ((row) * 136 + ((col) ^ ((((row) >> 4) & 3) << 4)))

// ---------------- init / weight prep ----------------

__global__ void rels_init(const float* __restrict__ rel_emb, float* __restrict__ rels) {
  int t = threadIdx.x;              // 512 = r*128 + c
  int r = t >> 7, c = t & 127;
  rels[t] = rel_emb[edge_perm(r) * DD + c];
}

__global__ void rels_update(const float* __restrict__ rin, const float* __restrict__ Wrt,
                            const float* __restrict__ brt, float* __restrict__ rout) {
  int t = threadIdx.x;  // 512 = r*128 + j
  int r = t >> 7, j = t & 127;
  float s = brt[j];
  const float* wr = Wrt + j * DD;
  const float* xr = rin + r * DD;
  for (int c = 0; c < DD; ++c) s += xr[c] * wr[c];
  rout[t] = s;
}

// Wsb[r][j][c] = bf16(rels[r][c] * Wg[c][j])  -- MFMA-B layout [n=j][k=c]
__global__ void scale_w_bf(const float* __restrict__ rels_i, const float* __restrict__ Wg,
                           unsigned short* __restrict__ Wsb) {
  int i = blockIdx.x * 256 + threadIdx.x;   // 4*16384
  int r = i >> 14, rem = i & 16383, j = rem >> 7, c = rem & 127;
  Wsb[i] = f2bf(rels_i[r * DD + c] * Wg[c * DD + j]);
}

// Wab = bf16( attn_w_in (3*16384) || attn_wout (16384) || fusion_w (16384) ), all [j][c]
__global__ void conv_w(const float* __restrict__ w_in, const float* __restrict__ w_out,
                       const float* __restrict__ w_fus, unsigned short* __restrict__ Wab) {
  int i = blockIdx.x * 256 + threadIdx.x;   // 5*16384
  float v = (i < 49152) ? w_in[i] : (i < 65536 ? w_out[i - 49152] : w_fus[i - 65536]);
  Wab[i] = f2bf(v);
}

// fp32 -> bf16 single slice
__global__ void conv_f2b(const float* __restrict__ in, unsigned* __restrict__ out2, size_t n4) {
  size_t i = (size_t)blockIdx.x * 256 + threadIdx.x;
  if (i < n4) {
    float4 v = ((const float4*)in)[i];
    out2[i * 2]     = pack2(v.x, v.y);
    out2[i * 2 + 1] = pack2(v.z, v.w);
  }
}

// ---------------- CSR build ----------------

__global__ void count_deg(const int* __restrict__ ei, int* __restrict__ deg, int N, int E) {
  int r = blockIdx.y;
  int base = blockIdx.x * 1024 + threadIdx.x;
  const int* dsts = ei + (size_t)edge_perm(r) * 2 * E + E;
#pragma unroll
  for (int k = 0; k < 4; ++k) {
    int e = base + k * 256;
    if (e < E) atomicAdd(deg + (size_t)r * N + dsts[e], 1);
  }
}

__global__ void finalize_dinv(const int* __restrict__ deg, float* __restrict__ dinv, int total) {
  int i = blockIdx.x * 256 + threadIdx.x;
  if (i < total) dinv[i] = rsqrtf((float)deg[i] + 1.0f);
}

__global__ void scan_block(const int* __restrict__ deg, int* __restrict__ excl,
                           int* __restrict__ bsums, int n) {
  __shared__ int sh[256];
  int i = blockIdx.x * 256 + threadIdx.x;
  int v = (i < n) ? deg[i] : 0;
  sh[threadIdx.x] = v;
  __syncthreads();
  for (int st = 1; st < 256; st <<= 1) {
    int t = (threadIdx.x >= st) ? sh[threadIdx.x - st] : 0;
    __syncthreads();
    sh[threadIdx.x] += t;
    __syncthreads();
  }
  if (i < n) excl[i] = sh[threadIdx.x] - v;
  if (threadIdx.x == 255) bsums[blockIdx.x] = sh[255];
}

__global__ void scan_sums(int* __restrict__ bsums, int nb) {
  __shared__ int sh[1024];
  int v = (threadIdx.x < nb) ? bsums[threadIdx.x] : 0;
  sh[threadIdx.x] = v;
  __syncthreads();
  for (int st = 1; st < 1024; st <<= 1) {
    int t = (threadIdx.x >= st) ? sh[threadIdx.x - st] : 0;
    __syncthreads();
    sh[threadIdx.x] += t;
    __syncthreads();
  }
  if (threadIdx.x < nb) bsums[threadIdx.x] = sh[threadIdx.x] - v;  // exclusive
}

__global__ void scan_add(int* __restrict__ excl, int* __restrict__ cursor,
                         const int* __restrict__ bsums, int n) {
  int i = blockIdx.x * 256 + threadIdx.x;
  if (i < n) {
    int o = excl[i] + bsums[blockIdx.x];
    excl[i] = o;
    cursor[i] = o;
  }
}

// 4 edges/thread: 4 independent atomic-returns in flight
__global__ void fill_edges(const int* __restrict__ ei, int* __restrict__ cursor,
                           int* __restrict__ srcbuf, int N, int E) {
  int r = blockIdx.y;
  int base = blockIdx.x * 1024 + threadIdx.x;
  const int* bp = ei + (size_t)edge_perm(r) * 2 * E;
  int s[4], d[4], pos[4];
#pragma unroll
  for (int k = 0; k < 4; ++k) {
    int e = base + k * 256;
    s[k] = (e < E) ? bp[e] : 0;
    d[k] = (e < E) ? bp[E + e] : 0;
  }
#pragma unroll
  for (int k = 0; k < 4; ++k) {
    int e = base + k * 256;
    if (e < E) pos[k] = atomicAdd(&cursor[r * N + d[k]], 1);
  }
#pragma unroll
  for (int k = 0; k < 4; ++k) {
    int e = base + k * 256;
    if (e < E) srcbuf[pos[k]] = r * N + s[k];
  }
}

// ---------------- weight-stationary MFMA GEMM (round-7 proven) ----------------
// Block 256 = 4 waves: wave = (rowhalf<<1)|colhalf; each wave: 32 rows x 64 cols.
// MODE 0: out bf16 = y * dinv[z*M+row]           (GCN messages)
template <int MODE>
__global__ __launch_bounds__(256) void gemm_ws(PtrB4 xs, PtrB4 wz, OutB4 ys,
                                               const float* __restrict__ bias,
                                               const float* __restrict__ dinv, int M) {
  int z = blockIdx.y;
  const unsigned short* __restrict__ X = xs.p[z];
  const unsigned short* __restrict__ W = wz.p[z];
  int tid = threadIdx.x;
  int wave = tid >> 6, lane = tid & 63;
  int r16 = lane & 15, kgrp = lane >> 4;
  int rowhalf = wave >> 1, colbase = (wave & 1) * 64;
  int blockrow = blockIdx.x * 64;

  short8 b[4][4];
#pragma unroll
  for (int s = 0; s < 4; ++s)
#pragma unroll
    for (int cn = 0; cn < 4; ++cn)
      b[s][cn] = *(const short8*)(W + ((colbase + cn * 16 + r16) << 7) + s * 32 + kgrp * 8);

  int row0 = blockrow + rowhalf * 32 + r16;
  int r0c = row0 < M ? row0 : M - 1;
  int r1c = row0 + 16 < M ? row0 + 16 : M - 1;
  short8 a[2][4];
#pragma unroll
  for (int s = 0; s < 4; ++s) {
    a[0][s] = *(const short8*)(X + (size_t)r0c * DD + s * 32 + kgrp * 8);
    a[1][s] = *(const short8*)(X + (size_t)r1c * DD + s * 32 + kgrp * 8);
  }

  f32x4 acc[2][4];
#pragma unroll
  for (int rt = 0; rt < 2; ++rt)
#pragma unroll
    for (int cn = 0; cn < 4; ++cn)
#pragma unroll
      for (int j = 0; j < 4; ++j) acc[rt][cn][j] = 0.f;

#pragma unroll
  for (int s = 0; s < 4; ++s)
#pragma unroll
    for (int rt = 0; rt < 2; ++rt)
#pragma unroll
      for (int cn = 0; cn < 4; ++cn)
        acc[rt][cn] = __builtin_amdgcn_mfma_f32_16x16x32_bf16(a[rt][s], b[s][cn], acc[rt][cn], 0, 0, 0);

  __shared__ __align__(16) unsigned short tile[64][DD + 8];
  float dv[2][4];
  if constexpr (MODE == 0) {
#pragma unroll
    for (int rt = 0; rt < 2; ++rt)
#pragma unroll
      for (int i = 0; i < 4; ++i) {
        int row = blockrow + rowhalf * 32 + rt * 16 + kgrp * 4 + i;
        dv[rt][i] = dinv[(size_t)z * M + (row < M ? row : 0)];
      }
  }
#pragma unroll
  for (int rt = 0; rt < 2; ++rt)
#pragma unroll
    for (int cn = 0; cn < 4; ++cn) {
      int col = colbase + cn * 16 + r16;
#pragma unroll
      for (int i = 0; i < 4; ++i) {
        int wrow = rowhalf * 32 + rt * 16 + kgrp * 4 + i;
        float y = acc[rt][cn][i];
        if constexpr (MODE == 0) y *= dv[rt][i];
        tile[wrow][col] = f2bf(y);
      }
    }
  __syncthreads();
  int orow = tid >> 2, seg = tid & 3;
  int grow = blockrow + orow;
  if (grow < M) {
    unsigned short* Yp = ys.p[z] + (size_t)grow * DD + seg * 32;
    const unsigned short* tp = &tile[orow][seg * 32];
#pragma unroll
    for (int k = 0; k < 4; ++k)
      *(uint4*)(Yp + k * 8) = *(const uint4*)(tp + k * 8);
  }
}

// Layers 1/2 fused GEMM (round-7 proven): e = res + leaky(bn(Ab)); optional writeback;
// messages = (e@Wz)*dinv
template <int WB>
__global__ __launch_bounds__(256) void gemm_upd(PtrB4 res, PtrB4 abs_, PtrB4 wz,
                                                OutB4 xout, OutB4 ys,
                                                const float* __restrict__ ssx,
                                                const float* __restrict__ dinv, int M) {
  int z = blockIdx.y;
  const unsigned short* __restrict__ R = res.p[z];
  const unsigned short* __restrict__ A = abs_.p[z];
  const unsigned short* __restrict__ W = wz.p[z];
  int tid = threadIdx.x;

  __shared__ float ssc[DD], ssh[DD];
  if (tid < DD) {
    ssc[tid] = ssx[((size_t)z * DD + tid) * 2];
    ssh[tid] = ssx[((size_t)z * DD + tid) * 2 + 1];
  }
  __syncthreads();

  int wave = tid >> 6, lane = tid & 63;
  int r16 = lane & 15, kgrp = lane >> 4;
  int rowhalf = wave >> 1, colbase = (wave & 1) * 64;
  int blockrow = blockIdx.x * 64;

  short8 b[4][4];
#pragma unroll
  for (int s = 0; s < 4; ++s)
#pragma unroll
    for (int cn = 0; cn < 4; ++cn)
      b[s][cn] = *(const short8*)(W + ((colbase + cn * 16 + r16) << 7) + s * 32 + kgrp * 8);

  int row0 = blockrow + rowhalf * 32 + r16;
  int rc[2];
  rc[0] = row0 < M ? row0 : M - 1;
  rc[1] = row0 + 16 < M ? row0 + 16 : M - 1;
  short8 a[2][4];
#pragma unroll
  for (int rt = 0; rt < 2; ++rt)
#pragma unroll
    for (int s = 0; s < 4; ++s) {
      int cbase = s * 32 + kgrp * 8;
      short8 rv = *(const short8*)(R + (size_t)rc[rt] * DD + cbase);
      short8 av = *(const short8*)(A + (size_t)rc[rt] * DD + cbase);
      unsigned w4p[4];
#pragma unroll
      for (int jj = 0; jj < 4; ++jj) {
        float x0 = bfe(av[2 * jj]) * ssc[cbase + 2 * jj] + ssh[cbase + 2 * jj];
        float x1 = bfe(av[2 * jj + 1]) * ssc[cbase + 2 * jj + 1] + ssh[cbase + 2 * jj + 1];
        x0 = x0 > 0.f ? x0 : 0.01f * x0;
        x1 = x1 > 0.f ? x1 : 0.01f * x1;
        w4p[jj] = pack2(bfe(rv[2 * jj]) + x0, bfe(rv[2 * jj + 1]) + x1);
      }
      uint4 packed = make_uint4(w4p[0], w4p[1], w4p[2], w4p[3]);
      short8 av2;
      __builtin_memcpy(&av2, &packed, sizeof(av2));
      a[rt][s] = av2;
    }
  if (WB) {
#pragma unroll
    for (int rt = 0; rt < 2; ++rt) {
      int row = row0 + rt * 16;
      if (row < M) {
#pragma unroll
        for (int s = 0; s < 4; ++s)
          *(short8*)(xout.p[z] + (size_t)row * DD + s * 32 + kgrp * 8) = a[rt][s];
      }
    }
  }

  f32x4 acc[2][4];
#pragma unroll
  for (int rt = 0; rt < 2; ++rt)
#pragma unroll
    for (int cn = 0; cn < 4; ++cn)
#pragma unroll
      for (int j = 0; j < 4; ++j) acc[rt][cn][j] = 0.f;
#pragma unroll
  for (int s = 0; s < 4; ++s)
#pragma unroll
    for (int rt = 0; rt < 2; ++rt)
#pragma unroll
      for (int cn = 0; cn < 4; ++cn)
        acc[rt][cn] = __builtin_amdgcn_mfma_f32_16x16x32_bf16(a[rt][s], b[s][cn], acc[rt][cn], 0, 0, 0);

  __shared__ __align__(16) unsigned short tile[64][DD + 8];
  float dv[2][4];
#pragma unroll
  for (int rt = 0; rt < 2; ++rt)
#pragma unroll
    for (int i = 0; i < 4; ++i) {
      int row = blockrow + rowhalf * 32 + rt * 16 + kgrp * 4 + i;
      dv[rt][i] = dinv[(size_t)z * M + (row < M ? row : 0)];
    }
#pragma unroll
  for (int rt = 0; rt < 2; ++rt)
#pragma unroll
    for (int cn = 0; cn < 4; ++cn) {
      int col = colbase + cn * 16 + r16;
#pragma unroll
      for (int i = 0; i < 4; ++i) {
        int wrow = rowhalf * 32 + rt * 16 + kgrp * 4 + i;
        tile[wrow][col] = f2bf(acc[rt][cn][i] * dv[rt][i]);
      }
    }
  __syncthreads();
  int orow = tid >> 2, seg = tid & 3;
  int grow = blockrow + orow;
  if (grow < M) {
    unsigned short* Yp = ys.p[z] + (size_t)grow * DD + seg * 32;
    const unsigned short* tp = &tile[orow][seg * 32];
#pragma unroll
    for (int k = 0; k < 4; ++k)
      *(uint4*)(Yp + k * 8) = *(const uint4*)(tp + k * 8);
  }
}

// ---------------- mega-fused attention phase (v5: v4 + fewer barriers + native cvt) ----------------
__global__ __launch_bounds__(256) void attn_mega(PtrB4 stks,
    const unsigned short* __restrict__ Wab,
    const float* __restrict__ b_in, const float* __restrict__ b_out,
    const float* __restrict__ alphas, const float* __restrict__ fus_b,
    const float* __restrict__ fq, unsigned short* __restrict__ fbuf,
    float* __restrict__ S, int N) {
  __shared__ __align__(16) unsigned short q_s[64 * 136];  // Q -> O
  __shared__ __align__(16) unsigned short k_s[64 * 136];  // K -> proj/f
  __shared__ __align__(16) unsigned short v_s[64 * 136];  // V
  __shared__ float lred[4];
  size_t NK = (size_t)N * DD;

  int tid = threadIdx.x;
  int wave = tid >> 6, lane = tid & 63;
  int r16 = lane & 15, kgrp = lane >> 4;
  int rowhalf = wave >> 1, colbase = (wave & 1) * 64;
  int nodebase = blockIdx.x * 16;

  int rlo = rowhalf * 32 + r16;     // 0..63
  int rhi = rlo + 16;
  int nlo = nodebase + (rlo & 15); if (nlo >= N) nlo = N - 1;
  int nhi = nodebase + (rhi & 15); if (nhi >= N) nhi = N - 1;
  const unsigned short* a0p = stks.p[rlo >> 4] + (size_t)nlo * DD + kgrp * 8;
  const unsigned short* a1p = stks.p[rhi >> 4] + (size_t)nhi * DD + kgrp * 8;

  // ---- Phase 1: Q,K,V GEMMs (A regs shared across the three) ----
  {
    short8 A0[4], A1[4];
#pragma unroll
    for (int s = 0; s < 4; ++s) {
      A0[s] = *(const short8*)(a0p + s * 32);
      A1[s] = *(const short8*)(a1p + s * 32);
    }
    for (int o = 0; o < 3; ++o) {
      const unsigned short* W = Wab + o * 16384;
      short8 b[4][4];
#pragma unroll
      for (int s = 0; s < 4; ++s)
#pragma unroll
        for (int cn = 0; cn < 4; ++cn)
          b[s][cn] = *(const short8*)(W + ((colbase + cn * 16 + r16) << 7) + s * 32 + kgrp * 8);
      f32x4 acc[2][4];
#pragma unroll
      for (int rt = 0; rt < 2; ++rt)
#pragma unroll
        for (int cn = 0; cn < 4; ++cn)
#pragma unroll
          for (int j = 0; j < 4; ++j) acc[rt][cn][j] = 0.f;
#pragma unroll
      for (int s = 0; s < 4; ++s)
#pragma unroll
        for (int cn = 0; cn < 4; ++cn) {
          acc[0][cn] = __builtin_amdgcn_mfma_f32_16x16x32_bf16(A0[s], b[s][cn], acc[0][cn], 0, 0, 0);
          acc[1][cn] = __builtin_amdgcn_mfma_f32_16x16x32_bf16(A1[s], b[s][cn], acc[1][cn], 0, 0, 0);
        }
      unsigned short* dst = (o == 0) ? q_s : (o == 1) ? k_s : v_s;
#pragma unroll
      for (int rt = 0; rt < 2; ++rt)
#pragma unroll
        for (int cn = 0; cn < 4; ++cn) {
          int col = colbase + cn * 16 + r16;
          float bb = b_in[o * DD + col];
#pragma unroll
          for (int i = 0; i < 4; ++i) {
            int wrow = rowhalf * 32 + rt * 16 + kgrp * 4 + i;
            dst[SWIDX(wrow, col)] = f2bf(acc[rt][cn][i] + bb);
          }
        }
    }
  }
  __syncthreads();

  // ---- Phase 2: scores -> p[4] regs (wave owns nodes wave*4..+3) ----
  float p[4];
  {
    int h = lane >> 4, li = (lane >> 2) & 3, m = lane & 3;
    for (int t = 0; t < 4; ++t) {
      int nd = wave * 4 + t;
      float sc = 0.f;
#pragma unroll
      for (int s4 = 0; s4 < 4; ++s4) {
        short8 qv = *(const short8*)&q_s[SWIDX(li * 16 + nd, h * 32 + s4 * 8)];
        short8 kv = *(const short8*)&k_s[SWIDX(m * 16 + nd, h * 32 + s4 * 8)];
#pragma unroll
        for (int j = 0; j < 8; ++j) sc += bfe(qv[j]) * bfe(kv[j]);
      }
      sc *= 0.17677669529663687f;              // 1/sqrt(32)
      float mx = sc;
      mx = fmaxf(mx, __shfl_xor(mx, 1));
      mx = fmaxf(mx, __shfl_xor(mx, 2));
      float e = expf(sc - mx);
      float sum = e;
      sum += __shfl_xor(sum, 1);
      sum += __shfl_xor(sum, 2);
      p[t] = e / sum;                          // lane holds p[h][li][m] for node nd
    }
  }
  __syncthreads();   // score reads done before O overwrites q_s

  // ---- Phase 3: PV -> O into q_s (p via shuffles; wave-local nodes) ----
  {
    int c0 = lane * 2, hh = lane >> 4;   // hh = c0>>5
    for (int t = 0; t < 4; ++t) {
      int nd = wave * 4 + t;
      unsigned v[4];
#pragma unroll
      for (int m = 0; m < 4; ++m)
        v[m] = *(const unsigned*)&v_s[SWIDX(m * 16 + nd, c0)];
#pragma unroll
      for (int lo = 0; lo < 4; ++lo) {
        float ol = 0.f, oh = 0.f;
#pragma unroll
        for (int m = 0; m < 4; ++m) {
          float pm = __shfl(p[t], hh * 16 + lo * 4 + m);
          ol += pm * bf_lo(v[m]);
          oh += pm * bf_hi(v[m]);
        }
        *(unsigned*)&q_s[SWIDX(lo * 16 + nd, c0)] = pack2(ol, oh);
      }
    }
  }
  __syncthreads();

  // ---- Phase 4: out-proj (A = O from q_s) -> k_s holds y + b_out ----
  {
    const unsigned short* W = Wab + 3 * 16384;
    short8 b[4][4];
#pragma unroll
    for (int s = 0; s < 4; ++s)
#pragma unroll
      for (int cn = 0; cn < 4; ++cn)
        b[s][cn] = *(const short8*)(W + ((colbase + cn * 16 + r16) << 7) + s * 32 + kgrp * 8);
    short8 AO0[4], AO1[4];
#pragma unroll
    for (int s = 0; s < 4; ++s) {
      AO0[s] = *(const short8*)&q_s[SWIDX(rlo, s * 32 + kgrp * 8)];
      AO1[s] = *(const short8*)&q_s[SWIDX(rhi, s * 32 + kgrp * 8)];
    }
    f32x4 acc[2][4];
#pragma unroll
    for (int rt = 0; rt < 2; ++rt)
#pragma unroll
      for (int cn = 0; cn < 4; ++cn)
#pragma unroll
        for (int j = 0; j < 4; ++j) acc[rt][cn][j] = 0.f;
#pragma unroll
    for (int s = 0; s < 4; ++s)
#pragma unroll
      for (int cn = 0; cn < 4; ++cn) {
        acc[0][cn] = __builtin_amdgcn_mfma_f32_16x16x32_bf16(AO0[s], b[s][cn], acc[0][cn], 0, 0, 0);
        acc[1][cn] = __builtin_amdgcn_mfma_f32_16x16x32_bf16(AO1[s], b[s][cn], acc[1][cn], 0, 0, 0);
      }
    // K-reads of k_s ended at the phase-2->3 barrier; safe to overwrite now.
#pragma unroll
    for (int rt = 0; rt < 2; ++rt)
#pragma unroll
      for (int cn = 0; cn < 4; ++cn) {
        int col = colbase + cn * 16 + r16;
        float bb = b_out[col];
#pragma unroll
        for (int i = 0; i < 4; ++i) {
          int wrow = rowhalf * 32 + rt * 16 + kgrp * 4 + i;
          k_s[SWIDX(wrow, col)] = f2bf(acc[rt][cn][i] + bb);
        }
      }
  }
  __syncthreads();

  // ---- Phase 5: blend with stk, store f to global, write back to k_s ----
  {
    if (tid < 4) lred[tid] = 0.f;
    int orow = tid >> 2, seg = tid & 3;
    int lb = orow >> 4, nb = nodebase + (orow & 15);
    if (nb < N) {
      float aa = alphas[lb], na = 1.f - aa;
      const unsigned short* sp = stks.p[lb] + (size_t)nb * DD + seg * 32;
      unsigned short* Yp = fbuf + (size_t)lb * NK + (size_t)nb * DD + seg * 32;
#pragma unroll
      for (int k = 0; k < 4; ++k) {
        unsigned short* tp = &k_s[SWIDX(orow, seg * 32 + k * 8)];
        uint4 pv = *(const uint4*)tp;
        uint4 sv = *(const uint4*)(sp + k * 8);
        const unsigned* pw = &pv.x;
        const unsigned* sw = &sv.x;
        uint4 o; unsigned* ow = &o.x;
#pragma unroll
        for (int j = 0; j < 4; ++j)
          ow[j] = pack2(aa * bf_lo(pw[j]) + na * bf_lo(sw[j]),
                        aa * bf_hi(pw[j]) + na * bf_hi(sw[j]));
        *(uint4*)(Yp + k * 8) = o;
        *(uint4*)tp = o;
      }
    }
  }
  __syncthreads();

  // ---- Phase 6: fusion GEMM on f (k_s) + leaky*fq score reduce ----
  {
    const unsigned short* W = Wab + 4 * 16384;
    short8 b[4][4];
#pragma unroll
    for (int s = 0; s < 4; ++s)
#pragma unroll
      for (int cn = 0; cn < 4; ++cn)
        b[s][cn] = *(const short8*)(W + ((colbase + cn * 16 + r16) << 7) + s * 32 + kgrp * 8);
    short8 AF0[4], AF1[4];
#pragma unroll
    for (int s = 0; s < 4; ++s) {
      AF0[s] = *(const short8*)&k_s[SWIDX(rlo, s * 32 + kgrp * 8)];
      AF1[s] = *(const short8*)&k_s[SWIDX(rhi, s * 32 + kgrp * 8)];
    }
    f32x4 acc[2][4];
#pragma unroll
    for (int rt = 0; rt < 2; ++rt)
#pragma unroll
      for (int cn = 0; cn < 4; ++cn)
#pragma unroll
        for (int j = 0; j < 4; ++j) acc[rt][cn][j] = 0.f;
#pragma unroll
    for (int s = 0; s < 4; ++s)
#pragma unroll
      for (int cn = 0; cn < 4; ++cn) {
        acc[0][cn] = __builtin_amdgcn_mfma_f32_16x16x32_bf16(AF0[s], b[s][cn], acc[0][cn], 0, 0, 0);
        acc[1][cn] = __builtin_amdgcn_mfma_f32_16x16x32_bf16(AF1[s], b[s][cn], acc[1][cn], 0, 0, 0);
      }
    float ss0 = 0.f, ss1 = 0.f;
#pragma unroll
    for (int cn = 0; cn < 4; ++cn) {
      int col = colbase + cn * 16 + r16;
      float bb = fus_b[col];
      float qc = fq[col];
#pragma unroll
      for (int i = 0; i < 4; ++i) {
        if (nodebase + kgrp * 4 + i < N) {
          float y0 = acc[0][cn][i] + bb;
          float y1 = acc[1][cn][i] + bb;
          ss0 += (y0 > 0.f ? y0 : 0.01f * y0) * qc;
          ss1 += (y1 > 0.f ? y1 : 0.01f * y1) * qc;
        }
      }
    }
    atomicAdd(&lred[rowhalf * 2], ss0);
    atomicAdd(&lred[rowhalf * 2 + 1], ss1);
    __syncthreads();
    if (tid < 4) atomicAdd(S + tid, lred[tid]);
  }
}

// ---------------- GCN aggregation: CSR gather, 2 nodes/wave, unroll x8 ----------------
__global__ __launch_bounds__(256) void gather_agg(const int* __restrict__ srcbuf,
                                                  const int* __restrict__ offs,
                                                  const int* __restrict__ deg,
                                                  const float* __restrict__ dinv,
                                                  const uint2* __restrict__ Bs2,
                                                  const float* __restrict__ bias,
                                                  uint2* __restrict__ Ab2, int N4) {
  int rn = blockIdx.x * 8 + (threadIdx.x >> 5);
  if (rn >= N4) return;
  int lane = threadIdx.x & 31;
  int st = offs[rn], cnt = deg[rn];
  uint2 u = Bs2[(size_t)rn * 32 + lane];        // self message
  float a0 = bf_lo(u.x), a1 = bf_hi(u.x), a2 = bf_lo(u.y), a3 = bf_hi(u.y);
  int e = 0;
  for (; e + 8 <= cnt; e += 8) {
    int rr[8];
#pragma unroll
    for (int j = 0; j < 8; ++j) rr[j] = srcbuf[st + e + j];
    uint2 vv[8];
#pragma unroll
    for (int j = 0; j < 8; ++j) vv[j] = Bs2[(size_t)rr[j] * 32 + lane];
#pragma unroll
    for (int j = 0; j < 8; ++j) {
      a0 += bf_lo(vv[j].x); a1 += bf_hi(vv[j].x);
      a2 += bf_lo(vv[j].y); a3 += bf_hi(vv[j].y);
    }
  }
  if (e + 4 <= cnt) {
    int rr[4];
#pragma unroll
    for (int j = 0; j < 4; ++j) rr[j] = srcbuf[st + e + j];
    uint2 vv[4];
#pragma unroll
    for (int j = 0; j < 4; ++j) vv[j] = Bs2[(size_t)rr[j] * 32 + lane];
#pragma unroll
    for (int j = 0; j < 4; ++j) {
      a0 += bf_lo(vv[j].x); a1 += bf_hi(vv[j].x);
      a2 += bf_lo(vv[j].y); a3 += bf_hi(vv[j].y);
    }
    e += 4;
  }
  for (; e < cnt; ++e) {
    uint2 v = Bs2[(size_t)srcbuf[st + e] * 32 + lane];
    a0 += bf_lo(v.x); a1 += bf_hi(v.x); a2 += bf_lo(v.y); a3 += bf_hi(v.y);
  }
  float dvv = dinv[rn];
  int c = lane * 4;
  uint2 o;
  o.x = pack2(a0 * dvv + bias[c],     a1 * dvv + bias[c + 1]);
  o.y = pack2(a2 * dvv + bias[c + 2], a3 * dvv + bias[c + 3]);
  Ab2[(size_t)rn * 32 + lane] = o;
}

// ---------------- batchnorm ----------------

__global__ void bn_stats(const unsigned* __restrict__ Ab2, float* __restrict__ sums, int N) {
  int r = blockIdx.y;
  int lane = threadIdx.x & 63, grp = threadIdx.x >> 6;
  float s0 = 0.f, q0 = 0.f, s1 = 0.f, q1 = 0.f;
  const unsigned* base = Ab2 + (size_t)r * N * 64;
  for (int n = blockIdx.x * 4 + grp; n < N; n += gridDim.x * 4) {
    unsigned u = base[(size_t)n * 64 + lane];
    float a = bf_lo(u), b = bf_hi(u);
    s0 += a; q0 += a * a; s1 += b; q1 += b * b;
  }
  __shared__ float sh[4][64][4];
  sh[grp][lane][0] = s0; sh[grp][lane][1] = q0; sh[grp][lane][2] = s1; sh[grp][lane][3] = q1;
  __syncthreads();
  if (grp == 0) {
#pragma unroll
    for (int g = 1; g < 4; ++g) {
      s0 += sh[g][lane][0]; q0 += sh[g][lane][1]; s1 += sh[g][lane][2]; q1 += sh[g][lane][3];
    }
    int c0 = lane * 2;
    atomicAdd(sums + (r * DD + c0) * 2, s0);
    atomicAdd(sums + (r * DD + c0) * 2 + 1, q0);
    atomicAdd(sums + (r * DD + c0 + 1) * 2, s1);
    atomicAdd(sums + (r * DD + c0 + 1) * 2 + 1, q1);
  }
}

__global__ void bn_final(const float* __restrict__ sums, const float* __restrict__ gamma,
                         const float* __restrict__ beta, float* __restrict__ ss, int N) {
  int t = threadIdx.x;       // 512 = r*128+c
  int c = t & 127;
  float mu = sums[t * 2] / N;
  float var = sums[t * 2 + 1] / N - mu * mu;
  float sc = gamma[c] * rsqrtf(var + 1e-5f);
  ss[t * 2] = sc;
  ss[t * 2 + 1] = beta[c] - mu * sc;
}

// w = softmax([S(f0),S(f1),S(f3),S(f2)]);  coef[l] multiplies f[l]: coef = [w0,w1,w3,w2]
__global__ void wcoef(const float* __restrict__ S, float* __restrict__ coef, int N) {
  if (threadIdx.x == 0) {
    float v0 = S[0] / N, v1 = S[1] / N, v2 = S[3] / N, v3 = S[2] / N;
    float mx = fmaxf(fmaxf(v0, v1), fmaxf(v2, v3));
    float e0 = expf(v0 - mx), e1 = expf(v1 - mx), e2 = expf(v2 - mx), e3 = expf(v3 - mx);
    float inv = 1.f / (e0 + e1 + e2 + e3);
    coef[0] = e0 * inv; coef[1] = e1 * inv; coef[2] = e3 * inv; coef[3] = e2 * inv;
  }
}

__device__ __forceinline__ float bfat(uint2 u, int j) {
  unsigned w = (j < 2) ? u.x : u.y;
  return (j & 1) ? bf_hi(w) : bf_lo(w);
}

// region = sum coef[l]*f[l]; outputs: region, region*rels3[{3,0,1,2}]
__global__ void final_out(const unsigned short* __restrict__ fb, const float* __restrict__ coef,
                          const float* __restrict__ rels3, float* __restrict__ out, int N) {
  size_t NK = (size_t)N * DD;
  size_t i4 = (size_t)blockIdx.x * 256 + threadIdx.x;  // 4-elem groups
  if (i4 >= NK / 4) return;
  size_t g = i4 * 4;
  int c = (int)(g & 127);
  float c0 = coef[0], c1 = coef[1], c2 = coef[2], c3 = coef[3];
  uint2 u0 = *(const uint2*)(fb + g);
  uint2 u1 = *(const uint2*)(fb + NK + g);
  uint2 u2 = *(const uint2*)(fb + 2 * NK + g);
  uint2 u3 = *(const uint2*)(fb + 3 * NK + g);
  float4 reg4, o1, o2, o3, o4;
  float* rp = &reg4.x; float* p1 = &o1.x; float* p2 = &o2.x; float* p3 = &o3.x; float* p4 = &o4.x;
#pragma unroll
  for (int j = 0; j < 4; ++j) {
    float region = c0 * bfat(u0, j) + c1 * bfat(u1, j) + c2 * bfat(u2, j) + c3 * bfat(u3, j);
    rp[j] = region;
    p1[j] = region * rels3[3 * DD + c + j];
    p2[j] = region * rels3[0 * DD + c + j];
    p3[j] = region * rels3[1 * DD + c + j];
    p4[j] = region * rels3[2 * DD + c + j];
  }
  *(float4*)(out + g) = reg4;
  *(float4*)(out + NK + g) = o1;
  *(float4*)(out + 2 * NK + g) = o2;
  *(float4*)(out + 3 * NK + g) = o3;
  *(float4*)(out + 4 * NK + g) = o4;
}

// ---------------- host ----------------

extern "C" void kernel_launch(void* const* d_in, const int* in_sizes, int n_in,
                              void* d_out, int out_size, void* d_ws, size_t ws_size,
                              hipStream_t stream) {
  const float* features  = (const float*)d_in[0];
  const float* rel_emb   = (const float*)d_in[1];
  const int*   edge_idx  = (const int*)d_in[2];
  const float* W_gcn     = (const float*)d_in[3];
  const float* b_gcn     = (const float*)d_in[4];
  const float* bn_gamma  = (const float*)d_in[5];
  const float* bn_beta   = (const float*)d_in[6];
  const float* W_rt      = (const float*)d_in[7];
  const float* b_rt      = (const float*)d_in[8];
  const float* attn_w_in = (const float*)d_in[9];
  const float* attn_b_in = (const float*)d_in[10];
  const float* attn_wout = (const float*)d_in[11];
  const float* attn_bout = (const float*)d_in[12];
  const float* alphas    = (const float*)d_in[13];
  const float* fusion_q  = (const float*)d_in[14];
  const float* fusion_w  = (const float*)d_in[15];
  const float* fusion_b  = (const float*)d_in[16];

  int N = in_sizes[0] / DD;                  // 50000
  int E = in_sizes[2] / (2 * NREL);          // 400000
  size_t NK = (size_t)N * DD;
  int N4 = 4 * N;

  unsigned short* Xb = (unsigned short*)d_ws;            // 4*NK (emb1)
  unsigned short* Bs = Xb + 4 * NK;                      // 4*NK (messages / f)
  unsigned short* Ab = Bs + 4 * NK;                      // 4*NK (agg / stack)
  unsigned short* Ub = Ab + 4 * NK;                      // 4*NK (spare)
  unsigned short* Fb = Ub + 4 * NK;                      // NK (bf16 features, shared)
  float* dinv  = (float*)(Fb + NK);                      // 4*N
  unsigned short* Wgcnb = (unsigned short*)(dinv + N4);  // 4*16384
  unsigned short* Wab   = Wgcnb + 4 * DD * DD;           // 5*16384
  float* rels  = (float*)(Wab + 5 * DD * DD);            // 4 stages * 512
  float* bnsum = rels + 4 * 512;                         // 1024
  float* bnss  = bnsum + 1024;                           // 1024
  float* S     = bnss + 1024;                            // 4
  float* coef  = S + 4;                                  // 4
  int* deg_i   = (int*)(coef + 4);                       // 4*N
  int* offs    = deg_i + N4;                             // 4*N
  int* cur     = offs + N4;                              // 4*N
  int* bsums   = cur + N4;                               // 1024
  int* srcb    = bsums + 1024;                           // 4*E

  size_t needed = (size_t)((char*)(srcb + 4 * E) - (char*)d_ws);
  if (ws_size < needed) {
    fprintf(stderr, "kernel_launch: ws too small (%zu < %zu)\n", ws_size, needed);
    return;
  }

  int gemmGrid = (N + 63) / 64;
  int scanBlocks = (N4 + 255) / 256;
  int egrid4 = (E + 1023) / 1024;

  // ---- CSR build (edges fixed across layers) ----
  (void)hipMemsetAsync(deg_i, 0, (size_t)N4 * sizeof(int), stream);
  count_deg<<<dim3(egrid4, 4), 256, 0, stream>>>(edge_idx, deg_i, N, E);
  finalize_dinv<<<scanBlocks, 256, 0, stream>>>(deg_i, dinv, N4);
  scan_block<<<scanBlocks, 256, 0, stream>>>(deg_i, offs, bsums, N4);
  scan_sums<<<1, 1024, 0, stream>>>(bsums, scanBlocks);
  scan_add<<<scanBlocks, 256, 0, stream>>>(offs, cur, bsums, N4);
  fill_edges<<<dim3(egrid4, 4), 256, 0, stream>>>(edge_idx, cur, srcb, N, E);

  rels_init<<<1, 512, 0, stream>>>(rel_emb, rels);
  conv_w<<<5 * 16384 / 256, 256, 0, stream>>>(attn_w_in, attn_wout, fusion_w, Wab);
  conv_f2b<<<(int)((NK / 4 + 255) / 256), 256, 0, stream>>>(features, (unsigned*)Fb, NK / 4);

  PtrB4 wz, abIn, resIn;
  OutB4 msgOut, xbOut, dummyO;
  for (int r = 0; r < 4; ++r) {
    wz.p[r] = Wgcnb + (size_t)r * DD * DD;
    abIn.p[r] = Ab + (size_t)r * NK;
    msgOut.p[r] = Bs + (size_t)r * NK;
    xbOut.p[r] = Xb + (size_t)r * NK;
    dummyO.p[r] = nullptr;
  }

  // ---- Layer 0 ----
  scale_w_bf<<<256, 256, 0, stream>>>(rels, W_gcn, Wgcnb);
  {
    PtrB4 xs; for (int r = 0; r < 4; ++r) xs.p[r] = Fb;
    gemm_ws<0><<<dim3(gemmGrid, 4), 256, 0, stream>>>(xs, wz, msgOut, nullptr, dinv, N);
  }
  gather_agg<<<(N4 + 7) / 8, 256, 0, stream>>>(srcb, offs, deg_i, dinv, (const uint2*)Bs,
                                               b_gcn, (uint2*)Ab, N4);
  (void)hipMemsetAsync(bnsum, 0, 1024 * sizeof(float), stream);
  bn_stats<<<dim3(400, 4), 256, 0, stream>>>((const unsigned*)Ab, bnsum, N);
  bn_final<<<1, 512, 0, stream>>>(bnsum, bn_gamma, bn_beta, bnss, N);
  rels_update<<<1, 512, 0, stream>>>(rels, W_rt, b_rt, rels + 512);

  // ---- Layer 1 (fused BN-update, writeback emb1) ----
  scale_w_bf<<<256, 256, 0, stream>>>(rels + 512, W_gcn + (size_t)DD * DD, Wgcnb);
  for (int r = 0; r < 4; ++r) resIn.p[r] = Fb;           // emb0 = features (shared)
  gemm_upd<1><<<dim3(gemmGrid, 4), 256, 0, stream>>>(resIn, abIn, wz, xbOut, msgOut,
                                                     bnss, dinv, N);
  gather_agg<<<(N4 + 7) / 8, 256, 0, stream>>>(srcb, offs, deg_i, dinv, (const uint2*)Bs,
                                               b_gcn + DD, (uint2*)Ab, N4);
  (void)hipMemsetAsync(bnsum, 0, 1024 * sizeof(float), stream);
  bn_stats<<<dim3(400, 4), 256, 0, stream>>>((const unsigned*)Ab, bnsum, N);
  bn_final<<<1, 512, 0, stream>>>(bnsum, bn_gamma + DD, bn_beta + DD, bnss, N);
  rels_update<<<1, 512, 0, stream>>>(rels + 512, W_rt + (size_t)DD * DD, b_rt + DD, rels + 1024);

  // ---- Layer 2 (fused BN-update, no writeback) ----
  scale_w_bf<<<256, 256, 0, stream>>>(rels + 1024, W_gcn + (size_t)2 * DD * DD, Wgcnb);
  for (int r = 0; r < 4; ++r) resIn.p[r] = Xb + (size_t)r * NK;   // emb1
  gemm_upd<0><<<dim3(gemmGrid, 4), 256, 0, stream>>>(resIn, abIn, wz, dummyO, msgOut,
                                                     bnss, dinv, N);
  gather_agg<<<(N4 + 7) / 8, 256, 0, stream>>>(srcb, offs, deg_i, dinv, (const uint2*)Bs,
                                               b_gcn + 2 * DD, (uint2*)Ab, N4);
  rels_update<<<1, 512, 0, stream>>>(rels + 1024, W_rt + (size_t)2 * DD * DD, b_rt + 2 * DD,
                                     rels + 1536);
  // Ab = final GCN outputs (stack source). Xb, Bs, Ub free.

  const int pstk[4] = {3, 0, 2, 1};
  PtrB4 stk;
  for (int l = 0; l < 4; ++l) stk.p[l] = Ab + (size_t)pstk[l] * NK;

  (void)hipMemsetAsync(S, 0, 4 * sizeof(float), stream);
  attn_mega<<<(N + 15) / 16, 256, 0, stream>>>(stk, Wab, attn_b_in, attn_bout, alphas,
                                               fusion_b, fusion_q, Bs, S, N);
  wcoef<<<1, 64, 0, stream>>>(S, coef, N);
  final_out<<<(int)((NK / 4 + 255) / 256), 256, 0, stream>>>(Bs, coef, rels + 1536,
                                                             (float*)d_out, N);
}

// Round 15
// 932.550 us; speedup vs baseline: 1.0844x; 1.0164x over previous
//
#include <hip/hip_runtime.h>
#include <hip/hip_bf16.h>
#include <cstdio>

#define DD 128
#define NREL 4

using short8 = __attribute__((ext_vector_type(8))) short;
using f32x4  = __attribute__((ext_vector_type(4))) float;

struct PtrB4 { const unsigned short* p[4]; };
struct OutB4 { unsigned short* p[4]; };

// processing-order relation r uses edge_index/rel_emb row (r+3)&3  (perm = [3,0,1,2])
__device__ __forceinline__ int edge_perm(int r) { return (r + 3) & 3; }

__device__ __forceinline__ float bf_lo(unsigned u) { return __uint_as_float(u << 16); }
__device__ __forceinline__ float bf_hi(unsigned u) { return __uint_as_float(u & 0xffff0000u); }
__device__ __forceinline__ float bfe(short s) {
  return __uint_as_float(((unsigned)(unsigned short)s) << 16);
}
// native RNE converts (compiler emits v_cvt_pk_bf16_f32 for adjacent pairs)
__device__ __forceinline__ unsigned short f2bf(float f) {
  return __bfloat16_as_ushort(__float2bfloat16(f));
}
__device__ __forceinline__ unsigned pack2(float a, float b) {
  return (unsigned)f2bf(a) | ((unsigned)f2bf(b) << 16);
}

// swizzled LDS index for 64x136-short tiles: rows 16 apart land on distinct banks
#define SWIDX(row, col) ((row) * 136 + ((col) ^ ((((row) >> 4) & 3) << 4)))

// ---------------- init / weight prep ----------------

__global__ void rels_init(const float* __restrict__ rel_emb, float* __restrict__ rels) {
  int t = threadIdx.x;              // 512 = r*128 + c
  int r = t >> 7, c = t & 127;
  rels[t] = rel_emb[edge_perm(r) * DD + c];
}

__global__ void rels_update(const float* __restrict__ rin, const float* __restrict__ Wrt,
                            const float* __restrict__ brt, float* __restrict__ rout) {
  int t = threadIdx.x;  // 512 = r*128 + j
  int r = t >> 7, j = t & 127;
  float s = brt[j];
  const float* wr = Wrt + j * DD;
  const float* xr = rin + r * DD;
  for (int c = 0; c < DD; ++c) s += xr[c] * wr[c];
  rout[t] = s;
}

// Wsb[r][j][c] = bf16(rels[r][c] * Wg[c][j])  -- MFMA-B layout [n=j][k=c]
__global__ void scale_w_bf(const float* __restrict__ rels_i, const float* __restrict__ Wg,
                           unsigned short* __restrict__ Wsb) {
  int i = blockIdx.x * 256 + threadIdx.x;   // 4*16384
  int r = i >> 14, rem = i & 16383, j = rem >> 7, c = rem & 127;
  Wsb[i] = f2bf(rels_i[r * DD + c] * Wg[c * DD + j]);
}

// Wab = bf16( attn_w_in (3*16384) || attn_wout (16384) || fusion_w (16384) ), all [j][c]
__global__ void conv_w(const float* __restrict__ w_in, const float* __restrict__ w_out,
                       const float* __restrict__ w_fus, unsigned short* __restrict__ Wab) {
  int i = blockIdx.x * 256 + threadIdx.x;   // 5*16384
  float v = (i < 49152) ? w_in[i] : (i < 65536 ? w_out[i - 49152] : w_fus[i - 65536]);
  Wab[i] = f2bf(v);
}

// fp32 -> bf16 single slice
__global__ void conv_f2b(const float* __restrict__ in, unsigned* __restrict__ out2, size_t n4) {
  size_t i = (size_t)blockIdx.x * 256 + threadIdx.x;
  if (i < n4) {
    float4 v = ((const float4*)in)[i];
    out2[i * 2]     = pack2(v.x, v.y);
    out2[i * 2 + 1] = pack2(v.z, v.w);
  }
}

// ---------------- CSR build ----------------

__global__ void count_deg(const int* __restrict__ ei, int* __restrict__ deg, int N, int E) {
  int r = blockIdx.y;
  int base = blockIdx.x * 1024 + threadIdx.x;
  const int* dsts = ei + (size_t)edge_perm(r) * 2 * E + E;
#pragma unroll
  for (int k = 0; k < 4; ++k) {
    int e = base + k * 256;
    if (e < E) atomicAdd(deg + (size_t)r * N + dsts[e], 1);
  }
}

__global__ void finalize_dinv(const int* __restrict__ deg, float* __restrict__ dinv, int total) {
  int i = blockIdx.x * 256 + threadIdx.x;
  if (i < total) dinv[i] = rsqrtf((float)deg[i] + 1.0f);
}

__global__ void scan_block(const int* __restrict__ deg, int* __restrict__ excl,
                           int* __restrict__ bsums, int n) {
  __shared__ int sh[256];
  int i = blockIdx.x * 256 + threadIdx.x;
  int v = (i < n) ? deg[i] : 0;
  sh[threadIdx.x] = v;
  __syncthreads();
  for (int st = 1; st < 256; st <<= 1) {
    int t = (threadIdx.x >= st) ? sh[threadIdx.x - st] : 0;
    __syncthreads();
    sh[threadIdx.x] += t;
    __syncthreads();
  }
  if (i < n) excl[i] = sh[threadIdx.x] - v;
  if (threadIdx.x == 255) bsums[blockIdx.x] = sh[255];
}

__global__ void scan_sums(int* __restrict__ bsums, int nb) {
  __shared__ int sh[1024];
  int v = (threadIdx.x < nb) ? bsums[threadIdx.x] : 0;
  sh[threadIdx.x] = v;
  __syncthreads();
  for (int st = 1; st < 1024; st <<= 1) {
    int t = (threadIdx.x >= st) ? sh[threadIdx.x - st] : 0;
    __syncthreads();
    sh[threadIdx.x] += t;
    __syncthreads();
  }
  if (threadIdx.x < nb) bsums[threadIdx.x] = sh[threadIdx.x] - v;  // exclusive
}

__global__ void scan_add(int* __restrict__ excl, int* __restrict__ cursor,
                         const int* __restrict__ bsums, int n) {
  int i = blockIdx.x * 256 + threadIdx.x;
  if (i < n) {
    int o = excl[i] + bsums[blockIdx.x];
    excl[i] = o;
    cursor[i] = o;
  }
}

// 4 edges/thread: 4 independent atomic-returns in flight
__global__ void fill_edges(const int* __restrict__ ei, int* __restrict__ cursor,
                           int* __restrict__ srcbuf, int N, int E) {
  int r = blockIdx.y;
  int base = blockIdx.x * 1024 + threadIdx.x;
  const int* bp = ei + (size_t)edge_perm(r) * 2 * E;
  int s[4], d[4], pos[4];
#pragma unroll
  for (int k = 0; k < 4; ++k) {
    int e = base + k * 256;
    s[k] = (e < E) ? bp[e] : 0;
    d[k] = (e < E) ? bp[E + e] : 0;
  }
#pragma unroll
  for (int k = 0; k < 4; ++k) {
    int e = base + k * 256;
    if (e < E) pos[k] = atomicAdd(&cursor[r * N + d[k]], 1);
  }
#pragma unroll
  for (int k = 0; k < 4; ++k) {
    int e = base + k * 256;
    if (e < E) srcbuf[pos[k]] = r * N + s[k];
  }
}

// ---------------- weight-stationary MFMA GEMM (round-7 proven) ----------------
// Block 256 = 4 waves: wave = (rowhalf<<1)|colhalf; each wave: 32 rows x 64 cols.
// MODE 0: out bf16 = y * dinv[z*M+row]           (GCN messages)
template <int MODE>
__global__ __launch_bounds__(256) void gemm_ws(PtrB4 xs, PtrB4 wz, OutB4 ys,
                                               const float* __restrict__ bias,
                                               const float* __restrict__ dinv, int M) {
  int z = blockIdx.y;
  const unsigned short* __restrict__ X = xs.p[z];
  const unsigned short* __restrict__ W = wz.p[z];
  int tid = threadIdx.x;
  int wave = tid >> 6, lane = tid & 63;
  int r16 = lane & 15, kgrp = lane >> 4;
  int rowhalf = wave >> 1, colbase = (wave & 1) * 64;
  int blockrow = blockIdx.x * 64;

  short8 b[4][4];
#pragma unroll
  for (int s = 0; s < 4; ++s)
#pragma unroll
    for (int cn = 0; cn < 4; ++cn)
      b[s][cn] = *(const short8*)(W + ((colbase + cn * 16 + r16) << 7) + s * 32 + kgrp * 8);

  int row0 = blockrow + rowhalf * 32 + r16;
  int r0c = row0 < M ? row0 : M - 1;
  int r1c = row0 + 16 < M ? row0 + 16 : M - 1;
  short8 a[2][4];
#pragma unroll
  for (int s = 0; s < 4; ++s) {
    a[0][s] = *(const short8*)(X + (size_t)r0c * DD + s * 32 + kgrp * 8);
    a[1][s] = *(const short8*)(X + (size_t)r1c * DD + s * 32 + kgrp * 8);
  }

  f32x4 acc[2][4];
#pragma unroll
  for (int rt = 0; rt < 2; ++rt)
#pragma unroll
    for (int cn = 0; cn < 4; ++cn)
#pragma unroll
      for (int j = 0; j < 4; ++j) acc[rt][cn][j] = 0.f;

#pragma unroll
  for (int s = 0; s < 4; ++s)
#pragma unroll
    for (int rt = 0; rt < 2; ++rt)
#pragma unroll
      for (int cn = 0; cn < 4; ++cn)
        acc[rt][cn] = __builtin_amdgcn_mfma_f32_16x16x32_bf16(a[rt][s], b[s][cn], acc[rt][cn], 0, 0, 0);

  __shared__ __align__(16) unsigned short tile[64][DD + 8];
  float dv[2][4];
  if constexpr (MODE == 0) {
#pragma unroll
    for (int rt = 0; rt < 2; ++rt)
#pragma unroll
      for (int i = 0; i < 4; ++i) {
        int row = blockrow + rowhalf * 32 + rt * 16 + kgrp * 4 + i;
        dv[rt][i] = dinv[(size_t)z * M + (row < M ? row : 0)];
      }
  }
#pragma unroll
  for (int rt = 0; rt < 2; ++rt)
#pragma unroll
    for (int cn = 0; cn < 4; ++cn) {
      int col = colbase + cn * 16 + r16;
#pragma unroll
      for (int i = 0; i < 4; ++i) {
        int wrow = rowhalf * 32 + rt * 16 + kgrp * 4 + i;
        float y = acc[rt][cn][i];
        if constexpr (MODE == 0) y *= dv[rt][i];
        tile[wrow][col] = f2bf(y);
      }
    }
  __syncthreads();
  int orow = tid >> 2, seg = tid & 3;
  int grow = blockrow + orow;
  if (grow < M) {
    unsigned short* Yp = ys.p[z] + (size_t)grow * DD + seg * 32;
    const unsigned short* tp = &tile[orow][seg * 32];
#pragma unroll
    for (int k = 0; k < 4; ++k)
      *(uint4*)(Yp + k * 8) = *(const uint4*)(tp + k * 8);
  }
}

// Layers 1/2 fused GEMM (round-7 proven): e = res + leaky(bn(Ab)); optional writeback;
// messages = (e@Wz)*dinv
template <int WB>
__global__ __launch_bounds__(256) void gemm_upd(PtrB4 res, PtrB4 abs_, PtrB4 wz,
                                                OutB4 xout, OutB4 ys,
                                                const float* __restrict__ ssx,
                                                const float* __restrict__ dinv, int M) {
  int z = blockIdx.y;
  const unsigned short* __restrict__ R = res.p[z];
  const unsigned short* __restrict__ A = abs_.p[z];
  const unsigned short* __restrict__ W = wz.p[z];
  int tid = threadIdx.x;

  __shared__ float ssc[DD], ssh[DD];
  if (tid < DD) {
    ssc[tid] = ssx[((size_t)z * DD + tid) * 2];
    ssh[tid] = ssx[((size_t)z * DD + tid) * 2 + 1];
  }
  __syncthreads();

  int wave = tid >> 6, lane = tid & 63;
  int r16 = lane & 15, kgrp = lane >> 4;
  int rowhalf = wave >> 1, colbase = (wave & 1) * 64;
  int blockrow = blockIdx.x * 64;

  short8 b[4][4];
#pragma unroll
  for (int s = 0; s < 4; ++s)
#pragma unroll
    for (int cn = 0; cn < 4; ++cn)
      b[s][cn] = *(const short8*)(W + ((colbase + cn * 16 + r16) << 7) + s * 32 + kgrp * 8);

  int row0 = blockrow + rowhalf * 32 + r16;
  int rc[2];
  rc[0] = row0 < M ? row0 : M - 1;
  rc[1] = row0 + 16 < M ? row0 + 16 : M - 1;
  short8 a[2][4];
#pragma unroll
  for (int rt = 0; rt < 2; ++rt)
#pragma unroll
    for (int s = 0; s < 4; ++s) {
      int cbase = s * 32 + kgrp * 8;
      short8 rv = *(const short8*)(R + (size_t)rc[rt] * DD + cbase);
      short8 av = *(const short8*)(A + (size_t)rc[rt] * DD + cbase);
      unsigned w4p[4];
#pragma unroll
      for (int jj = 0; jj < 4; ++jj) {
        float x0 = bfe(av[2 * jj]) * ssc[cbase + 2 * jj] + ssh[cbase + 2 * jj];
        float x1 = bfe(av[2 * jj + 1]) * ssc[cbase + 2 * jj + 1] + ssh[cbase + 2 * jj + 1];
        x0 = x0 > 0.f ? x0 : 0.01f * x0;
        x1 = x1 > 0.f ? x1 : 0.01f * x1;
        w4p[jj] = pack2(bfe(rv[2 * jj]) + x0, bfe(rv[2 * jj + 1]) + x1);
      }
      uint4 packed = make_uint4(w4p[0], w4p[1], w4p[2], w4p[3]);
      short8 av2;
      __builtin_memcpy(&av2, &packed, sizeof(av2));
      a[rt][s] = av2;
    }
  if (WB) {
#pragma unroll
    for (int rt = 0; rt < 2; ++rt) {
      int row = row0 + rt * 16;
      if (row < M) {
#pragma unroll
        for (int s = 0; s < 4; ++s)
          *(short8*)(xout.p[z] + (size_t)row * DD + s * 32 + kgrp * 8) = a[rt][s];
      }
    }
  }

  f32x4 acc[2][4];
#pragma unroll
  for (int rt = 0; rt < 2; ++rt)
#pragma unroll
    for (int cn = 0; cn < 4; ++cn)
#pragma unroll
      for (int j = 0; j < 4; ++j) acc[rt][cn][j] = 0.f;
#pragma unroll
  for (int s = 0; s < 4; ++s)
#pragma unroll
    for (int rt = 0; rt < 2; ++rt)
#pragma unroll
      for (int cn = 0; cn < 4; ++cn)
        acc[rt][cn] = __builtin_amdgcn_mfma_f32_16x16x32_bf16(a[rt][s], b[s][cn], acc[rt][cn], 0, 0, 0);

  __shared__ __align__(16) unsigned short tile[64][DD + 8];
  float dv[2][4];
#pragma unroll
  for (int rt = 0; rt < 2; ++rt)
#pragma unroll
    for (int i = 0; i < 4; ++i) {
      int row = blockrow + rowhalf * 32 + rt * 16 + kgrp * 4 + i;
      dv[rt][i] = dinv[(size_t)z * M + (row < M ? row : 0)];
    }
#pragma unroll
  for (int rt = 0; rt < 2; ++rt)
#pragma unroll
    for (int cn = 0; cn < 4; ++cn) {
      int col = colbase + cn * 16 + r16;
#pragma unroll
      for (int i = 0; i < 4; ++i) {
        int wrow = rowhalf * 32 + rt * 16 + kgrp * 4 + i;
        tile[wrow][col] = f2bf(acc[rt][cn][i] * dv[rt][i]);
      }
    }
  __syncthreads();
  int orow = tid >> 2, seg = tid & 3;
  int grow = blockrow + orow;
  if (grow < M) {
    unsigned short* Yp = ys.p[z] + (size_t)grow * DD + seg * 32;
    const unsigned short* tp = &tile[orow][seg * 32];
#pragma unroll
    for (int k = 0; k < 4; ++k)
      *(uint4*)(Yp + k * 8) = *(const uint4*)(tp + k * 8);
  }
}

// ---------------- mega-fused attention phase (v5, round-14 proven) ----------------
__global__ __launch_bounds__(256) void attn_mega(PtrB4 stks,
    const unsigned short* __restrict__ Wab,
    const float* __restrict__ b_in, const float* __restrict__ b_out,
    const float* __restrict__ alphas, const float* __restrict__ fus_b,
    const float* __restrict__ fq, unsigned short* __restrict__ fbuf,
    float* __restrict__ S, int N) {
  __shared__ __align__(16) unsigned short q_s[64 * 136];  // Q -> O
  __shared__ __align__(16) unsigned short k_s[64 * 136];  // K -> proj/f
  __shared__ __align__(16) unsigned short v_s[64 * 136];  // V
  __shared__ float lred[4];
  size_t NK = (size_t)N * DD;

  int tid = threadIdx.x;
  int wave = tid >> 6, lane = tid & 63;
  int r16 = lane & 15, kgrp = lane >> 4;
  int rowhalf = wave >> 1, colbase = (wave & 1) * 64;
  int nodebase = blockIdx.x * 16;

  int rlo = rowhalf * 32 + r16;     // 0..63
  int rhi = rlo + 16;
  int nlo = nodebase + (rlo & 15); if (nlo >= N) nlo = N - 1;
  int nhi = nodebase + (rhi & 15); if (nhi >= N) nhi = N - 1;
  const unsigned short* a0p = stks.p[rlo >> 4] + (size_t)nlo * DD + kgrp * 8;
  const unsigned short* a1p = stks.p[rhi >> 4] + (size_t)nhi * DD + kgrp * 8;

  // ---- Phase 1: Q,K,V GEMMs (A regs shared across the three) ----
  {
    short8 A0[4], A1[4];
#pragma unroll
    for (int s = 0; s < 4; ++s) {
      A0[s] = *(const short8*)(a0p + s * 32);
      A1[s] = *(const short8*)(a1p + s * 32);
    }
    for (int o = 0; o < 3; ++o) {
      const unsigned short* W = Wab + o * 16384;
      short8 b[4][4];
#pragma unroll
      for (int s = 0; s < 4; ++s)
#pragma unroll
        for (int cn = 0; cn < 4; ++cn)
          b[s][cn] = *(const short8*)(W + ((colbase + cn * 16 + r16) << 7) + s * 32 + kgrp * 8);
      f32x4 acc[2][4];
#pragma unroll
      for (int rt = 0; rt < 2; ++rt)
#pragma unroll
        for (int cn = 0; cn < 4; ++cn)
#pragma unroll
          for (int j = 0; j < 4; ++j) acc[rt][cn][j] = 0.f;
#pragma unroll
      for (int s = 0; s < 4; ++s)
#pragma unroll
        for (int cn = 0; cn < 4; ++cn) {
          acc[0][cn] = __builtin_amdgcn_mfma_f32_16x16x32_bf16(A0[s], b[s][cn], acc[0][cn], 0, 0, 0);
          acc[1][cn] = __builtin_amdgcn_mfma_f32_16x16x32_bf16(A1[s], b[s][cn], acc[1][cn], 0, 0, 0);
        }
      unsigned short* dst = (o == 0) ? q_s : (o == 1) ? k_s : v_s;
#pragma unroll
      for (int rt = 0; rt < 2; ++rt)
#pragma unroll
        for (int cn = 0; cn < 4; ++cn) {
          int col = colbase + cn * 16 + r16;
          float bb = b_in[o * DD + col];
#pragma unroll
          for (int i = 0; i < 4; ++i) {
            int wrow = rowhalf * 32 + rt * 16 + kgrp * 4 + i;
            dst[SWIDX(wrow, col)] = f2bf(acc[rt][cn][i] + bb);
          }
        }
    }
  }
  __syncthreads();

  // ---- Phase 2: scores -> p[4] regs (wave owns nodes wave*4..+3) ----
  float p[4];
  {
    int h = lane >> 4, li = (lane >> 2) & 3, m = lane & 3;
    for (int t = 0; t < 4; ++t) {
      int nd = wave * 4 + t;
      float sc = 0.f;
#pragma unroll
      for (int s4 = 0; s4 < 4; ++s4) {
        short8 qv = *(const short8*)&q_s[SWIDX(li * 16 + nd, h * 32 + s4 * 8)];
        short8 kv = *(const short8*)&k_s[SWIDX(m * 16 + nd, h * 32 + s4 * 8)];
#pragma unroll
        for (int j = 0; j < 8; ++j) sc += bfe(qv[j]) * bfe(kv[j]);
      }
      sc *= 0.17677669529663687f;              // 1/sqrt(32)
      float mx = sc;
      mx = fmaxf(mx, __shfl_xor(mx, 1));
      mx = fmaxf(mx, __shfl_xor(mx, 2));
      float e = expf(sc - mx);
      float sum = e;
      sum += __shfl_xor(sum, 1);
      sum += __shfl_xor(sum, 2);
      p[t] = e / sum;                          // lane holds p[h][li][m] for node nd
    }
  }
  __syncthreads();   // score reads done before O overwrites q_s

  // ---- Phase 3: PV -> O into q_s (p via shuffles; wave-local nodes) ----
  {
    int c0 = lane * 2, hh = lane >> 4;   // hh = c0>>5
    for (int t = 0; t < 4; ++t) {
      int nd = wave * 4 + t;
      unsigned v[4];
#pragma unroll
      for (int m = 0; m < 4; ++m)
        v[m] = *(const unsigned*)&v_s[SWIDX(m * 16 + nd, c0)];
#pragma unroll
      for (int lo = 0; lo < 4; ++lo) {
        float ol = 0.f, oh = 0.f;
#pragma unroll
        for (int m = 0; m < 4; ++m) {
          float pm = __shfl(p[t], hh * 16 + lo * 4 + m);
          ol += pm * bf_lo(v[m]);
          oh += pm * bf_hi(v[m]);
        }
        *(unsigned*)&q_s[SWIDX(lo * 16 + nd, c0)] = pack2(ol, oh);
      }
    }
  }
  __syncthreads();

  // ---- Phase 4: out-proj (A = O from q_s) -> k_s holds y + b_out ----
  {
    const unsigned short* W = Wab + 3 * 16384;
    short8 b[4][4];
#pragma unroll
    for (int s = 0; s < 4; ++s)
#pragma unroll
      for (int cn = 0; cn < 4; ++cn)
        b[s][cn] = *(const short8*)(W + ((colbase + cn * 16 + r16) << 7) + s * 32 + kgrp * 8);
    short8 AO0[4], AO1[4];
#pragma unroll
    for (int s = 0; s < 4; ++s) {
      AO0[s] = *(const short8*)&q_s[SWIDX(rlo, s * 32 + kgrp * 8)];
      AO1[s] = *(const short8*)&q_s[SWIDX(rhi, s * 32 + kgrp * 8)];
    }
    f32x4 acc[2][4];
#pragma unroll
    for (int rt = 0; rt < 2; ++rt)
#pragma unroll
      for (int cn = 0; cn < 4; ++cn)
#pragma unroll
        for (int j = 0; j < 4; ++j) acc[rt][cn][j] = 0.f;
#pragma unroll
    for (int s = 0; s < 4; ++s)
#pragma unroll
      for (int cn = 0; cn < 4; ++cn) {
        acc[0][cn] = __builtin_amdgcn_mfma_f32_16x16x32_bf16(AO0[s], b[s][cn], acc[0][cn], 0, 0, 0);
        acc[1][cn] = __builtin_amdgcn_mfma_f32_16x16x32_bf16(AO1[s], b[s][cn], acc[1][cn], 0, 0, 0);
      }
    // K-reads of k_s ended at the phase-2->3 barrier; safe to overwrite now.
#pragma unroll
    for (int rt = 0; rt < 2; ++rt)
#pragma unroll
      for (int cn = 0; cn < 4; ++cn) {
        int col = colbase + cn * 16 + r16;
        float bb = b_out[col];
#pragma unroll
        for (int i = 0; i < 4; ++i) {
          int wrow = rowhalf * 32 + rt * 16 + kgrp * 4 + i;
          k_s[SWIDX(wrow, col)] = f2bf(acc[rt][cn][i] + bb);
        }
      }
  }
  __syncthreads();

  // ---- Phase 5: blend with stk, store f to global, write back to k_s ----
  {
    if (tid < 4) lred[tid] = 0.f;
    int orow = tid >> 2, seg = tid & 3;
    int lb = orow >> 4, nb = nodebase + (orow & 15);
    if (nb < N) {
      float aa = alphas[lb], na = 1.f - aa;
      const unsigned short* sp = stks.p[lb] + (size_t)nb * DD + seg * 32;
      unsigned short* Yp = fbuf + (size_t)lb * NK + (size_t)nb * DD + seg * 32;
#pragma unroll
      for (int k = 0; k < 4; ++k) {
        unsigned short* tp = &k_s[SWIDX(orow, seg * 32 + k * 8)];
        uint4 pv = *(const uint4*)tp;
        uint4 sv = *(const uint4*)(sp + k * 8);
        const unsigned* pw = &pv.x;
        const unsigned* sw = &sv.x;
        uint4 o; unsigned* ow = &o.x;
#pragma unroll
        for (int j = 0; j < 4; ++j)
          ow[j] = pack2(aa * bf_lo(pw[j]) + na * bf_lo(sw[j]),
                        aa * bf_hi(pw[j]) + na * bf_hi(sw[j]));
        *(uint4*)(Yp + k * 8) = o;
        *(uint4*)tp = o;
      }
    }
  }
  __syncthreads();

  // ---- Phase 6: fusion GEMM on f (k_s) + leaky*fq score reduce ----
  {
    const unsigned short* W = Wab + 4 * 16384;
    short8 b[4][4];
#pragma unroll
    for (int s = 0; s < 4; ++s)
#pragma unroll
      for (int cn = 0; cn < 4; ++cn)
        b[s][cn] = *(const short8*)(W + ((colbase + cn * 16 + r16) << 7) + s * 32 + kgrp * 8);
    short8 AF0[4], AF1[4];
#pragma unroll
    for (int s = 0; s < 4; ++s) {
      AF0[s] = *(const short8*)&k_s[SWIDX(rlo, s * 32 + kgrp * 8)];
      AF1[s] = *(const short8*)&k_s[SWIDX(rhi, s * 32 + kgrp * 8)];
    }
    f32x4 acc[2][4];
#pragma unroll
    for (int rt = 0; rt < 2; ++rt)
#pragma unroll
      for (int cn = 0; cn < 4; ++cn)
#pragma unroll
        for (int j = 0; j < 4; ++j) acc[rt][cn][j] = 0.f;
#pragma unroll
    for (int s = 0; s < 4; ++s)
#pragma unroll
      for (int cn = 0; cn < 4; ++cn) {
        acc[0][cn] = __builtin_amdgcn_mfma_f32_16x16x32_bf16(AF0[s], b[s][cn], acc[0][cn], 0, 0, 0);
        acc[1][cn] = __builtin_amdgcn_mfma_f32_16x16x32_bf16(AF1[s], b[s][cn], acc[1][cn], 0, 0, 0);
      }
    float ss0 = 0.f, ss1 = 0.f;
#pragma unroll
    for (int cn = 0; cn < 4; ++cn) {
      int col = colbase + cn * 16 + r16;
      float bb = fus_b[col];
      float qc = fq[col];
#pragma unroll
      for (int i = 0; i < 4; ++i) {
        if (nodebase + kgrp * 4 + i < N) {
          float y0 = acc[0][cn][i] + bb;
          float y1 = acc[1][cn][i] + bb;
          ss0 += (y0 > 0.f ? y0 : 0.01f * y0) * qc;
          ss1 += (y1 > 0.f ? y1 : 0.01f * y1) * qc;
        }
      }
    }
    atomicAdd(&lred[rowhalf * 2], ss0);
    atomicAdd(&lred[rowhalf * 2 + 1], ss1);
    __syncthreads();
    if (tid < 4) atomicAdd(S + tid, lred[tid]);
  }
}

// ---------------- GCN aggregation: CSR gather, 4 nodes/wave (16 lanes x 16B), unroll x8 ----------------
__global__ __launch_bounds__(256) void gather_agg(const int* __restrict__ srcbuf,
                                                  const int* __restrict__ offs,
                                                  const int* __restrict__ deg,
                                                  const float* __restrict__ dinv,
                                                  const uint4* __restrict__ Bs4,
                                                  const float* __restrict__ bias,
                                                  uint4* __restrict__ Ab4, int N4) {
  int rn = blockIdx.x * 16 + (threadIdx.x >> 4);
  if (rn >= N4) return;
  int lane = threadIdx.x & 15;
  int st = offs[rn], cnt = deg[rn];
  uint4 u = Bs4[(size_t)rn * 16 + lane];        // self message (8 bf16)
  float a0 = bf_lo(u.x), a1 = bf_hi(u.x), a2 = bf_lo(u.y), a3 = bf_hi(u.y);
  float a4 = bf_lo(u.z), a5 = bf_hi(u.z), a6 = bf_lo(u.w), a7 = bf_hi(u.w);
  int e = 0;
  for (; e + 8 <= cnt; e += 8) {
    int rr[8];
#pragma unroll
    for (int j = 0; j < 8; ++j) rr[j] = srcbuf[st + e + j];
    uint4 vv[8];
#pragma unroll
    for (int j = 0; j < 8; ++j) vv[j] = Bs4[(size_t)rr[j] * 16 + lane];
#pragma unroll
    for (int j = 0; j < 8; ++j) {
      a0 += bf_lo(vv[j].x); a1 += bf_hi(vv[j].x);
      a2 += bf_lo(vv[j].y); a3 += bf_hi(vv[j].y);
      a4 += bf_lo(vv[j].z); a5 += bf_hi(vv[j].z);
      a6 += bf_lo(vv[j].w); a7 += bf_hi(vv[j].w);
    }
  }
  if (e + 4 <= cnt) {
    int rr[4];
#pragma unroll
    for (int j = 0; j < 4; ++j) rr[j] = srcbuf[st + e + j];
    uint4 vv[4];
#pragma unroll
    for (int j = 0; j < 4; ++j) vv[j] = Bs4[(size_t)rr[j] * 16 + lane];
#pragma unroll
    for (int j = 0; j < 4; ++j) {
      a0 += bf_lo(vv[j].x); a1 += bf_hi(vv[j].x);
      a2 += bf_lo(vv[j].y); a3 += bf_hi(vv[j].y);
      a4 += bf_lo(vv[j].z); a5 += bf_hi(vv[j].z);
      a6 += bf_lo(vv[j].w); a7 += bf_hi(vv[j].w);
    }
    e += 4;
  }
  for (; e < cnt; ++e) {
    uint4 v = Bs4[(size_t)srcbuf[st + e] * 16 + lane];
    a0 += bf_lo(v.x); a1 += bf_hi(v.x); a2 += bf_lo(v.y); a3 += bf_hi(v.y);
    a4 += bf_lo(v.z); a5 += bf_hi(v.z); a6 += bf_lo(v.w); a7 += bf_hi(v.w);
  }
  float dvv = dinv[rn];
  int c = lane * 8;
  uint4 o;
  o.x = pack2(a0 * dvv + bias[c],     a1 * dvv + bias[c + 1]);
  o.y = pack2(a2 * dvv + bias[c + 2], a3 * dvv + bias[c + 3]);
  o.z = pack2(a4 * dvv + bias[c + 4], a5 * dvv + bias[c + 5]);
  o.w = pack2(a6 * dvv + bias[c + 6], a7 * dvv + bias[c + 7]);
  Ab4[(size_t)rn * 16 + lane] = o;
}

// ---------------- batchnorm ----------------

__global__ void bn_stats(const unsigned* __restrict__ Ab2, float* __restrict__ sums, int N) {
  int r = blockIdx.y;
  int lane = threadIdx.x & 63, grp = threadIdx.x >> 6;
  float s0 = 0.f, q0 = 0.f, s1 = 0.f, q1 = 0.f;
  const unsigned* base = Ab2 + (size_t)r * N * 64;
  for (int n = blockIdx.x * 4 + grp; n < N; n += gridDim.x * 4) {
    unsigned u = base[(size_t)n * 64 + lane];
    float a = bf_lo(u), b = bf_hi(u);
    s0 += a; q0 += a * a; s1 += b; q1 += b * b;
  }
  __shared__ float sh[4][64][4];
  sh[grp][lane][0] = s0; sh[grp][lane][1] = q0; sh[grp][lane][2] = s1; sh[grp][lane][3] = q1;
  __syncthreads();
  if (grp == 0) {
#pragma unroll
    for (int g = 1; g < 4; ++g) {
      s0 += sh[g][lane][0]; q0 += sh[g][lane][1]; s1 += sh[g][lane][2]; q1 += sh[g][lane][3];
    }
    int c0 = lane * 2;
    atomicAdd(sums + (r * DD + c0) * 2, s0);
    atomicAdd(sums + (r * DD + c0) * 2 + 1, q0);
    atomicAdd(sums + (r * DD + c0 + 1) * 2, s1);
    atomicAdd(sums + (r * DD + c0 + 1) * 2 + 1, q1);
  }
}

__global__ void bn_final(const float* __restrict__ sums, const float* __restrict__ gamma,
                         const float* __restrict__ beta, float* __restrict__ ss, int N) {
  int t = threadIdx.x;       // 512 = r*128+c
  int c = t & 127;
  float mu = sums[t * 2] / N;
  float var = sums[t * 2 + 1] / N - mu * mu;
  float sc = gamma[c] * rsqrtf(var + 1e-5f);
  ss[t * 2] = sc;
  ss[t * 2 + 1] = beta[c] - mu * sc;
}

// w = softmax([S(f0),S(f1),S(f3),S(f2)]);  coef[l] multiplies f[l]: coef = [w0,w1,w3,w2]
__global__ void wcoef(const float* __restrict__ S, float* __restrict__ coef, int N) {
  if (threadIdx.x == 0) {
    float v0 = S[0] / N, v1 = S[1] / N, v2 = S[3] / N, v3 = S[2] / N;
    float mx = fmaxf(fmaxf(v0, v1), fmaxf(v2, v3));
    float e0 = expf(v0 - mx), e1 = expf(v1 - mx), e2 = expf(v2 - mx), e3 = expf(v3 - mx);
    float inv = 1.f / (e0 + e1 + e2 + e3);
    coef[0] = e0 * inv; coef[1] = e1 * inv; coef[2] = e3 * inv; coef[3] = e2 * inv;
  }
}

__device__ __forceinline__ float bfat(uint2 u, int j) {
  unsigned w = (j < 2) ? u.x : u.y;
  return (j & 1) ? bf_hi(w) : bf_lo(w);
}

// region = sum coef[l]*f[l]; outputs: region, region*rels3[{3,0,1,2}]
__global__ void final_out(const unsigned short* __restrict__ fb, const float* __restrict__ coef,
                          const float* __restrict__ rels3, float* __restrict__ out, int N) {
  size_t NK = (size_t)N * DD;
  size_t i4 = (size_t)blockIdx.x * 256 + threadIdx.x;  // 4-elem groups
  if (i4 >= NK / 4) return;
  size_t g = i4 * 4;
  int c = (int)(g & 127);
  float c0 = coef[0], c1 = coef[1], c2 = coef[2], c3 = coef[3];
  uint2 u0 = *(const uint2*)(fb + g);
  uint2 u1 = *(const uint2*)(fb + NK + g);
  uint2 u2 = *(const uint2*)(fb + 2 * NK + g);
  uint2 u3 = *(const uint2*)(fb + 3 * NK + g);
  float4 reg4, o1, o2, o3, o4;
  float* rp = &reg4.x; float* p1 = &o1.x; float* p2 = &o2.x; float* p3 = &o3.x; float* p4 = &o4.x;
#pragma unroll
  for (int j = 0; j < 4; ++j) {
    float region = c0 * bfat(u0, j) + c1 * bfat(u1, j) + c2 * bfat(u2, j) + c3 * bfat(u3, j);
    rp[j] = region;
    p1[j] = region * rels3[3 * DD + c + j];
    p2[j] = region * rels3[0 * DD + c + j];
    p3[j] = region * rels3[1 * DD + c + j];
    p4[j] = region * rels3[2 * DD + c + j];
  }
  *(float4*)(out + g) = reg4;
  *(float4*)(out + NK + g) = o1;
  *(float4*)(out + 2 * NK + g) = o2;
  *(float4*)(out + 3 * NK + g) = o3;
  *(float4*)(out + 4 * NK + g) = o4;
}

// ---------------- host ----------------

extern "C" void kernel_launch(void* const* d_in, const int* in_sizes, int n_in,
                              void* d_out, int out_size, void* d_ws, size_t ws_size,
                              hipStream_t stream) {
  const float* features  = (const float*)d_in[0];
  const float* rel_emb   = (const float*)d_in[1];
  const int*   edge_idx  = (const int*)d_in[2];
  const float* W_gcn     = (const float*)d_in[3];
  const float* b_gcn     = (const float*)d_in[4];
  const float* bn_gamma  = (const float*)d_in[5];
  const float* bn_beta   = (const float*)d_in[6];
  const float* W_rt      = (const float*)d_in[7];
  const float* b_rt      = (const float*)d_in[8];
  const float* attn_w_in = (const float*)d_in[9];
  const float* attn_b_in = (const float*)d_in[10];
  const float* attn_wout = (const float*)d_in[11];
  const float* attn_bout = (const float*)d_in[12];
  const float* alphas    = (const float*)d_in[13];
  const float* fusion_q  = (const float*)d_in[14];
  const float* fusion_w  = (const float*)d_in[15];
  const float* fusion_b  = (const float*)d_in[16];

  int N = in_sizes[0] / DD;                  // 50000
  int E = in_sizes[2] / (2 * NREL);          // 400000
  size_t NK = (size_t)N * DD;
  int N4 = 4 * N;

  unsigned short* Xb = (unsigned short*)d_ws;            // 4*NK (emb1)
  unsigned short* Bs = Xb + 4 * NK;                      // 4*NK (messages / f)
  unsigned short* Ab = Bs + 4 * NK;                      // 4*NK (agg / stack)
  unsigned short* Ub = Ab + 4 * NK;                      // 4*NK (spare)
  unsigned short* Fb = Ub + 4 * NK;                      // NK (bf16 features, shared)
  float* dinv  = (float*)(Fb + NK);                      // 4*N
  unsigned short* Wgcnb = (unsigned short*)(dinv + N4);  // 4*16384
  unsigned short* Wab   = Wgcnb + 4 * DD * DD;           // 5*16384
  float* rels  = (float*)(Wab + 5 * DD * DD);            // 4 stages * 512
  float* bnsum = rels + 4 * 512;                         // 1024
  float* bnss  = bnsum + 1024;                           // 1024
  float* S     = bnss + 1024;                            // 4
  float* coef  = S + 4;                                  // 4
  int* deg_i   = (int*)(coef + 4);                       // 4*N
  int* offs    = deg_i + N4;                             // 4*N
  int* cur     = offs + N4;                              // 4*N
  int* bsums   = cur + N4;                               // 1024
  int* srcb    = bsums + 1024;                           // 4*E

  size_t needed = (size_t)((char*)(srcb + 4 * E) - (char*)d_ws);
  if (ws_size < needed) {
    fprintf(stderr, "kernel_launch: ws too small (%zu < %zu)\n", ws_size, needed);
    return;
  }

  int gemmGrid = (N + 63) / 64;
  int scanBlocks = (N4 + 255) / 256;
  int egrid4 = (E + 1023) / 1024;

  // ---- CSR build (edges fixed across layers) ----
  (void)hipMemsetAsync(deg_i, 0, (size_t)N4 * sizeof(int), stream);
  count_deg<<<dim3(egrid4, 4), 256, 0, stream>>>(edge_idx, deg_i, N, E);
  finalize_dinv<<<scanBlocks, 256, 0, stream>>>(deg_i, dinv, N4);
  scan_block<<<scanBlocks, 256, 0, stream>>>(deg_i, offs, bsums, N4);
  scan_sums<<<1, 1024, 0, stream>>>(bsums, scanBlocks);
  scan_add<<<scanBlocks, 256, 0, stream>>>(offs, cur, bsums, N4);
  fill_edges<<<dim3(egrid4, 4), 256, 0, stream>>>(edge_idx, cur, srcb, N, E);

  rels_init<<<1, 512, 0, stream>>>(rel_emb, rels);
  conv_w<<<5 * 16384 / 256, 256, 0, stream>>>(attn_w_in, attn_wout, fusion_w, Wab);
  conv_f2b<<<(int)((NK / 4 + 255) / 256), 256, 0, stream>>>(features, (unsigned*)Fb, NK / 4);

  PtrB4 wz, abIn, resIn;
  OutB4 msgOut, xbOut, dummyO;
  for (int r = 0; r < 4; ++r) {
    wz.p[r] = Wgcnb + (size_t)r * DD * DD;
    abIn.p[r] = Ab + (size_t)r * NK;
    msgOut.p[r] = Bs + (size_t)r * NK;
    xbOut.p[r] = Xb + (size_t)r * NK;
    dummyO.p[r] = nullptr;
  }

  // ---- Layer 0 ----
  scale_w_bf<<<256, 256, 0, stream>>>(rels, W_gcn, Wgcnb);
  {
    PtrB4 xs; for (int r = 0; r < 4; ++r) xs.p[r] = Fb;
    gemm_ws<0><<<dim3(gemmGrid, 4), 256, 0, stream>>>(xs, wz, msgOut, nullptr, dinv, N);
  }
  gather_agg<<<(N4 + 15) / 16, 256, 0, stream>>>(srcb, offs, deg_i, dinv, (const uint4*)Bs,
                                                 b_gcn, (uint4*)Ab, N4);
  (void)hipMemsetAsync(bnsum, 0, 1024 * sizeof(float), stream);
  bn_stats<<<dim3(400, 4), 256, 0, stream>>>((const unsigned*)Ab, bnsum, N);
  bn_final<<<1, 512, 0, stream>>>(bnsum, bn_gamma, bn_beta, bnss, N);
  rels_update<<<1, 512, 0, stream>>>(rels, W_rt, b_rt, rels + 512);

  // ---- Layer 1 (fused BN-update, writeback emb1) ----
  scale_w_bf<<<256, 256, 0, stream>>>(rels + 512, W_gcn + (size_t)DD * DD, Wgcnb);
  for (int r = 0; r < 4; ++r) resIn.p[r] = Fb;           // emb0 = features (shared)
  gemm_upd<1><<<dim3(gemmGrid, 4), 256, 0, stream>>>(resIn, abIn, wz, xbOut, msgOut,
                                                     bnss, dinv, N);
  gather_agg<<<(N4 + 15) / 16, 256, 0, stream>>>(srcb, offs, deg_i, dinv, (const uint4*)Bs,
                                                 b_gcn + DD, (uint4*)Ab, N4);
  (void)hipMemsetAsync(bnsum, 0, 1024 * sizeof(float), stream);
  bn_stats<<<dim3(400, 4), 256, 0, stream>>>((const unsigned*)Ab, bnsum, N);
  bn_final<<<1, 512, 0, stream>>>(bnsum, bn_gamma + DD, bn_beta + DD, bnss, N);
  rels_update<<<1, 512, 0, stream>>>(rels + 512, W_rt + (size_t)DD * DD, b_rt + DD, rels + 1024);

  // ---- Layer 2 (fused BN-update, no writeback) ----
  scale_w_bf<<<256, 256, 0, stream>>>(rels + 1024, W_gcn + (size_t)2 * DD * DD, Wgcnb);
  for (int r = 0; r < 4; ++r) resIn.p[r] = Xb + (size_t)r * NK;   // emb1
  gemm_upd<0><<<dim3(gemmGrid, 4), 256, 0, stream>>>(resIn, abIn, wz, dummyO, msgOut,
                                                     bnss, dinv, N);
  gather_agg<<<(N4 + 15) / 16, 256, 0, stream>>>(srcb, offs, deg_i, dinv, (const uint4*)Bs,
                                                 b_gcn + 2 * DD, (uint4*)Ab, N4);
  rels_update<<<1, 512, 0, stream>>>(rels + 1024, W_rt + (size_t)2 * DD * DD, b_rt + 2 * DD,
                                     rels + 1536);
  // Ab = final GCN outputs (stack source). Xb, Bs, Ub free.

  const int pstk[4] = {3, 0, 2, 1};
  PtrB4 stk;
  for (int l = 0; l < 4; ++l) stk.p[l] = Ab + (size_t)pstk[l] * NK;

  (void)hipMemsetAsync(S, 0, 4 * sizeof(float), stream);
  attn_mega<<<(N + 15) / 16, 256, 0, stream>>>(stk, Wab, attn_b_in, attn_bout, alphas,
                                               fusion_b, fusion_q, Bs, S, N);
  wcoef<<<1, 64, 0, stream>>>(S, coef, N);
  final_out<<<(int)((NK / 4 + 255) / 256), 256, 0, stream>>>(Bs, coef, rels + 1536,
                                                             (float*)d_out, N);
}

// Round 16
// 920.243 us; speedup vs baseline: 1.0989x; 1.0134x over previous
//
#include <hip/hip_runtime.h>
#include <hip/hip_bf16.h>
#include <cstdio>

#define DD 128
#define NREL 4

using short8 = __attribute__((ext_vector_type(8))) short;
using f32x4  = __attribute__((ext_vector_type(4))) float;

struct PtrB4 { const unsigned short* p[4]; };
struct OutB4 { unsigned short* p[4]; };

// processing-order relation r uses edge_index/rel_emb row (r+3)&3  (perm = [3,0,1,2])
__device__ __forceinline__ int edge_perm(int r) { return (r + 3) & 3; }

__device__ __forceinline__ float bf_lo(unsigned u) { return __uint_as_float(u << 16); }
__device__ __forceinline__ float bf_hi(unsigned u) { return __uint_as_float(u & 0xffff0000u); }
__device__ __forceinline__ float bfe(short s) {
  return __uint_as_float(((unsigned)(unsigned short)s) << 16);
}
// native RNE converts (compiler emits v_cvt_pk_bf16_f32 for adjacent pairs)
__device__ __forceinline__ unsigned short f2bf(float f) {
  return __bfloat16_as_ushort(__float2bfloat16(f));
}
__device__ __forceinline__ unsigned pack2(float a, float b) {
  return (unsigned)f2bf(a) | ((unsigned)f2bf(b) << 16);
}

// swizzled LDS index for 64x136-short tiles: rows 16 apart land on distinct banks
#define SWIDX(row, col) ((row) * 136 + ((col) ^ ((((row) >> 4) & 3) << 4)))

// ---------------- fused prep: rels_init + conv_w + features->bf16 ----------------
__global__ void prep(const float* __restrict__ rel_emb, const float* __restrict__ w_in,
                     const float* __restrict__ w_out, const float* __restrict__ w_fus,
                     const float* __restrict__ features, float* __restrict__ rels,
                     unsigned short* __restrict__ Wab, unsigned* __restrict__ Fb2,
                     size_t n4) {
  size_t i = (size_t)blockIdx.x * 256 + threadIdx.x;
  if (i < n4) {
    float4 v = ((const float4*)features)[i];
    Fb2[i * 2]     = pack2(v.x, v.y);
    Fb2[i * 2 + 1] = pack2(v.z, v.w);
  }
  if (i < 5 * 16384) {
    int ii = (int)i;
    float v = (ii < 49152) ? w_in[ii] : (ii < 65536 ? w_out[ii - 49152] : w_fus[ii - 65536]);
    Wab[ii] = f2bf(v);
  }
  if (i < 512) {
    int t = (int)i, r = t >> 7, c = t & 127;
    rels[t] = rel_emb[edge_perm(r) * DD + c];
  }
}

__global__ void rels_update(const float* __restrict__ rin, const float* __restrict__ Wrt,
                            const float* __restrict__ brt, float* __restrict__ rout) {
  int t = threadIdx.x;  // 512 = r*128 + j
  int r = t >> 7, j = t & 127;
  float s = brt[j];
  const float* wr = Wrt + j * DD;
  const float* xr = rin + r * DD;
  for (int c = 0; c < DD; ++c) s += xr[c] * wr[c];
  rout[t] = s;
}

// merged bn_final + rels_update (512 threads)
__global__ void bn_rels(const float* __restrict__ sums, const float* __restrict__ gamma,
                        const float* __restrict__ beta, float* __restrict__ ss,
                        const float* __restrict__ rin, const float* __restrict__ Wrt,
                        const float* __restrict__ brt, float* __restrict__ rout, int N) {
  int t = threadIdx.x;       // 512
  int c = t & 127;
  float mu = sums[t * 2] / N;
  float var = sums[t * 2 + 1] / N - mu * mu;
  float sc = gamma[c] * rsqrtf(var + 1e-5f);
  ss[t * 2] = sc;
  ss[t * 2 + 1] = beta[c] - mu * sc;
  int r = t >> 7, j = t & 127;
  float s = brt[j];
  const float* wr = Wrt + j * DD;
  const float* xr = rin + r * DD;
  for (int cc = 0; cc < DD; ++cc) s += xr[cc] * wr[cc];
  rout[t] = s;
}

// Wsb[r][j][c] = bf16(rels[r][c] * Wg[c][j])  -- MFMA-B layout [n=j][k=c]
__global__ void scale_w_bf(const float* __restrict__ rels_i, const float* __restrict__ Wg,
                           unsigned short* __restrict__ Wsb) {
  int i = blockIdx.x * 256 + threadIdx.x;   // 4*16384
  int r = i >> 14, rem = i & 16383, j = rem >> 7, c = rem & 127;
  Wsb[i] = f2bf(rels_i[r * DD + c] * Wg[c * DD + j]);
}

// ---------------- CSR build ----------------

__global__ void count_deg(const int* __restrict__ ei, int* __restrict__ deg, int N, int E) {
  int r = blockIdx.y;
  int base = blockIdx.x * 1024 + threadIdx.x;
  const int* dsts = ei + (size_t)edge_perm(r) * 2 * E + E;
#pragma unroll
  for (int k = 0; k < 4; ++k) {
    int e = base + k * 256;
    if (e < E) atomicAdd(deg + (size_t)r * N + dsts[e], 1);
  }
}

// block scan + dinv in one pass
__global__ void scan_block(const int* __restrict__ deg, int* __restrict__ excl,
                           int* __restrict__ bsums, float* __restrict__ dinv, int n) {
  __shared__ int sh[256];
  int i = blockIdx.x * 256 + threadIdx.x;
  int v = (i < n) ? deg[i] : 0;
  sh[threadIdx.x] = v;
  __syncthreads();
  for (int st = 1; st < 256; st <<= 1) {
    int t = (threadIdx.x >= st) ? sh[threadIdx.x - st] : 0;
    __syncthreads();
    sh[threadIdx.x] += t;
    __syncthreads();
  }
  if (i < n) {
    excl[i] = sh[threadIdx.x] - v;
    dinv[i] = rsqrtf((float)v + 1.0f);
  }
  if (threadIdx.x == 255) bsums[blockIdx.x] = sh[255];
}

__global__ void scan_sums(int* __restrict__ bsums, int nb) {
  __shared__ int sh[1024];
  int v = (threadIdx.x < nb) ? bsums[threadIdx.x] : 0;
  sh[threadIdx.x] = v;
  __syncthreads();
  for (int st = 1; st < 1024; st <<= 1) {
    int t = (threadIdx.x >= st) ? sh[threadIdx.x - st] : 0;
    __syncthreads();
    sh[threadIdx.x] += t;
    __syncthreads();
  }
  if (threadIdx.x < nb) bsums[threadIdx.x] = sh[threadIdx.x] - v;  // exclusive
}

__global__ void scan_add(int* __restrict__ excl, int* __restrict__ cursor,
                         const int* __restrict__ bsums, int n) {
  int i = blockIdx.x * 256 + threadIdx.x;
  if (i < n) {
    int o = excl[i] + bsums[blockIdx.x];
    excl[i] = o;
    cursor[i] = o;
  }
}

// 4 edges/thread: 4 independent atomic-returns in flight
__global__ void fill_edges(const int* __restrict__ ei, int* __restrict__ cursor,
                           int* __restrict__ srcbuf, int N, int E) {
  int r = blockIdx.y;
  int base = blockIdx.x * 1024 + threadIdx.x;
  const int* bp = ei + (size_t)edge_perm(r) * 2 * E;
  int s[4], d[4], pos[4];
#pragma unroll
  for (int k = 0; k < 4; ++k) {
    int e = base + k * 256;
    s[k] = (e < E) ? bp[e] : 0;
    d[k] = (e < E) ? bp[E + e] : 0;
  }
#pragma unroll
  for (int k = 0; k < 4; ++k) {
    int e = base + k * 256;
    if (e < E) pos[k] = atomicAdd(&cursor[r * N + d[k]], 1);
  }
#pragma unroll
  for (int k = 0; k < 4; ++k) {
    int e = base + k * 256;
    if (e < E) srcbuf[pos[k]] = r * N + s[k];
  }
}

// ---------------- weight-stationary MFMA GEMM (round-7 proven) ----------------
template <int MODE>
__global__ __launch_bounds__(256) void gemm_ws(PtrB4 xs, PtrB4 wz, OutB4 ys,
                                               const float* __restrict__ bias,
                                               const float* __restrict__ dinv, int M) {
  int z = blockIdx.y;
  const unsigned short* __restrict__ X = xs.p[z];
  const unsigned short* __restrict__ W = wz.p[z];
  int tid = threadIdx.x;
  int wave = tid >> 6, lane = tid & 63;
  int r16 = lane & 15, kgrp = lane >> 4;
  int rowhalf = wave >> 1, colbase = (wave & 1) * 64;
  int blockrow = blockIdx.x * 64;

  short8 b[4][4];
#pragma unroll
  for (int s = 0; s < 4; ++s)
#pragma unroll
    for (int cn = 0; cn < 4; ++cn)
      b[s][cn] = *(const short8*)(W + ((colbase + cn * 16 + r16) << 7) + s * 32 + kgrp * 8);

  int row0 = blockrow + rowhalf * 32 + r16;
  int r0c = row0 < M ? row0 : M - 1;
  int r1c = row0 + 16 < M ? row0 + 16 : M - 1;
  short8 a[2][4];
#pragma unroll
  for (int s = 0; s < 4; ++s) {
    a[0][s] = *(const short8*)(X + (size_t)r0c * DD + s * 32 + kgrp * 8);
    a[1][s] = *(const short8*)(X + (size_t)r1c * DD + s * 32 + kgrp * 8);
  }

  f32x4 acc[2][4];
#pragma unroll
  for (int rt = 0; rt < 2; ++rt)
#pragma unroll
    for (int cn = 0; cn < 4; ++cn)
#pragma unroll
      for (int j = 0; j < 4; ++j) acc[rt][cn][j] = 0.f;

#pragma unroll
  for (int s = 0; s < 4; ++s)
#pragma unroll
    for (int rt = 0; rt < 2; ++rt)
#pragma unroll
      for (int cn = 0; cn < 4; ++cn)
        acc[rt][cn] = __builtin_amdgcn_mfma_f32_16x16x32_bf16(a[rt][s], b[s][cn], acc[rt][cn], 0, 0, 0);

  __shared__ __align__(16) unsigned short tile[64][DD + 8];
  float dv[2][4];
  if constexpr (MODE == 0) {
#pragma unroll
    for (int rt = 0; rt < 2; ++rt)
#pragma unroll
      for (int i = 0; i < 4; ++i) {
        int row = blockrow + rowhalf * 32 + rt * 16 + kgrp * 4 + i;
        dv[rt][i] = dinv[(size_t)z * M + (row < M ? row : 0)];
      }
  }
#pragma unroll
  for (int rt = 0; rt < 2; ++rt)
#pragma unroll
    for (int cn = 0; cn < 4; ++cn) {
      int col = colbase + cn * 16 + r16;
#pragma unroll
      for (int i = 0; i < 4; ++i) {
        int wrow = rowhalf * 32 + rt * 16 + kgrp * 4 + i;
        float y = acc[rt][cn][i];
        if constexpr (MODE == 0) y *= dv[rt][i];
        tile[wrow][col] = f2bf(y);
      }
    }
  __syncthreads();
  int orow = tid >> 2, seg = tid & 3;
  int grow = blockrow + orow;
  if (grow < M) {
    unsigned short* Yp = ys.p[z] + (size_t)grow * DD + seg * 32;
    const unsigned short* tp = &tile[orow][seg * 32];
#pragma unroll
    for (int k = 0; k < 4; ++k)
      *(uint4*)(Yp + k * 8) = *(const uint4*)(tp + k * 8);
  }
}

// Layers 1/2 fused GEMM (round-7 proven)
template <int WB>
__global__ __launch_bounds__(256) void gemm_upd(PtrB4 res, PtrB4 abs_, PtrB4 wz,
                                                OutB4 xout, OutB4 ys,
                                                const float* __restrict__ ssx,
                                                const float* __restrict__ dinv, int M) {
  int z = blockIdx.y;
  const unsigned short* __restrict__ R = res.p[z];
  const unsigned short* __restrict__ A = abs_.p[z];
  const unsigned short* __restrict__ W = wz.p[z];
  int tid = threadIdx.x;

  __shared__ float ssc[DD], ssh[DD];
  if (tid < DD) {
    ssc[tid] = ssx[((size_t)z * DD + tid) * 2];
    ssh[tid] = ssx[((size_t)z * DD + tid) * 2 + 1];
  }
  __syncthreads();

  int wave = tid >> 6, lane = tid & 63;
  int r16 = lane & 15, kgrp = lane >> 4;
  int rowhalf = wave >> 1, colbase = (wave & 1) * 64;
  int blockrow = blockIdx.x * 64;

  short8 b[4][4];
#pragma unroll
  for (int s = 0; s < 4; ++s)
#pragma unroll
    for (int cn = 0; cn < 4; ++cn)
      b[s][cn] = *(const short8*)(W + ((colbase + cn * 16 + r16) << 7) + s * 32 + kgrp * 8);

  int row0 = blockrow + rowhalf * 32 + r16;
  int rc[2];
  rc[0] = row0 < M ? row0 : M - 1;
  rc[1] = row0 + 16 < M ? row0 + 16 : M - 1;
  short8 a[2][4];
#pragma unroll
  for (int rt = 0; rt < 2; ++rt)
#pragma unroll
    for (int s = 0; s < 4; ++s) {
      int cbase = s * 32 + kgrp * 8;
      short8 rv = *(const short8*)(R + (size_t)rc[rt] * DD + cbase);
      short8 av = *(const short8*)(A + (size_t)rc[rt] * DD + cbase);
      unsigned w4p[4];
#pragma unroll
      for (int jj = 0; jj < 4; ++jj) {
        float x0 = bfe(av[2 * jj]) * ssc[cbase + 2 * jj] + ssh[cbase + 2 * jj];
        float x1 = bfe(av[2 * jj + 1]) * ssc[cbase + 2 * jj + 1] + ssh[cbase + 2 * jj + 1];
        x0 = x0 > 0.f ? x0 : 0.01f * x0;
        x1 = x1 > 0.f ? x1 : 0.01f * x1;
        w4p[jj] = pack2(bfe(rv[2 * jj]) + x0, bfe(rv[2 * jj + 1]) + x1);
      }
      uint4 packed = make_uint4(w4p[0], w4p[1], w4p[2], w4p[3]);
      short8 av2;
      __builtin_memcpy(&av2, &packed, sizeof(av2));
      a[rt][s] = av2;
    }
  if (WB) {
#pragma unroll
    for (int rt = 0; rt < 2; ++rt) {
      int row = row0 + rt * 16;
      if (row < M) {
#pragma unroll
        for (int s = 0; s < 4; ++s)
          *(short8*)(xout.p[z] + (size_t)row * DD + s * 32 + kgrp * 8) = a[rt][s];
      }
    }
  }

  f32x4 acc[2][4];
#pragma unroll
  for (int rt = 0; rt < 2; ++rt)
#pragma unroll
    for (int cn = 0; cn < 4; ++cn)
#pragma unroll
      for (int j = 0; j < 4; ++j) acc[rt][cn][j] = 0.f;
#pragma unroll
  for (int s = 0; s < 4; ++s)
#pragma unroll
    for (int rt = 0; rt < 2; ++rt)
#pragma unroll
      for (int cn = 0; cn < 4; ++cn)
        acc[rt][cn] = __builtin_amdgcn_mfma_f32_16x16x32_bf16(a[rt][s], b[s][cn], acc[rt][cn], 0, 0, 0);

  __shared__ __align__(16) unsigned short tile[64][DD + 8];
  float dv[2][4];
#pragma unroll
  for (int rt = 0; rt < 2; ++rt)
#pragma unroll
    for (int i = 0; i < 4; ++i) {
      int row = blockrow + rowhalf * 32 + rt * 16 + kgrp * 4 + i;
      dv[rt][i] = dinv[(size_t)z * M + (row < M ? row : 0)];
    }
#pragma unroll
  for (int rt = 0; rt < 2; ++rt)
#pragma unroll
    for (int cn = 0; cn < 4; ++cn) {
      int col = colbase + cn * 16 + r16;
#pragma unroll
      for (int i = 0; i < 4; ++i) {
        int wrow = rowhalf * 32 + rt * 16 + kgrp * 4 + i;
        tile[wrow][col] = f2bf(acc[rt][cn][i] * dv[rt][i]);
      }
    }
  __syncthreads();
  int orow = tid >> 2, seg = tid & 3;
  int grow = blockrow + orow;
  if (grow < M) {
    unsigned short* Yp = ys.p[z] + (size_t)grow * DD + seg * 32;
    const unsigned short* tp = &tile[orow][seg * 32];
#pragma unroll
    for (int k = 0; k < 4; ++k)
      *(uint4*)(Yp + k * 8) = *(const uint4*)(tp + k * 8);
  }
}

// ---------------- mega-fused attention phase (v5, round-14 proven) ----------------
__global__ __launch_bounds__(256) void attn_mega(PtrB4 stks,
    const unsigned short* __restrict__ Wab,
    const float* __restrict__ b_in, const float* __restrict__ b_out,
    const float* __restrict__ alphas, const float* __restrict__ fus_b,
    const float* __restrict__ fq, unsigned short* __restrict__ fbuf,
    float* __restrict__ S, int N) {
  __shared__ __align__(16) unsigned short q_s[64 * 136];  // Q -> O
  __shared__ __align__(16) unsigned short k_s[64 * 136];  // K -> proj/f
  __shared__ __align__(16) unsigned short v_s[64 * 136];  // V
  __shared__ float lred[4];
  size_t NK = (size_t)N * DD;

  int tid = threadIdx.x;
  int wave = tid >> 6, lane = tid & 63;
  int r16 = lane & 15, kgrp = lane >> 4;
  int rowhalf = wave >> 1, colbase = (wave & 1) * 64;
  int nodebase = blockIdx.x * 16;

  int rlo = rowhalf * 32 + r16;     // 0..63
  int rhi = rlo + 16;
  int nlo = nodebase + (rlo & 15); if (nlo >= N) nlo = N - 1;
  int nhi = nodebase + (rhi & 15); if (nhi >= N) nhi = N - 1;
  const unsigned short* a0p = stks.p[rlo >> 4] + (size_t)nlo * DD + kgrp * 8;
  const unsigned short* a1p = stks.p[rhi >> 4] + (size_t)nhi * DD + kgrp * 8;

  // ---- Phase 1: Q,K,V GEMMs (A regs shared across the three) ----
  {
    short8 A0[4], A1[4];
#pragma unroll
    for (int s = 0; s < 4; ++s) {
      A0[s] = *(const short8*)(a0p + s * 32);
      A1[s] = *(const short8*)(a1p + s * 32);
    }
    for (int o = 0; o < 3; ++o) {
      const unsigned short* W = Wab + o * 16384;
      short8 b[4][4];
#pragma unroll
      for (int s = 0; s < 4; ++s)
#pragma unroll
        for (int cn = 0; cn < 4; ++cn)
          b[s][cn] = *(const short8*)(W + ((colbase + cn * 16 + r16) << 7) + s * 32 + kgrp * 8);
      f32x4 acc[2][4];
#pragma unroll
      for (int rt = 0; rt < 2; ++rt)
#pragma unroll
        for (int cn = 0; cn < 4; ++cn)
#pragma unroll
          for (int j = 0; j < 4; ++j) acc[rt][cn][j] = 0.f;
#pragma unroll
      for (int s = 0; s < 4; ++s)
#pragma unroll
        for (int cn = 0; cn < 4; ++cn) {
          acc[0][cn] = __builtin_amdgcn_mfma_f32_16x16x32_bf16(A0[s], b[s][cn], acc[0][cn], 0, 0, 0);
          acc[1][cn] = __builtin_amdgcn_mfma_f32_16x16x32_bf16(A1[s], b[s][cn], acc[1][cn], 0, 0, 0);
        }
      unsigned short* dst = (o == 0) ? q_s : (o == 1) ? k_s : v_s;
#pragma unroll
      for (int rt = 0; rt < 2; ++rt)
#pragma unroll
        for (int cn = 0; cn < 4; ++cn) {
          int col = colbase + cn * 16 + r16;
          float bb = b_in[o * DD + col];
#pragma unroll
          for (int i = 0; i < 4; ++i) {
            int wrow = rowhalf * 32 + rt * 16 + kgrp * 4 + i;
            dst[SWIDX(wrow, col)] = f2bf(acc[rt][cn][i] + bb);
          }
        }
    }
  }
  __syncthreads();

  // ---- Phase 2: scores -> p[4] regs (wave owns nodes wave*4..+3) ----
  float p[4];
  {
    int h = lane >> 4, li = (lane >> 2) & 3, m = lane & 3;
    for (int t = 0; t < 4; ++t) {
      int nd = wave * 4 + t;
      float sc = 0.f;
#pragma unroll
      for (int s4 = 0; s4 < 4; ++s4) {
        short8 qv = *(const short8*)&q_s[SWIDX(li * 16 + nd, h * 32 + s4 * 8)];
        short8 kv = *(const short8*)&k_s[SWIDX(m * 16 + nd, h * 32 + s4 * 8)];
#pragma unroll
        for (int j = 0; j < 8; ++j) sc += bfe(qv[j]) * bfe(kv[j]);
      }
      sc *= 0.17677669529663687f;              // 1/sqrt(32)
      float mx = sc;
      mx = fmaxf(mx, __shfl_xor(mx, 1));
      mx = fmaxf(mx, __shfl_xor(mx, 2));
      float e = expf(sc - mx);
      float sum = e;
      sum += __shfl_xor(sum, 1);
      sum += __shfl_xor(sum, 2);
      p[t] = e / sum;                          // lane holds p[h][li][m] for node nd
    }
  }
  __syncthreads();   // score reads done before O overwrites q_s

  // ---- Phase 3: PV -> O into q_s (p via shuffles; wave-local nodes) ----
  {
    int c0 = lane * 2, hh = lane >> 4;   // hh = c0>>5
    for (int t = 0; t < 4; ++t) {
      int nd = wave * 4 + t;
      unsigned v[4];
#pragma unroll
      for (int m = 0; m < 4; ++m)
        v[m] = *(const unsigned*)&v_s[SWIDX(m * 16 + nd, c0)];
#pragma unroll
      for (int lo = 0; lo < 4; ++lo) {
        float ol = 0.f, oh = 0.f;
#pragma unroll
        for (int m = 0; m < 4; ++m) {
          float pm = __shfl(p[t], hh * 16 + lo * 4 + m);
          ol += pm * bf_lo(v[m]);
          oh += pm * bf_hi(v[m]);
        }
        *(unsigned*)&q_s[SWIDX(lo * 16 + nd, c0)] = pack2(ol, oh);
      }
    }
  }
  __syncthreads();

  // ---- Phase 4: out-proj (A = O from q_s) -> k_s holds y + b_out ----
  {
    const unsigned short* W = Wab + 3 * 16384;
    short8 b[4][4];
#pragma unroll
    for (int s = 0; s < 4; ++s)
#pragma unroll
      for (int cn = 0; cn < 4; ++cn)
        b[s][cn] = *(const short8*)(W + ((colbase + cn * 16 + r16) << 7) + s * 32 + kgrp * 8);
    short8 AO0[4], AO1[4];
#pragma unroll
    for (int s = 0; s < 4; ++s) {
      AO0[s] = *(const short8*)&q_s[SWIDX(rlo, s * 32 + kgrp * 8)];
      AO1[s] = *(const short8*)&q_s[SWIDX(rhi, s * 32 + kgrp * 8)];
    }
    f32x4 acc[2][4];
#pragma unroll
    for (int rt = 0; rt < 2; ++rt)
#pragma unroll
      for (int cn = 0; cn < 4; ++cn)
#pragma unroll
        for (int j = 0; j < 4; ++j) acc[rt][cn][j] = 0.f;
#pragma unroll
    for (int s = 0; s < 4; ++s)
#pragma unroll
      for (int cn = 0; cn < 4; ++cn) {
        acc[0][cn] = __builtin_amdgcn_mfma_f32_16x16x32_bf16(AO0[s], b[s][cn], acc[0][cn], 0, 0, 0);
        acc[1][cn] = __builtin_amdgcn_mfma_f32_16x16x32_bf16(AO1[s], b[s][cn], acc[1][cn], 0, 0, 0);
      }
#pragma unroll
    for (int rt = 0; rt < 2; ++rt)
#pragma unroll
      for (int cn = 0; cn < 4; ++cn) {
        int col = colbase + cn * 16 + r16;
        float bb = b_out[col];
#pragma unroll
        for (int i = 0; i < 4; ++i) {
          int wrow = rowhalf * 32 + rt * 16 + kgrp * 4 + i;
          k_s[SWIDX(wrow, col)] = f2bf(acc[rt][cn][i] + bb);
        }
      }
  }
  __syncthreads();

  // ---- Phase 5: blend with stk, store f to global, write back to k_s ----
  {
    if (tid < 4) lred[tid] = 0.f;
    int orow = tid >> 2, seg = tid & 3;
    int lb = orow >> 4, nb = nodebase + (orow & 15);
    if (nb < N) {
      float aa = alphas[lb], na = 1.f - aa;
      const unsigned short* sp = stks.p[lb] + (size_t)nb * DD + seg * 32;
      unsigned short* Yp = fbuf + (size_t)lb * NK + (size_t)nb * DD + seg * 32;
#pragma unroll
      for (int k = 0; k < 4; ++k) {
        unsigned short* tp = &k_s[SWIDX(orow, seg * 32 + k * 8)];
        uint4 pv = *(const uint4*)tp;
        uint4 sv = *(const uint4*)(sp + k * 8);
        const unsigned* pw = &pv.x;
        const unsigned* sw = &sv.x;
        uint4 o; unsigned* ow = &o.x;
#pragma unroll
        for (int j = 0; j < 4; ++j)
          ow[j] = pack2(aa * bf_lo(pw[j]) + na * bf_lo(sw[j]),
                        aa * bf_hi(pw[j]) + na * bf_hi(sw[j]));
        *(uint4*)(Yp + k * 8) = o;
        *(uint4*)tp = o;
      }
    }
  }
  __syncthreads();

  // ---- Phase 6: fusion GEMM on f (k_s) + leaky*fq score reduce ----
  {
    const unsigned short* W = Wab + 4 * 16384;
    short8 b[4][4];
#pragma unroll
    for (int s = 0; s < 4; ++s)
#pragma unroll
      for (int cn = 0; cn < 4; ++cn)
        b[s][cn] = *(const short8*)(W + ((colbase + cn * 16 + r16) << 7) + s * 32 + kgrp * 8);
    short8 AF0[4], AF1[4];
#pragma unroll
    for (int s = 0; s < 4; ++s) {
      AF0[s] = *(const short8*)&k_s[SWIDX(rlo, s * 32 + kgrp * 8)];
      AF1[s] = *(const short8*)&k_s[SWIDX(rhi, s * 32 + kgrp * 8)];
    }
    f32x4 acc[2][4];
#pragma unroll
    for (int rt = 0; rt < 2; ++rt)
#pragma unroll
      for (int cn = 0; cn < 4; ++cn)
#pragma unroll
        for (int j = 0; j < 4; ++j) acc[rt][cn][j] = 0.f;
#pragma unroll
    for (int s = 0; s < 4; ++s)
#pragma unroll
      for (int cn = 0; cn < 4; ++cn) {
        acc[0][cn] = __builtin_amdgcn_mfma_f32_16x16x32_bf16(AF0[s], b[s][cn], acc[0][cn], 0, 0, 0);
        acc[1][cn] = __builtin_amdgcn_mfma_f32_16x16x32_bf16(AF1[s], b[s][cn], acc[1][cn], 0, 0, 0);
      }
    float ss0 = 0.f, ss1 = 0.f;
#pragma unroll
    for (int cn = 0; cn < 4; ++cn) {
      int col = colbase + cn * 16 + r16;
      float bb = fus_b[col];
      float qc = fq[col];
#pragma unroll
      for (int i = 0; i < 4; ++i) {
        if (nodebase + kgrp * 4 + i < N) {
          float y0 = acc[0][cn][i] + bb;
          float y1 = acc[1][cn][i] + bb;
          ss0 += (y0 > 0.f ? y0 : 0.01f * y0) * qc;
          ss1 += (y1 > 0.f ? y1 : 0.01f * y1) * qc;
        }
      }
    }
    atomicAdd(&lred[rowhalf * 2], ss0);
    atomicAdd(&lred[rowhalf * 2 + 1], ss1);
    __syncthreads();
    if (tid < 4) atomicAdd(S + tid, lred[tid]);
  }
}

// ---------------- GCN aggregation: CSR gather, 4 nodes/wave, unroll x8 ----------------
__global__ __launch_bounds__(256) void gather_agg(const int* __restrict__ srcbuf,
                                                  const int* __restrict__ offs,
                                                  const int* __restrict__ deg,
                                                  const float* __restrict__ dinv,
                                                  const uint4* __restrict__ Bs4,
                                                  const float* __restrict__ bias,
                                                  uint4* __restrict__ Ab4, int N4) {
  int rn = blockIdx.x * 16 + (threadIdx.x >> 4);
  if (rn >= N4) return;
  int lane = threadIdx.x & 15;
  int st = offs[rn], cnt = deg[rn];
  uint4 u = Bs4[(size_t)rn * 16 + lane];        // self message (8 bf16)
  float a0 = bf_lo(u.x), a1 = bf_hi(u.x), a2 = bf_lo(u.y), a3 = bf_hi(u.y);
  float a4 = bf_lo(u.z), a5 = bf_hi(u.z), a6 = bf_lo(u.w), a7 = bf_hi(u.w);
  int e = 0;
  for (; e + 8 <= cnt; e += 8) {
    int rr[8];
#pragma unroll
    for (int j = 0; j < 8; ++j) rr[j] = srcbuf[st + e + j];
    uint4 vv[8];
#pragma unroll
    for (int j = 0; j < 8; ++j) vv[j] = Bs4[(size_t)rr[j] * 16 + lane];
#pragma unroll
    for (int j = 0; j < 8; ++j) {
      a0 += bf_lo(vv[j].x); a1 += bf_hi(vv[j].x);
      a2 += bf_lo(vv[j].y); a3 += bf_hi(vv[j].y);
      a4 += bf_lo(vv[j].z); a5 += bf_hi(vv[j].z);
      a6 += bf_lo(vv[j].w); a7 += bf_hi(vv[j].w);
    }
  }
  if (e + 4 <= cnt) {
    int rr[4];
#pragma unroll
    for (int j = 0; j < 4; ++j) rr[j] = srcbuf[st + e + j];
    uint4 vv[4];
#pragma unroll
    for (int j = 0; j < 4; ++j) vv[j] = Bs4[(size_t)rr[j] * 16 + lane];
#pragma unroll
    for (int j = 0; j < 4; ++j) {
      a0 += bf_lo(vv[j].x); a1 += bf_hi(vv[j].x);
      a2 += bf_lo(vv[j].y); a3 += bf_hi(vv[j].y);
      a4 += bf_lo(vv[j].z); a5 += bf_hi(vv[j].z);
      a6 += bf_lo(vv[j].w); a7 += bf_hi(vv[j].w);
    }
    e += 4;
  }
  for (; e < cnt; ++e) {
    uint4 v = Bs4[(size_t)srcbuf[st + e] * 16 + lane];
    a0 += bf_lo(v.x); a1 += bf_hi(v.x); a2 += bf_lo(v.y); a3 += bf_hi(v.y);
    a4 += bf_lo(v.z); a5 += bf_hi(v.z); a6 += bf_lo(v.w); a7 += bf_hi(v.w);
  }
  float dvv = dinv[rn];
  int c = lane * 8;
  uint4 o;
  o.x = pack2(a0 * dvv + bias[c],     a1 * dvv + bias[c + 1]);
  o.y = pack2(a2 * dvv + bias[c + 2], a3 * dvv + bias[c + 3]);
  o.z = pack2(a4 * dvv + bias[c + 4], a5 * dvv + bias[c + 5]);
  o.w = pack2(a6 * dvv + bias[c + 6], a7 * dvv + bias[c + 7]);
  Ab4[(size_t)rn * 16 + lane] = o;
}

// ---------------- batchnorm stats ----------------

__global__ void bn_stats(const unsigned* __restrict__ Ab2, float* __restrict__ sums, int N) {
  int r = blockIdx.y;
  int lane = threadIdx.x & 63, grp = threadIdx.x >> 6;
  float s0 = 0.f, q0 = 0.f, s1 = 0.f, q1 = 0.f;
  const unsigned* base = Ab2 + (size_t)r * N * 64;
  for (int n = blockIdx.x * 4 + grp; n < N; n += gridDim.x * 4) {
    unsigned u = base[(size_t)n * 64 + lane];
    float a = bf_lo(u), b = bf_hi(u);
    s0 += a; q0 += a * a; s1 += b; q1 += b * b;
  }
  __shared__ float sh[4][64][4];
  sh[grp][lane][0] = s0; sh[grp][lane][1] = q0; sh[grp][lane][2] = s1; sh[grp][lane][3] = q1;
  __syncthreads();
  if (grp == 0) {
#pragma unroll
    for (int g = 1; g < 4; ++g) {
      s0 += sh[g][lane][0]; q0 += sh[g][lane][1]; s1 += sh[g][lane][2]; q1 += sh[g][lane][3];
    }
    int c0 = lane * 2;
    atomicAdd(sums + (r * DD + c0) * 2, s0);
    atomicAdd(sums + (r * DD + c0) * 2 + 1, q0);
    atomicAdd(sums + (r * DD + c0 + 1) * 2, s1);
    atomicAdd(sums + (r * DD + c0 + 1) * 2 + 1, q1);
  }
}

__device__ __forceinline__ float bfat(uint2 u, int j) {
  unsigned w = (j < 2) ? u.x : u.y;
  return (j & 1) ? bf_hi(w) : bf_lo(w);
}

// region = sum coef[l]*f[l]; coef computed inline from S (softmax w/ stack permutation)
__global__ void final_out(const unsigned short* __restrict__ fb, const float* __restrict__ S,
                          const float* __restrict__ rels3, float* __restrict__ out, int N) {
  size_t NK = (size_t)N * DD;
  size_t i4 = (size_t)blockIdx.x * 256 + threadIdx.x;  // 4-elem groups
  if (i4 >= NK / 4) return;
  float v0 = S[0] / N, v1 = S[1] / N, v2 = S[3] / N, v3 = S[2] / N;
  float mx = fmaxf(fmaxf(v0, v1), fmaxf(v2, v3));
  float e0 = __expf(v0 - mx), e1 = __expf(v1 - mx), e2 = __expf(v2 - mx), e3 = __expf(v3 - mx);
  float inv = 1.f / (e0 + e1 + e2 + e3);
  float c0 = e0 * inv, c1 = e1 * inv, c2 = e3 * inv, c3 = e2 * inv;
  size_t g = i4 * 4;
  int c = (int)(g & 127);
  uint2 u0 = *(const uint2*)(fb + g);
  uint2 u1 = *(const uint2*)(fb + NK + g);
  uint2 u2 = *(const uint2*)(fb + 2 * NK + g);
  uint2 u3 = *(const uint2*)(fb + 3 * NK + g);
  float4 reg4, o1, o2, o3, o4;
  float* rp = &reg4.x; float* p1 = &o1.x; float* p2 = &o2.x; float* p3 = &o3.x; float* p4 = &o4.x;
#pragma unroll
  for (int j = 0; j < 4; ++j) {
    float region = c0 * bfat(u0, j) + c1 * bfat(u1, j) + c2 * bfat(u2, j) + c3 * bfat(u3, j);
    rp[j] = region;
    p1[j] = region * rels3[3 * DD + c + j];
    p2[j] = region * rels3[0 * DD + c + j];
    p3[j] = region * rels3[1 * DD + c + j];
    p4[j] = region * rels3[2 * DD + c + j];
  }
  *(float4*)(out + g) = reg4;
  *(float4*)(out + NK + g) = o1;
  *(float4*)(out + 2 * NK + g) = o2;
  *(float4*)(out + 3 * NK + g) = o3;
  *(float4*)(out + 4 * NK + g) = o4;
}

// ---------------- host ----------------

extern "C" void kernel_launch(void* const* d_in, const int* in_sizes, int n_in,
                              void* d_out, int out_size, void* d_ws, size_t ws_size,
                              hipStream_t stream) {
  const float* features  = (const float*)d_in[0];
  const float* rel_emb   = (const float*)d_in[1];
  const int*   edge_idx  = (const int*)d_in[2];
  const float* W_gcn     = (const float*)d_in[3];
  const float* b_gcn     = (const float*)d_in[4];
  const float* bn_gamma  = (const float*)d_in[5];
  const float* bn_beta   = (const float*)d_in[6];
  const float* W_rt      = (const float*)d_in[7];
  const float* b_rt      = (const float*)d_in[8];
  const float* attn_w_in = (const float*)d_in[9];
  const float* attn_b_in = (const float*)d_in[10];
  const float* attn_wout = (const float*)d_in[11];
  const float* attn_bout = (const float*)d_in[12];
  const float* alphas    = (const float*)d_in[13];
  const float* fusion_q  = (const float*)d_in[14];
  const float* fusion_w  = (const float*)d_in[15];
  const float* fusion_b  = (const float*)d_in[16];

  int N = in_sizes[0] / DD;                  // 50000
  int E = in_sizes[2] / (2 * NREL);          // 400000
  size_t NK = (size_t)N * DD;
  int N4 = 4 * N;

  unsigned short* Xb = (unsigned short*)d_ws;            // 4*NK (emb1)
  unsigned short* Bs = Xb + 4 * NK;                      // 4*NK (messages / f)
  unsigned short* Ab = Bs + 4 * NK;                      // 4*NK (agg / stack)
  unsigned short* Ub = Ab + 4 * NK;                      // 4*NK (spare)
  unsigned short* Fb = Ub + 4 * NK;                      // NK (bf16 features, shared)
  float* dinv  = (float*)(Fb + NK);                      // 4*N
  unsigned short* Wgcnb = (unsigned short*)(dinv + N4);  // 4*16384
  unsigned short* Wab   = Wgcnb + 4 * DD * DD;           // 5*16384
  float* rels  = (float*)(Wab + 5 * DD * DD);            // 4 stages * 512
  float* bnsum = rels + 4 * 512;                         // 2048 (two layers)
  float* bnss  = bnsum + 2048;                           // 1024
  float* S     = bnss + 1024;                            // 4
  int* deg_i   = (int*)(S + 4);                          // 4*N
  int* offs    = deg_i + N4;                             // 4*N
  int* cur     = offs + N4;                              // 4*N
  int* bsums   = cur + N4;                               // 1024
  int* srcb    = bsums + 1024;                           // 4*E

  size_t needed = (size_t)((char*)(srcb + 4 * E) - (char*)d_ws);
  if (ws_size < needed) {
    fprintf(stderr, "kernel_launch: ws too small (%zu < %zu)\n", ws_size, needed);
    return;
  }

  int gemmGrid = (N + 63) / 64;
  int scanBlocks = (N4 + 255) / 256;
  int egrid4 = (E + 1023) / 1024;

  // ---- CSR build + prep (two memsets total) ----
  (void)hipMemsetAsync(deg_i, 0, (size_t)N4 * sizeof(int), stream);
  (void)hipMemsetAsync(bnsum, 0, (2048 + 1024 + 4) * sizeof(float), stream);
  count_deg<<<dim3(egrid4, 4), 256, 0, stream>>>(edge_idx, deg_i, N, E);
  scan_block<<<scanBlocks, 256, 0, stream>>>(deg_i, offs, bsums, dinv, N4);
  scan_sums<<<1, 1024, 0, stream>>>(bsums, scanBlocks);
  scan_add<<<scanBlocks, 256, 0, stream>>>(offs, cur, bsums, N4);
  fill_edges<<<dim3(egrid4, 4), 256, 0, stream>>>(edge_idx, cur, srcb, N, E);

  prep<<<(int)((NK / 4 + 255) / 256), 256, 0, stream>>>(rel_emb, attn_w_in, attn_wout,
                                                        fusion_w, features, rels, Wab,
                                                        (unsigned*)Fb, NK / 4);

  PtrB4 wz, abIn, resIn;
  OutB4 msgOut, xbOut, dummyO;
  for (int r = 0; r < 4; ++r) {
    wz.p[r] = Wgcnb + (size_t)r * DD * DD;
    abIn.p[r] = Ab + (size_t)r * NK;
    msgOut.p[r] = Bs + (size_t)r * NK;
    xbOut.p[r] = Xb + (size_t)r * NK;
    dummyO.p[r] = nullptr;
  }

  // ---- Layer 0 ----
  scale_w_bf<<<256, 256, 0, stream>>>(rels, W_gcn, Wgcnb);
  {
    PtrB4 xs; for (int r = 0; r < 4; ++r) xs.p[r] = Fb;
    gemm_ws<0><<<dim3(gemmGrid, 4), 256, 0, stream>>>(xs, wz, msgOut, nullptr, dinv, N);
  }
  gather_agg<<<(N4 + 15) / 16, 256, 0, stream>>>(srcb, offs, deg_i, dinv, (const uint4*)Bs,
                                                 b_gcn, (uint4*)Ab, N4);
  bn_stats<<<dim3(400, 4), 256, 0, stream>>>((const unsigned*)Ab, bnsum, N);
  bn_rels<<<1, 512, 0, stream>>>(bnsum, bn_gamma, bn_beta, bnss,
                                 rels, W_rt, b_rt, rels + 512, N);

  // ---- Layer 1 (fused BN-update, writeback emb1) ----
  scale_w_bf<<<256, 256, 0, stream>>>(rels + 512, W_gcn + (size_t)DD * DD, Wgcnb);
  for (int r = 0; r < 4; ++r) resIn.p[r] = Fb;           // emb0 = features (shared)
  gemm_upd<1><<<dim3(gemmGrid, 4), 256, 0, stream>>>(resIn, abIn, wz, xbOut, msgOut,
                                                     bnss, dinv, N);
  gather_agg<<<(N4 + 15) / 16, 256, 0, stream>>>(srcb, offs, deg_i, dinv, (const uint4*)Bs,
                                                 b_gcn + DD, (uint4*)Ab, N4);
  bn_stats<<<dim3(400, 4), 256, 0, stream>>>((const unsigned*)Ab, bnsum + 1024, N);
  bn_rels<<<1, 512, 0, stream>>>(bnsum + 1024, bn_gamma + DD, bn_beta + DD, bnss,
                                 rels + 512, W_rt + (size_t)DD * DD, b_rt + DD,
                                 rels + 1024, N);

  // ---- Layer 2 (fused BN-update, no writeback) ----
  scale_w_bf<<<256, 256, 0, stream>>>(rels + 1024, W_gcn + (size_t)2 * DD * DD, Wgcnb);
  for (int r = 0; r < 4; ++r) resIn.p[r] = Xb + (size_t)r * NK;   // emb1
  gemm_upd<0><<<dim3(gemmGrid, 4), 256, 0, stream>>>(resIn, abIn, wz, dummyO, msgOut,
                                                     bnss, dinv, N);
  gather_agg<<<(N4 + 15) / 16, 256, 0, stream>>>(srcb, offs, deg_i, dinv, (const uint4*)Bs,
                                                 b_gcn + 2 * DD, (uint4*)Ab, N4);
  rels_update<<<1, 512, 0, stream>>>(rels + 1024, W_rt + (size_t)2 * DD * DD, b_rt + 2 * DD,
                                     rels + 1536);
  // Ab = final GCN outputs (stack source). Xb, Bs, Ub free.

  const int pstk[4] = {3, 0, 2, 1};
  PtrB4 stk;
  for (int l = 0; l < 4; ++l) stk.p[l] = Ab + (size_t)pstk[l] * NK;

  attn_mega<<<(N + 15) / 16, 256, 0, stream>>>(stk, Wab, attn_b_in, attn_bout, alphas,
                                               fusion_b, fusion_q, Bs, S, N);
  final_out<<<(int)((NK / 4 + 255) / 256), 256, 0, stream>>>(Bs, S, rels + 1536,
                                                             (float*)d_out, N);
}